// Round 1
// baseline (696.833 us; speedup 1.0000x reference)
//
#include <hip/hip_runtime.h>

// Problem constants
#define DM   1024
#define HEADS 16
#define DH   64
#define BB   2
#define CUR  1024
#define TT   2048   // PREV + CUR

typedef float  f32x4  __attribute__((ext_vector_type(4)));
typedef __bf16 bf16_t;
typedef __bf16 bf16x8 __attribute__((ext_vector_type(8)));
typedef __bf16 bf16x4 __attribute__((ext_vector_type(4)));
typedef short  s16x4  __attribute__((ext_vector_type(4)));

static __device__ __forceinline__ f32x4 mfma32(bf16x8 a, bf16x8 b, f32x4 c) {
  return __builtin_amdgcn_mfma_f32_16x16x32_bf16(a, b, c, 0, 0, 0);
}
static __device__ __forceinline__ f32x4 mfma16(bf16x4 a, bf16x4 b, f32x4 c) {
  return __builtin_amdgcn_mfma_f32_16x16x16bf16_1k(
      __builtin_bit_cast(s16x4, a), __builtin_bit_cast(s16x4, b), c, 0, 0, 0);
}

// ---------------- conversion kernels ----------------

__global__ __launch_bounds__(256) void f2bf_kernel(const float* __restrict__ src,
                                                   bf16_t* __restrict__ dst, int n4) {
  int t = blockIdx.x * 256 + threadIdx.x;
  if (t >= n4) return;
  f32x4 v = *(const f32x4*)(src + (size_t)t * 4);
  bf16x4 o;
  o[0] = (bf16_t)v[0]; o[1] = (bf16_t)v[1]; o[2] = (bf16_t)v[2]; o[3] = (bf16_t)v[3];
  *(bf16x4*)(dst + (size_t)t * 4) = o;
}

// h = concat(mem, x) along time, cast to bf16. 1M threads x 4 elems.
__global__ __launch_bounds__(256) void conv_h_kernel(const float* __restrict__ mem,
                                                     const float* __restrict__ x,
                                                     bf16_t* __restrict__ hb) {
  int t = blockIdx.x * 256 + threadIdx.x;       // [0, 2^20)
  int idx = t << 2;                              // element index in (B, T, DM)
  int b   = idx >> 21;                           // T*DM = 2^21
  int rem = idx & ((1 << 21) - 1);
  int tt  = rem >> 10;
  int c   = rem & 1023;
  const float* s = (tt < 1024)
      ? (mem + ((size_t)b * 1024 + tt) * DM + c)
      : (x   + ((size_t)b * 1024 + (tt - 1024)) * DM + c);
  f32x4 v = *(const f32x4*)s;
  bf16x4 o;
  o[0] = (bf16_t)v[0]; o[1] = (bf16_t)v[1]; o[2] = (bf16_t)v[2]; o[3] = (bf16_t)v[3];
  *(bf16x4*)(hb + idx) = o;
}

// B_s second half: pe[j,h,d] = pos_emb[j, h*64+d], replicated for both b.
__global__ __launch_bounds__(256) void pe_fill_kernel(const float* __restrict__ pos_emb,
                                                      bf16_t* __restrict__ Bs) {
  int t  = blockIdx.x * 256 + threadIdx.x;      // [0, 2^20): 32 bh * 2048 j * 16 groups
  int d4 = (t & 15) << 2;
  int j  = (t >> 4) & 2047;
  int bh = t >> 15;                              // b*16+h in [0,32)
  int h  = bh & 15;
  f32x4 v = *(const f32x4*)(pos_emb + (size_t)j * DM + h * 64 + d4);
  bf16x4 o;
  o[0] = (bf16_t)v[0]; o[1] = (bf16_t)v[1]; o[2] = (bf16_t)v[2]; o[3] = (bf16_t)v[3];
  *(bf16x4*)(Bs + ((size_t)bh * TT + j) * 128 + 64 + d4) = o;
}

// ---------------- generic 16x64 GEMM tile (row-major x row-major^T) ----------------
// C[r][c] = sum_k A[r][k] * B[c][k].  Direct global frag loads, no LDS (round-1).
__device__ __forceinline__ void gemm_tile_16x64(const bf16_t* __restrict__ A,
                                                const bf16_t* __restrict__ B,
                                                int lda, int ldb, int r0, int c0,
                                                int K, int lane, f32x4 acc[4]) {
  const int lm   = lane & 15;
  const int kofs = (lane >> 4) << 3;
  const bf16_t* ap = A + (size_t)(r0 + lm) * lda + kofs;
  const bf16_t* bp = B + (size_t)(c0 + lm) * ldb + kofs;
  for (int k = 0; k < K; k += 32) {
    bf16x8 a = *(const bf16x8*)(ap + k);
    acc[0] = mfma32(a, *(const bf16x8*)(bp + k),                     acc[0]);
    acc[1] = mfma32(a, *(const bf16x8*)(bp + (size_t)16 * ldb + k),  acc[1]);
    acc[2] = mfma32(a, *(const bf16x8*)(bp + (size_t)32 * ldb + k),  acc[2]);
    acc[3] = mfma32(a, *(const bf16x8*)(bp + (size_t)48 * ldb + k),  acc[3]);
  }
}

// ---------------- K1: q GEMM -> A_s = [ (q+u)/8 | shift((q+v))/8 ] ----------------
// grid (32,16): x = row-block (64 rows), y = head. 4 waves/block stacked in M.
__global__ __launch_bounds__(256) void k1_q(const bf16_t* __restrict__ xb,
                                            const bf16_t* __restrict__ Wqb,
                                            const float* __restrict__ u,
                                            const float* __restrict__ v,
                                            bf16_t* __restrict__ As) {
  int lane = threadIdx.x & 63, w = threadIdx.x >> 6;
  int r0 = blockIdx.x * 64 + w * 16;
  int h  = blockIdx.y;
  int c0 = h * 64;
  f32x4 acc[4] = {};
  gemm_tile_16x64(xb, Wqb, DM, DM, r0, c0, DM, lane, acc);
  int lm = lane & 15, rowOff = (lane >> 4) << 2;
#pragma unroll
  for (int n = 0; n < 4; n++) {
    int d = n * 16 + lm;
    float uu = u[h * 64 + d];
    float vvv = v[h * 64 + d];
#pragma unroll
    for (int r = 0; r < 4; r++) {
      int row = r0 + rowOff + r;
      int b = row >> 10, i = row & 1023;
      float val = acc[n][r];
      // content operand (q+u)/8
      As[(((size_t)(b * 16 + h)) * CUR + i) * 128 + d] = (bf16_t)((val + uu) * 0.125f);
      // pos operand with rel_shift folded in: b=0 rows shift up by 1, row 1023 = 0
      float qv = (val + vvv) * 0.125f;
      if (b == 0) {
        if (i >= 1)
          As[(((size_t)h) * CUR + (i - 1)) * 128 + 64 + d] = (bf16_t)qv;
        if (i == 1023)
          As[(((size_t)h) * CUR + 1023) * 128 + 64 + d] = (bf16_t)0.0f;
      } else {
        As[(((size_t)(16 + h)) * CUR + i) * 128 + 64 + d] = (bf16_t)qv;
      }
    }
  }
}

// ---------------- K2: kv GEMM -> k into B_s[..][0:64], vv (fp32) ----------------
// grid (64,32): x = row-block of 64 (over B*T=4096), y = col-block of 64 (over 2048)
__global__ __launch_bounds__(256) void k2_kv(const bf16_t* __restrict__ hb,
                                             const bf16_t* __restrict__ Wkvb,
                                             bf16_t* __restrict__ Bs,
                                             float* __restrict__ vv) {
  int lane = threadIdx.x & 63, w = threadIdx.x >> 6;
  int r0 = blockIdx.x * 64 + w * 16;
  int c0 = blockIdx.y * 64;
  f32x4 acc[4] = {};
  gemm_tile_16x64(hb, Wkvb, DM, DM, r0, c0, DM, lane, acc);
  int lm = lane & 15, rowOff = (lane >> 4) << 2;
#pragma unroll
  for (int n = 0; n < 4; n++) {
    int c = c0 + n * 16 + lm;
#pragma unroll
    for (int r = 0; r < 4; r++) {
      int row = r0 + rowOff + r;
      int b = row >> 11, j = row & 2047;
      float val = acc[n][r];
      if (c < 1024) {
        int h = c >> 6, d = c & 63;
        Bs[(((size_t)(b * 16 + h)) * TT + j) * 128 + d] = (bf16_t)val;
      } else {
        int c2 = c - 1024;
        int h = c2 >> 6, d = c2 & 63;
        vv[(((size_t)(b * 16 + h)) * TT + j) * 64 + d] = val;
      }
    }
  }
}

// ---------------- K3: column softmax stats over i (per b,h,j) ----------------
// 4096 waves; each wave: one (b,h, j-tile of 16), loops all 64 i-tiles.
__global__ __launch_bounds__(256) void k3_stats(const bf16_t* __restrict__ As,
                                                const bf16_t* __restrict__ Bs,
                                                float* __restrict__ Mv,
                                                float* __restrict__ Lv) {
  int lane = threadIdx.x & 63;
  int wid  = blockIdx.x * 4 + (threadIdx.x >> 6);
  int j0 = (wid & 127) << 4;
  int bh = wid >> 7;                       // [0,32)
  const bf16_t* arows = As + (size_t)bh * CUR * 128;
  const bf16_t* brows = Bs + (size_t)bh * TT * 128;
  int lm = lane & 15;
  int kofs = (lane >> 4) << 3;
  bf16x8 bfr[4];
  const bf16_t* bp = brows + (size_t)(j0 + lm) * 128 + kofs;
#pragma unroll
  for (int kt = 0; kt < 4; kt++) bfr[kt] = *(const bf16x8*)(bp + kt * 32);
  float m = -3.0e38f, l = 0.0f;
  for (int it = 0; it < 64; it++) {
    const bf16_t* ap = arows + (size_t)(it * 16 + lm) * 128 + kofs;
    f32x4 d = {};
#pragma unroll
    for (int kt = 0; kt < 4; kt++) {
      bf16x8 a = *(const bf16x8*)(ap + kt * 32);
      d = mfma32(a, bfr[kt], d);
    }
    // lane holds col j0+lm, rows (quad*4 + r): online max/sum over its 4 rows
    float tm = fmaxf(fmaxf(d[0], d[1]), fmaxf(d[2], d[3]));
    float nm = fmaxf(m, tm);
    l = l * __expf(m - nm) + __expf(d[0] - nm) + __expf(d[1] - nm) +
        __expf(d[2] - nm) + __expf(d[3] - nm);
    m = nm;
  }
  // combine the 4 quads that share a column
#pragma unroll
  for (int off = 16; off <= 32; off <<= 1) {
    float m2 = __shfl_xor(m, off, 64);
    float l2 = __shfl_xor(l, off, 64);
    float nm = fmaxf(m, m2);
    l = l * __expf(m - nm) + l2 * __expf(m2 - nm);
    m = nm;
  }
  if (lane < 16) {
    Mv[(size_t)bh * TT + j0 + lane] = m;
    Lv[(size_t)bh * TT + j0 + lane] = l;
  }
}

// ---------------- K2c: vvnT[b,h,d,j] = bf16(vv[b,h,j,d] / L[b,h,j]) ----------------
// grid 1024: (bh, j-chunk of 64)
__global__ __launch_bounds__(256) void k2c_vvn(const float* __restrict__ vv,
                                               const float* __restrict__ Lv,
                                               bf16_t* __restrict__ vvnT) {
  __shared__ float tile[64][65];
  __shared__ float rl[64];
  int bid = blockIdx.x;
  int jc = bid & 31, bh = bid >> 5;
  int j0 = jc * 64;
  const float* src = vv + ((size_t)bh * TT + j0) * 64;
  int t = threadIdx.x;
#pragma unroll
  for (int s = 0; s < 16; s++) {
    int idx = s * 256 + t;
    tile[idx >> 6][idx & 63] = src[idx];
  }
  if (t < 64) rl[t] = 1.0f / Lv[(size_t)bh * TT + j0 + t];
  __syncthreads();
  int d = t >> 2, jg = (t & 3) * 16;
  bf16_t* dst = vvnT + ((size_t)bh * 64 + d) * TT + j0 + jg;
#pragma unroll
  for (int e4 = 0; e4 < 4; e4++) {
    bf16x4 o;
#pragma unroll
    for (int e = 0; e < 4; e++) {
      int jj = jg + e4 * 4 + e;
      o[e] = (bf16_t)(tile[jj][d] * rl[jj]);
    }
    *(bf16x4*)(dst + e4 * 4) = o;
  }
}

// ---------------- K4: out_w[i,d] = sum_j exp(s[i,j]-M[j]) * vvnT[d,j] ----------------
// 2048 waves; each wave: one (b,h, i-tile of 16), loops all 128 j-tiles.
// sT via 16x16x32 MFMA; its C-layout == B-operand layout of 16x16x16 MFMA (PV step).
__global__ __launch_bounds__(256) void k4_attnv(const bf16_t* __restrict__ As,
                                                const bf16_t* __restrict__ Bs,
                                                const bf16_t* __restrict__ vvnT,
                                                const float* __restrict__ Mv,
                                                bf16_t* __restrict__ wout) {
  __shared__ float lds[4][64 * 17];
  int lane = threadIdx.x & 63, widx = threadIdx.x >> 6;
  int wid = blockIdx.x * 4 + widx;
  int i0 = (wid & 63) << 4;
  int bh = wid >> 6;                       // [0,32)
  int b = bh >> 4, h = bh & 15;
  const bf16_t* arows = Bs + (size_t)bh * TT * 128;    // A-operand: B_s j-rows
  const bf16_t* brows = As + (size_t)bh * CUR * 128;   // B-operand: A_s i-rows
  const bf16_t* vrows = vvnT + (size_t)bh * 64 * TT;
  const float* mcol = Mv + (size_t)bh * TT;
  int lm = lane & 15, q = lane >> 4;
  int kofs = q << 3;
  bf16x8 bfr[4];
  const bf16_t* bp = brows + (size_t)(i0 + lm) * 128 + kofs;
#pragma unroll
  for (int kt = 0; kt < 4; kt++) bfr[kt] = *(const bf16x8*)(bp + kt * 32);
  f32x4 acc[4] = {};
  for (int jt = 0; jt < 128; jt++) {
    int j0 = jt * 16;
    const bf16_t* ap = arows + (size_t)(j0 + lm) * 128 + kofs;
    f32x4 s = {};
#pragma unroll
    for (int kt = 0; kt < 4; kt++) {
      bf16x8 a = *(const bf16x8*)(ap + kt * 32);
      s = mfma32(a, bfr[kt], s);
    }
    // lane: rows j = j0 + q*4 + r, col i = i0 + lm
    f32x4 mj = *(const f32x4*)(mcol + j0 + q * 4);
    bf16x4 p;
    p[0] = (bf16_t)__expf(s[0] - mj[0]);
    p[1] = (bf16_t)__expf(s[1] - mj[1]);
    p[2] = (bf16_t)__expf(s[2] - mj[2]);
    p[3] = (bf16_t)__expf(s[3] - mj[3]);
#pragma unroll
    for (int dt = 0; dt < 4; dt++) {
      bf16x4 a2 = *(const bf16x4*)(vrows + (size_t)(dt * 16 + lm) * TT + j0 + q * 4);
      acc[dt] = mfma16(a2, p, acc[dt]);     // wT[d][i] accumulate
    }
  }
  // transpose wT (64 d x 16 i) -> w rows via LDS
  float* T = lds[widx];
#pragma unroll
  for (int dt = 0; dt < 4; dt++)
#pragma unroll
    for (int r = 0; r < 4; r++)
      T[(dt * 16 + q * 4 + r) * 17 + lm] = acc[dt][r];
  __syncthreads();
  int ir = lane >> 2;
  int dc = (lane & 3) * 16;
  bf16_t* orow = wout + ((size_t)(b * CUR + i0 + ir)) * DM + h * 64 + dc;
#pragma unroll
  for (int e4 = 0; e4 < 4; e4++) {
    bf16x4 o;
#pragma unroll
    for (int e = 0; e < 4; e++) o[e] = (bf16_t)T[(dc + e4 * 4 + e) * 17 + ir];
    *(bf16x4*)(orow + e4 * 4) = o;
  }
}

// ---------------- K5: y = x + w @ Wfc^T + bfc ----------------
__global__ __launch_bounds__(256) void k5_fc(const bf16_t* __restrict__ wb,
                                             const bf16_t* __restrict__ Wfcb,
                                             const float* __restrict__ x,
                                             const float* __restrict__ bfc,
                                             float* __restrict__ y) {
  int lane = threadIdx.x & 63, w = threadIdx.x >> 6;
  int r0 = blockIdx.x * 64 + w * 16;
  int c0 = blockIdx.y * 64;
  f32x4 acc[4] = {};
  gemm_tile_16x64(wb, Wfcb, DM, DM, r0, c0, DM, lane, acc);
  int lm = lane & 15, rowOff = (lane >> 4) << 2;
#pragma unroll
  for (int n = 0; n < 4; n++) {
    int c = c0 + n * 16 + lm;
    float bc = bfc[c];
#pragma unroll
    for (int r = 0; r < 4; r++) {
      int row = r0 + rowOff + r;
      y[(size_t)row * DM + c] = acc[n][r] + x[(size_t)row * DM + c] + bc;
    }
  }
}

// ---------------- K6: LayerNorm ----------------
__global__ __launch_bounds__(256) void k6_ln(const float* __restrict__ y,
                                             const float* __restrict__ gamma,
                                             const float* __restrict__ beta,
                                             float* __restrict__ out) {
  int row = blockIdx.x, t = threadIdx.x;
  const float* yr = y + (size_t)row * DM;
  f32x4 v = *(const f32x4*)(yr + t * 4);
  float s = v[0] + v[1] + v[2] + v[3];
  float ss = v[0] * v[0] + v[1] * v[1] + v[2] * v[2] + v[3] * v[3];
#pragma unroll
  for (int off = 1; off < 64; off <<= 1) {
    s += __shfl_xor(s, off, 64);
    ss += __shfl_xor(ss, off, 64);
  }
  __shared__ float ps[4], pss[4];
  int wv = t >> 6, ln = t & 63;
  if (ln == 0) { ps[wv] = s; pss[wv] = ss; }
  __syncthreads();
  s = ps[0] + ps[1] + ps[2] + ps[3];
  ss = pss[0] + pss[1] + pss[2] + pss[3];
  float mu = s * (1.0f / DM);
  float var = ss * (1.0f / DM) - mu * mu;
  float rstd = rsqrtf(var + 1e-5f);
  f32x4 g = *(const f32x4*)(gamma + t * 4);
  f32x4 bb = *(const f32x4*)(beta + t * 4);
  f32x4 o;
#pragma unroll
  for (int e = 0; e < 4; e++) o[e] = (v[e] - mu) * rstd * g[e] + bb[e];
  *(f32x4*)(out + (size_t)row * DM + t * 4) = o;
}

// ---------------- launch ----------------
extern "C" void kernel_launch(void* const* d_in, const int* in_sizes, int n_in,
                              void* d_out, int out_size, void* d_ws, size_t ws_size,
                              hipStream_t stream) {
  const float* x    = (const float*)d_in[0];
  const float* pos  = (const float*)d_in[1];
  const float* u    = (const float*)d_in[2];
  const float* v    = (const float*)d_in[3];
  // d_in[4] = tgt_mask: all ones in this problem -> masking is a no-op
  const float* mem  = (const float*)d_in[5];
  const float* Wq   = (const float*)d_in[6];
  const float* Wkv  = (const float*)d_in[7];
  const float* Wfc  = (const float*)d_in[8];
  const float* bfc  = (const float*)d_in[9];
  const float* gam  = (const float*)d_in[10];
  const float* bet  = (const float*)d_in[11];
  float* out = (float*)d_out;

  char* ws = (char*)d_ws;
  const size_t MB = 1ull << 20;
  bf16_t* xb   = (bf16_t*)(ws);              // 4 MB  (2M bf16)
  bf16_t* hb   = (bf16_t*)(ws + 4 * MB);     // 8 MB  (4M bf16)
  bf16_t* wqb  = (bf16_t*)(ws + 12 * MB);    // 2 MB
  bf16_t* wkvb = (bf16_t*)(ws + 14 * MB);    // 4 MB
  bf16_t* wfcb = (bf16_t*)(ws + 18 * MB);    // 2 MB
  bf16_t* As   = (bf16_t*)(ws + 20 * MB);    // 8 MB  [bh][i][128]
  bf16_t* Bs   = (bf16_t*)(ws + 28 * MB);    // 16 MB [bh][j][128]
  float*  vvb  = (float*) (ws + 44 * MB);    // 16 MB [bh][j][64]
  float*  Mv   = (float*) (ws + 60 * MB);    // 256 KB
  float*  Lv   = (float*) (ws + 61 * MB);    // 256 KB
  bf16_t* vvnT = (bf16_t*)(ws + 62 * MB);    // 8 MB  [bh][d][2048]
  bf16_t* wbuf = (bf16_t*)(ws + 70 * MB);    // 4 MB  [b*CUR][DM]
  float*  y    = (float*) (ws + 74 * MB);    // 8 MB  -> total 82 MB

  // conversions
  f2bf_kernel<<<2048, 256, 0, stream>>>(x, xb, 2 * CUR * DM / 4);
  conv_h_kernel<<<4096, 256, 0, stream>>>(mem, x, hb);
  f2bf_kernel<<<1024, 256, 0, stream>>>(Wq, wqb, DM * DM / 4);
  f2bf_kernel<<<2048, 256, 0, stream>>>(Wkv, wkvb, 2 * DM * DM / 4);
  f2bf_kernel<<<1024, 256, 0, stream>>>(Wfc, wfcb, DM * DM / 4);
  // projections
  k1_q<<<dim3(32, 16), 256, 0, stream>>>(xb, wqb, u, v, As);
  k2_kv<<<dim3(64, 32), 256, 0, stream>>>(hb, wkvb, Bs, vvb);
  pe_fill_kernel<<<4096, 256, 0, stream>>>(pos, Bs);
  // softmax-over-i stats
  k3_stats<<<1024, 256, 0, stream>>>(As, Bs, Mv, Lv);
  // V / L, transposed
  k2c_vvn<<<1024, 256, 0, stream>>>(vvb, Lv, vvnT);
  // attention * V
  k4_attnv<<<512, 256, 0, stream>>>(As, Bs, vvnT, Mv, wbuf);
  // fc + residual
  k5_fc<<<dim3(32, 16), 256, 0, stream>>>(wbuf, wfcb, x, bfc, y);
  // layernorm
  k6_ln<<<2048, 256, 0, stream>>>(y, gam, bet, out);
}

// Round 2
// 303.845 us; speedup vs baseline: 2.2934x; 2.2934x over previous
//
#include <hip/hip_runtime.h>

#define DM   1024
#define HEADS 16
#define DH   64
#define CUR  1024
#define TT   2048

typedef float  f32x4  __attribute__((ext_vector_type(4)));
typedef __bf16 bf16_t;
typedef __bf16 bf16x8 __attribute__((ext_vector_type(8)));
typedef __bf16 bf16x4 __attribute__((ext_vector_type(4)));
typedef short  s16x4  __attribute__((ext_vector_type(4)));

static __device__ __forceinline__ f32x4 mfma32(bf16x8 a, bf16x8 b, f32x4 c) {
  return __builtin_amdgcn_mfma_f32_16x16x32_bf16(a, b, c, 0, 0, 0);
}
static __device__ __forceinline__ f32x4 mfma16(bf16x4 a, bf16x4 b, f32x4 c) {
  return __builtin_amdgcn_mfma_f32_16x16x16bf16_1k(
      __builtin_bit_cast(s16x4, a), __builtin_bit_cast(s16x4, b), c, 0, 0, 0);
}
static __device__ __forceinline__ void gl_lds16(const bf16_t* g, bf16_t* l) {
  __builtin_amdgcn_global_load_lds(
      (const __attribute__((address_space(1))) void*)g,
      (__attribute__((address_space(3))) void*)l, 16, 0, 0);
}

// ---------------- conversion kernels ----------------

__global__ __launch_bounds__(256) void f2bf_kernel(const float* __restrict__ src,
                                                   bf16_t* __restrict__ dst, int n4) {
  int t = blockIdx.x * 256 + threadIdx.x;
  if (t >= n4) return;
  f32x4 v = *(const f32x4*)(src + (size_t)t * 4);
  bf16x4 o;
  o[0] = (bf16_t)v[0]; o[1] = (bf16_t)v[1]; o[2] = (bf16_t)v[2]; o[3] = (bf16_t)v[3];
  *(bf16x4*)(dst + (size_t)t * 4) = o;
}

__global__ __launch_bounds__(256) void conv_h_kernel(const float* __restrict__ mem,
                                                     const float* __restrict__ x,
                                                     bf16_t* __restrict__ hb) {
  int t = blockIdx.x * 256 + threadIdx.x;
  int idx = t << 2;
  int b   = idx >> 21;
  int rem = idx & ((1 << 21) - 1);
  int tt  = rem >> 10;
  int c   = rem & 1023;
  const float* s = (tt < 1024)
      ? (mem + ((size_t)b * 1024 + tt) * DM + c)
      : (x   + ((size_t)b * 1024 + (tt - 1024)) * DM + c);
  f32x4 v = *(const f32x4*)s;
  bf16x4 o;
  o[0] = (bf16_t)v[0]; o[1] = (bf16_t)v[1]; o[2] = (bf16_t)v[2]; o[3] = (bf16_t)v[3];
  *(bf16x4*)(hb + idx) = o;
}

__global__ __launch_bounds__(256) void pe_fill_kernel(const float* __restrict__ pos_emb,
                                                      bf16_t* __restrict__ Bs) {
  int t  = blockIdx.x * 256 + threadIdx.x;
  int d4 = (t & 15) << 2;
  int j  = (t >> 4) & 2047;
  int bh = t >> 15;
  int h  = bh & 15;
  f32x4 v = *(const f32x4*)(pos_emb + (size_t)j * DM + h * 64 + d4);
  bf16x4 o;
  o[0] = (bf16_t)v[0]; o[1] = (bf16_t)v[1]; o[2] = (bf16_t)v[2]; o[3] = (bf16_t)v[3];
  *(bf16x4*)(Bs + ((size_t)bh * TT + j) * 128 + 64 + d4) = o;
}

// ---------------- LDS-staged GEMM core: C[r][c] = sum_k A[r][k]*B[c][k] ----------------
// 256 threads, BN=128, BM=WM*32 (WM tiles of 16 rows per wave), BK=32, K=1024.
template<int WM>
__device__ __forceinline__ void gemm_core(const bf16_t* __restrict__ A,
                                          const bf16_t* __restrict__ B,
                                          int r0, int c0,
                                          bf16_t* At, bf16_t* Bt,
                                          f32x4 (&acc)[WM][4]) {
  const int BM = WM * 32;
  const int tid = threadIdx.x;
  const int w = tid >> 6, l = tid & 63;
  const int lm = l & 15, q = l >> 4;
  const int wrow = w >> 1, wcol = w & 1;
  const bf16_t* gA = A + (size_t)(r0 + w * (BM / 64) * 16 + (l >> 2)) * 1024 + (l & 3) * 8;
  const bf16_t* gB = B + (size_t)(c0 + w * 32 + (l >> 2)) * 1024 + (l & 3) * 8;
  bf16_t* lA = At + (w * (BM / 64)) * 512;
  bf16_t* lB = Bt + (w * 2) * 512;
  const bf16_t* fA = At + (wrow * WM * 16 + lm) * 32 + q * 8;
  const bf16_t* fB = Bt + (wcol * 64 + lm) * 32 + q * 8;
  for (int k0 = 0; k0 < 1024; k0 += 32) {
#pragma unroll
    for (int t = 0; t < BM / 64; ++t)
      gl_lds16(gA + (size_t)t * 16 * 1024 + k0, lA + t * 512);
#pragma unroll
    for (int t = 0; t < 2; ++t)
      gl_lds16(gB + (size_t)t * 16 * 1024 + k0, lB + t * 512);
    __syncthreads();
    bf16x8 af[WM], bfm[4];
#pragma unroll
    for (int it = 0; it < WM; ++it) af[it] = *(const bf16x8*)(fA + it * 512);
#pragma unroll
    for (int jt = 0; jt < 4; ++jt)  bfm[jt] = *(const bf16x8*)(fB + jt * 512);
#pragma unroll
    for (int it = 0; it < WM; ++it)
#pragma unroll
      for (int jt = 0; jt < 4; ++jt)
        acc[it][jt] = mfma32(af[it], bfm[jt], acc[it][jt]);
    __syncthreads();
  }
}

// ---------------- K1: q GEMM -> A_s = [ (q+u)/8 | shift((q+v))/8 ] ----------------
// grid (32, 8): BM=64 over rows (B*CUR), BN=128 over cols (d_model)
__global__ __launch_bounds__(256) void k1_q(const bf16_t* __restrict__ xb,
                                            const bf16_t* __restrict__ Wqb,
                                            const float* __restrict__ u,
                                            const float* __restrict__ v,
                                            bf16_t* __restrict__ As) {
  __shared__ bf16_t At[64 * 32];
  __shared__ bf16_t Bt[128 * 32];
  __shared__ float Tt[4][16 * 17];
  int r0 = blockIdx.x * 64, c0 = blockIdx.y * 128;
  f32x4 acc[2][4] = {};
  gemm_core<2>(xb, Wqb, r0, c0, At, Bt, acc);
  const int tid = threadIdx.x;
  const int w = tid >> 6, l = tid & 63;
  const int lm = l & 15, q = l >> 4;
  const int wrow = w >> 1, wcol = w & 1;
  float* Tw = Tt[w];
  int h = (c0 + wcol * 64) >> 6;
#pragma unroll
  for (int it = 0; it < 2; ++it) {
#pragma unroll
    for (int jt = 0; jt < 4; ++jt) {
#pragma unroll
      for (int r = 0; r < 4; ++r) Tw[(q * 4 + r) * 17 + lm] = acc[it][jt][r];
      __builtin_amdgcn_wave_barrier();
      // transposed view: lane -> row i_off=lm, cols d0 = jt*16+q*4..+3
      int row = r0 + wrow * 32 + it * 16 + lm;
      int b = row >> 10, ii = row & 1023;
      int cbase = c0 + wcol * 64 + jt * 16 + q * 4;
      int d0 = cbase & 63;
      f32x4 u4 = *(const f32x4*)(u + cbase);
      f32x4 v4 = *(const f32x4*)(v + cbase);
      f32x4 tv;
#pragma unroll
      for (int e = 0; e < 4; ++e) tv[e] = Tw[lm * 17 + q * 4 + e];
      bf16x4 oc, op;
#pragma unroll
      for (int e = 0; e < 4; ++e) {
        oc[e] = (bf16_t)((tv[e] + u4[e]) * 0.125f);
        op[e] = (bf16_t)((tv[e] + v4[e]) * 0.125f);
      }
      *(bf16x4*)(As + (((size_t)(b * 16 + h)) * CUR + ii) * 128 + d0) = oc;
      if (b == 0) {
        if (ii >= 1)
          *(bf16x4*)(As + (((size_t)h) * CUR + (ii - 1)) * 128 + 64 + d0) = op;
        if (ii == 1023) {
          bf16x4 z = {};
          *(bf16x4*)(As + (((size_t)h) * CUR + 1023) * 128 + 64 + d0) = z;
        }
      } else {
        *(bf16x4*)(As + (((size_t)(16 + h)) * CUR + ii) * 128 + 64 + d0) = op;
      }
      __builtin_amdgcn_wave_barrier();
    }
  }
}

// ---------------- K2: kv GEMM -> k into Bs[..][0:64], v -> vvT[bh][d][j] ----------------
// grid (32, 16): BM=128 over rows (B*T), BN=128 over cols (2*d_model)
__global__ __launch_bounds__(256) void k2_kv(const bf16_t* __restrict__ hb,
                                             const bf16_t* __restrict__ Wkvb,
                                             bf16_t* __restrict__ Bs,
                                             bf16_t* __restrict__ vvT) {
  __shared__ bf16_t At[128 * 32];
  __shared__ bf16_t Bt[128 * 32];
  int r0 = blockIdx.x * 128, c0 = blockIdx.y * 128;
  f32x4 acc[4][4] = {};
  gemm_core<4>(hb, Wkvb, r0, c0, At, Bt, acc);
  const int tid = threadIdx.x;
  const int w = tid >> 6, l = tid & 63;
  const int lm = l & 15, q = l >> 4;
  const int wrow = w >> 1, wcol = w & 1;
  bool khalf = (c0 < 1024);
  int b = r0 >> 11;  // block rows stay within one batch (2048 % 128 == 0)
#pragma unroll
  for (int it = 0; it < 4; ++it) {
#pragma unroll
    for (int jt = 0; jt < 4; ++jt) {
      int row0 = r0 + wrow * 64 + it * 16 + q * 4;
      int c = c0 + wcol * 64 + jt * 16 + lm;
      if (khalf) {
        int h = c >> 6, d = c & 63;
#pragma unroll
        for (int r = 0; r < 4; ++r) {
          int j = (row0 + r) & 2047;
          Bs[(((size_t)(b * 16 + h)) * TT + j) * 128 + d] = (bf16_t)acc[it][jt][r];
        }
      } else {
        int c2 = c - 1024;
        int h = c2 >> 6, d = c2 & 63;
        int j = row0 & 2047;
        bf16x4 o;
#pragma unroll
        for (int r = 0; r < 4; ++r) o[r] = (bf16_t)acc[it][jt][r];
        *(bf16x4*)(vvT + (((size_t)(b * 16 + h)) * 64 + d) * TT + j) = o;
      }
    }
  }
}

// ---------------- K3: column stats over i -> LL[bh][j] = M + log(L) ----------------
// grid 512: (bh, j-block of 128). 4 waves x 32 j each. As staged in LDS.
__global__ __launch_bounds__(256) void k3_stats(const bf16_t* __restrict__ As,
                                                const bf16_t* __restrict__ Bs,
                                                float* __restrict__ LL) {
  __shared__ bf16_t At[64 * 128];  // four [64][32] kt-subtiles
  const int tid = threadIdx.x;
  const int w = tid >> 6, l = tid & 63;
  const int lm = l & 15, q = l >> 4;
  int jblk = blockIdx.x & 15, bh = blockIdx.x >> 4;
  int j0 = jblk * 128;
  const bf16_t* bsrow = Bs + ((size_t)bh * TT + j0 + w * 32 + lm) * 128 + q * 8;
  bf16x8 bfr[2][4];
#pragma unroll
  for (int js = 0; js < 2; ++js)
#pragma unroll
    for (int kt = 0; kt < 4; ++kt)
      bfr[js][kt] = *(const bf16x8*)(bsrow + js * 16 * 128 + kt * 32);
  const bf16_t* abase = As + (size_t)bh * CUR * 128 + (size_t)(l >> 2) * 128 + w * 32 + (l & 3) * 8;
  bf16_t* lA = At + w * 2048;
  const bf16_t* fA = At + lm * 32 + q * 8;
  float m0 = -3.0e38f, l0 = 0.f, m1 = -3.0e38f, l1 = 0.f;
  for (int ib = 0; ib < 16; ++ib) {
#pragma unroll
    for (int t = 0; t < 4; ++t)
      gl_lds16(abase + (size_t)(ib * 64 + t * 16) * 128, lA + t * 512);
    __syncthreads();
#pragma unroll
    for (int isub = 0; isub < 4; ++isub) {
      bf16x8 af[4];
#pragma unroll
      for (int kt = 0; kt < 4; ++kt)
        af[kt] = *(const bf16x8*)(fA + kt * 2048 + isub * 512);
      f32x4 s0 = {}, s1 = {};
#pragma unroll
      for (int kt = 0; kt < 4; ++kt) {
        s0 = mfma32(af[kt], bfr[0][kt], s0);
        s1 = mfma32(af[kt], bfr[1][kt], s1);
      }
      float tm = fmaxf(fmaxf(s0[0], s0[1]), fmaxf(s0[2], s0[3]));
      float nm = fmaxf(m0, tm);
      l0 = l0 * __expf(m0 - nm) + __expf(s0[0] - nm) + __expf(s0[1] - nm) +
           __expf(s0[2] - nm) + __expf(s0[3] - nm);
      m0 = nm;
      tm = fmaxf(fmaxf(s1[0], s1[1]), fmaxf(s1[2], s1[3]));
      nm = fmaxf(m1, tm);
      l1 = l1 * __expf(m1 - nm) + __expf(s1[0] - nm) + __expf(s1[1] - nm) +
           __expf(s1[2] - nm) + __expf(s1[3] - nm);
      m1 = nm;
    }
    __syncthreads();
  }
#pragma unroll
  for (int off = 16; off <= 32; off <<= 1) {
    float m2 = __shfl_xor(m0, off, 64), l2 = __shfl_xor(l0, off, 64);
    float nm = fmaxf(m0, m2);
    l0 = l0 * __expf(m0 - nm) + l2 * __expf(m2 - nm);
    m0 = nm;
    m2 = __shfl_xor(m1, off, 64); l2 = __shfl_xor(l1, off, 64);
    nm = fmaxf(m1, m2);
    l1 = l1 * __expf(m1 - nm) + l2 * __expf(m2 - nm);
    m1 = nm;
  }
  if (l < 16) {
    LL[(size_t)bh * TT + j0 + w * 32 + l]      = m0 + logf(l0);
    LL[(size_t)bh * TT + j0 + w * 32 + 16 + l] = m1 + logf(l1);
  }
}

// ---------------- K4: out_w[i,d] = sum_j exp(s[i,j]-LL[j]) * vT[d,j] ----------------
// grid 256: (bh, i-block of 128). 4 waves x 32 i each. Bs+vT staged in LDS per 64-j step.
__global__ __launch_bounds__(256) void k4_attnv(const bf16_t* __restrict__ As,
                                                const bf16_t* __restrict__ Bs,
                                                const bf16_t* __restrict__ vvT,
                                                const float* __restrict__ LL,
                                                bf16_t* __restrict__ wbuf) {
  __shared__ bf16_t Bt[64 * 128];  // four [64][32] kt-subtiles
  __shared__ bf16_t Vt[64 * 64];   // two [64][32] jh-subtiles (rows=d)
  __shared__ float Tt[4][64 * 17];
  const int tid = threadIdx.x;
  const int w = tid >> 6, l = tid & 63;
  const int lm = l & 15, q = l >> 4;
  int iblk = blockIdx.x & 7, bh = blockIdx.x >> 3;
  int b = bh >> 4, h = bh & 15;
  int i0 = iblk * 128;
  const bf16_t* abase = As + (size_t)bh * CUR * 128;
  const bf16_t* bbase = Bs + (size_t)bh * TT * 128 + (size_t)(l >> 2) * 128 + w * 32 + (l & 3) * 8;
  const float* llb = LL + (size_t)bh * TT;
  bf16x8 bi[2][4];
  const bf16_t* ar = abase + (size_t)(i0 + w * 32 + lm) * 128 + q * 8;
#pragma unroll
  for (int is = 0; is < 2; ++is)
#pragma unroll
    for (int kt = 0; kt < 4; ++kt)
      bi[is][kt] = *(const bf16x8*)(ar + is * 16 * 128 + kt * 32);
  // vT staging source: wave w handles insts w*2, w*2+1
  int inst0 = w * 2;
  const bf16_t* vsrc0 = vvT + ((size_t)bh * 64 + ((inst0 & 3) * 16) + (l >> 2)) * TT +
                        ((inst0 >> 2) * 32) + (l & 3) * 8;
  int inst1 = w * 2 + 1;
  const bf16_t* vsrc1 = vvT + ((size_t)bh * 64 + ((inst1 & 3) * 16) + (l >> 2)) * TT +
                        ((inst1 >> 2) * 32) + (l & 3) * 8;
  bf16_t* vdst0 = Vt + (inst0 >> 2) * 2048 + (inst0 & 3) * 512;
  bf16_t* vdst1 = Vt + (inst1 >> 2) * 2048 + (inst1 & 3) * 512;
  bf16_t* lB = Bt + w * 2048;
  const bf16_t* fB = Bt + lm * 32 + q * 8;
  f32x4 acc0[4] = {}, acc1[4] = {};
  for (int jb = 0; jb < 32; ++jb) {
    int j0 = jb * 64;
#pragma unroll
    for (int t = 0; t < 4; ++t)
      gl_lds16(bbase + (size_t)(j0 + t * 16) * 128, lB + t * 512);
    gl_lds16(vsrc0 + j0, vdst0);
    gl_lds16(vsrc1 + j0, vdst1);
    __syncthreads();
#pragma unroll
    for (int js = 0; js < 4; ++js) {
      bf16x8 af[4];
#pragma unroll
      for (int kt = 0; kt < 4; ++kt)
        af[kt] = *(const bf16x8*)(fB + kt * 2048 + js * 512);
      f32x4 s0 = {}, s1 = {};
#pragma unroll
      for (int kt = 0; kt < 4; ++kt) {
        s0 = mfma32(af[kt], bi[0][kt], s0);
        s1 = mfma32(af[kt], bi[1][kt], s1);
      }
      f32x4 ll = *(const f32x4*)(llb + j0 + js * 16 + q * 4);
      bf16x4 p0, p1;
#pragma unroll
      for (int e = 0; e < 4; ++e) {
        p0[e] = (bf16_t)__expf(s0[e] - ll[e]);
        p1[e] = (bf16_t)__expf(s1[e] - ll[e]);
      }
      const bf16_t* vf = Vt + (js >> 1) * 2048 + lm * 32 + (js & 1) * 16 + q * 4;
#pragma unroll
      for (int dt = 0; dt < 4; ++dt) {
        bf16x4 a2 = *(const bf16x4*)(vf + dt * 512);
        acc0[dt] = mfma16(a2, p0, acc0[dt]);
        acc1[dt] = mfma16(a2, p1, acc1[dt]);
      }
    }
    __syncthreads();
  }
  // epilogue: per i-tile transpose wT[64d][16i] -> rows, store bf16
  float* Tw = Tt[w];
  int ir = l >> 2, dc = (l & 3) * 16;
#pragma unroll
  for (int is = 0; is < 2; ++is) {
#pragma unroll
    for (int dt = 0; dt < 4; ++dt) {
      f32x4 a = is ? acc1[dt] : acc0[dt];
#pragma unroll
      for (int r = 0; r < 4; ++r) Tw[(dt * 16 + q * 4 + r) * 17 + lm] = a[r];
    }
    __builtin_amdgcn_wave_barrier();
    int i = i0 + w * 32 + is * 16 + ir;
    bf16_t* orow = wbuf + ((size_t)(b * CUR + i)) * DM + h * 64 + dc;
#pragma unroll
    for (int e4 = 0; e4 < 4; ++e4) {
      bf16x4 o;
#pragma unroll
      for (int e = 0; e < 4; ++e) o[e] = (bf16_t)Tw[(dc + e4 * 4 + e) * 17 + ir];
      *(bf16x4*)(orow + e4 * 4) = o;
    }
    __builtin_amdgcn_wave_barrier();
  }
}

// ---------------- K5: y = x + w @ Wfc^T + bfc ----------------
// grid (32, 8): BM=64, BN=128
__global__ __launch_bounds__(256) void k5_fc(const bf16_t* __restrict__ wb,
                                             const bf16_t* __restrict__ Wfcb,
                                             const float* __restrict__ x,
                                             const float* __restrict__ bfc,
                                             float* __restrict__ y) {
  __shared__ bf16_t At[64 * 32];
  __shared__ bf16_t Bt[128 * 32];
  int r0 = blockIdx.x * 64, c0 = blockIdx.y * 128;
  f32x4 acc[2][4] = {};
  gemm_core<2>(wb, Wfcb, r0, c0, At, Bt, acc);
  const int tid = threadIdx.x;
  const int w = tid >> 6, l = tid & 63;
  const int lm = l & 15, q = l >> 4;
  const int wrow = w >> 1, wcol = w & 1;
#pragma unroll
  for (int it = 0; it < 2; ++it) {
#pragma unroll
    for (int jt = 0; jt < 4; ++jt) {
      int c = c0 + wcol * 64 + jt * 16 + lm;
      float bc = bfc[c];
#pragma unroll
      for (int r = 0; r < 4; ++r) {
        int row = r0 + wrow * 32 + it * 16 + q * 4 + r;
        y[(size_t)row * DM + c] = acc[it][jt][r] + x[(size_t)row * DM + c] + bc;
      }
    }
  }
}

// ---------------- K6: LayerNorm ----------------
__global__ __launch_bounds__(256) void k6_ln(const float* __restrict__ y,
                                             const float* __restrict__ gamma,
                                             const float* __restrict__ beta,
                                             float* __restrict__ out) {
  int row = blockIdx.x, t = threadIdx.x;
  const float* yr = y + (size_t)row * DM;
  f32x4 v = *(const f32x4*)(yr + t * 4);
  float s = v[0] + v[1] + v[2] + v[3];
  float ss = v[0] * v[0] + v[1] * v[1] + v[2] * v[2] + v[3] * v[3];
#pragma unroll
  for (int off = 1; off < 64; off <<= 1) {
    s += __shfl_xor(s, off, 64);
    ss += __shfl_xor(ss, off, 64);
  }
  __shared__ float ps[4], pss[4];
  int wv = t >> 6, ln = t & 63;
  if (ln == 0) { ps[wv] = s; pss[wv] = ss; }
  __syncthreads();
  s = ps[0] + ps[1] + ps[2] + ps[3];
  ss = pss[0] + pss[1] + pss[2] + pss[3];
  float mu = s * (1.0f / DM);
  float var = ss * (1.0f / DM) - mu * mu;
  float rstd = rsqrtf(var + 1e-5f);
  f32x4 g = *(const f32x4*)(gamma + t * 4);
  f32x4 bb = *(const f32x4*)(beta + t * 4);
  f32x4 o;
#pragma unroll
  for (int e = 0; e < 4; ++e) o[e] = (v[e] - mu) * rstd * g[e] + bb[e];
  *(f32x4*)(out + (size_t)row * DM + t * 4) = o;
}

// ---------------- launch ----------------
extern "C" void kernel_launch(void* const* d_in, const int* in_sizes, int n_in,
                              void* d_out, int out_size, void* d_ws, size_t ws_size,
                              hipStream_t stream) {
  const float* x    = (const float*)d_in[0];
  const float* pos  = (const float*)d_in[1];
  const float* u    = (const float*)d_in[2];
  const float* v    = (const float*)d_in[3];
  const float* mem  = (const float*)d_in[5];
  const float* Wq   = (const float*)d_in[6];
  const float* Wkv  = (const float*)d_in[7];
  const float* Wfc  = (const float*)d_in[8];
  const float* bfc  = (const float*)d_in[9];
  const float* gam  = (const float*)d_in[10];
  const float* bet  = (const float*)d_in[11];
  float* out = (float*)d_out;

  char* ws = (char*)d_ws;
  const size_t MB = 1ull << 20;
  bf16_t* xb   = (bf16_t*)(ws);              // 4 MB
  bf16_t* hb   = (bf16_t*)(ws + 4 * MB);     // 8 MB
  bf16_t* wqb  = (bf16_t*)(ws + 12 * MB);    // 2 MB
  bf16_t* wkvb = (bf16_t*)(ws + 14 * MB);    // 4 MB
  bf16_t* wfcb = (bf16_t*)(ws + 18 * MB);    // 2 MB
  bf16_t* As   = (bf16_t*)(ws + 20 * MB);    // 8 MB  [bh][i][128]
  bf16_t* Bs   = (bf16_t*)(ws + 28 * MB);    // 16 MB [bh][j][128]
  bf16_t* vvT  = (bf16_t*)(ws + 44 * MB);    // 8 MB  [bh][d][2048]
  float*  LL   = (float*) (ws + 52 * MB);    // 256 KB
  bf16_t* wbuf = (bf16_t*)(ws + 53 * MB);    // 4 MB
  float*  y    = (float*) (ws + 57 * MB);    // 8 MB -> 65 MB total

  f2bf_kernel<<<2048, 256, 0, stream>>>(x, xb, 2 * CUR * DM / 4);
  conv_h_kernel<<<4096, 256, 0, stream>>>(mem, x, hb);
  f2bf_kernel<<<1024, 256, 0, stream>>>(Wq, wqb, DM * DM / 4);
  f2bf_kernel<<<2048, 256, 0, stream>>>(Wkv, wkvb, 2 * DM * DM / 4);
  f2bf_kernel<<<1024, 256, 0, stream>>>(Wfc, wfcb, DM * DM / 4);

  k1_q<<<dim3(32, 8), 256, 0, stream>>>(xb, wqb, u, v, As);
  k2_kv<<<dim3(32, 16), 256, 0, stream>>>(hb, wkvb, Bs, vvT);
  pe_fill_kernel<<<4096, 256, 0, stream>>>(pos, Bs);

  k3_stats<<<512, 256, 0, stream>>>(As, Bs, LL);
  k4_attnv<<<256, 256, 0, stream>>>(As, Bs, vvT, LL, wbuf);

  k5_fc<<<dim3(32, 8), 256, 0, stream>>>(wbuf, wfcb, x, bfc, y);
  k6_ln<<<2048, 256, 0, stream>>>(y, gam, bet, out);
}

// Round 4
// 251.032 us; speedup vs baseline: 2.7759x; 1.2104x over previous
//
#include <hip/hip_runtime.h>

#define DM   1024
#define CUR  1024
#define TT   2048

typedef float  f32x4  __attribute__((ext_vector_type(4)));
typedef __bf16 bf16_t;
typedef __bf16 bf16x8 __attribute__((ext_vector_type(8)));
typedef __bf16 bf16x4 __attribute__((ext_vector_type(4)));
typedef short  s16x4  __attribute__((ext_vector_type(4)));

#define SCALE_A 0.18033688f   // 0.125 * log2(e): puts scores in log2 domain

static __device__ __forceinline__ float exp2fast(float x) { return __builtin_amdgcn_exp2f(x); }
static __device__ __forceinline__ float log2fast(float x) { return __builtin_amdgcn_logf(x); }

static __device__ __forceinline__ f32x4 mfma32(bf16x8 a, bf16x8 b, f32x4 c) {
  return __builtin_amdgcn_mfma_f32_16x16x32_bf16(a, b, c, 0, 0, 0);
}
static __device__ __forceinline__ f32x4 mfma16(bf16x4 a, bf16x4 b, f32x4 c) {
  return __builtin_amdgcn_mfma_f32_16x16x16bf16_1k(
      __builtin_bit_cast(s16x4, a), __builtin_bit_cast(s16x4, b), c, 0, 0, 0);
}
static __device__ __forceinline__ void gl_lds16(const bf16_t* g, bf16_t* l) {
  __builtin_amdgcn_global_load_lds(
      (const __attribute__((address_space(1))) void*)g,
      (__attribute__((address_space(3))) void*)l, 16, 0, 0);
}

// ---------------- conversion kernels ----------------

// fused weight conversion: Wq (1M) | Wkv (2M) | Wfc (1M)
__global__ __launch_bounds__(256) void wconv_kernel(const float* __restrict__ Wq,
                                                    const float* __restrict__ Wkv,
                                                    const float* __restrict__ Wfc,
                                                    bf16_t* __restrict__ wqb,
                                                    bf16_t* __restrict__ wkvb,
                                                    bf16_t* __restrict__ wfcb) {
  int t = blockIdx.x * 256 + threadIdx.x;    // [0, 1M) groups of 4
  const float* src; bf16_t* dst; int off;
  if (t < 262144)      { src = Wq;  dst = wqb;  off = t; }
  else if (t < 786432) { src = Wkv; dst = wkvb; off = t - 262144; }
  else                 { src = Wfc; dst = wfcb; off = t - 786432; }
  f32x4 v = *(const f32x4*)(src + (size_t)off * 4);
  bf16x4 o;
  o[0] = (bf16_t)v[0]; o[1] = (bf16_t)v[1]; o[2] = (bf16_t)v[2]; o[3] = (bf16_t)v[3];
  *(bf16x4*)(dst + (size_t)off * 4) = o;
}

__global__ __launch_bounds__(256) void conv_h_kernel(const float* __restrict__ mem,
                                                     const float* __restrict__ x,
                                                     bf16_t* __restrict__ hb) {
  int t = blockIdx.x * 256 + threadIdx.x;
  int idx = t << 2;
  int b   = idx >> 21;
  int rem = idx & ((1 << 21) - 1);
  int tt  = rem >> 10;
  int c   = rem & 1023;
  const float* s = (tt < 1024)
      ? (mem + ((size_t)b * 1024 + tt) * DM + c)
      : (x   + ((size_t)b * 1024 + (tt - 1024)) * DM + c);
  f32x4 v = *(const f32x4*)s;
  bf16x4 o;
  o[0] = (bf16_t)v[0]; o[1] = (bf16_t)v[1]; o[2] = (bf16_t)v[2]; o[3] = (bf16_t)v[3];
  *(bf16x4*)(hb + idx) = o;
}

__global__ __launch_bounds__(256) void pe_fill_kernel(const float* __restrict__ pos_emb,
                                                      bf16_t* __restrict__ Bs) {
  int t  = blockIdx.x * 256 + threadIdx.x;
  int d4 = (t & 15) << 2;
  int j  = (t >> 4) & 2047;
  int bh = t >> 15;
  int h  = bh & 15;
  f32x4 v = *(const f32x4*)(pos_emb + (size_t)j * DM + h * 64 + d4);
  bf16x4 o;
  o[0] = (bf16_t)v[0]; o[1] = (bf16_t)v[1]; o[2] = (bf16_t)v[2]; o[3] = (bf16_t)v[3];
  *(bf16x4*)(Bs + ((size_t)bh * TT + j) * 128 + 64 + d4) = o;
}

// ---------------- LDS-staged GEMM core, double-buffered, XOR-swizzled ----------------
// C[r][c] = sum_k A[r][k]*B[c][k]. 256 thr, BN=128, BM=WM*32, BK=32, K=1024.
// LDS row = 32 bf16; colgroup g of row r holds global colgroup g ^ ((r>>1)&3)  -> 2-way
// bank aliasing only (free).
template<int WM>
__device__ __forceinline__ void gemm_core(const bf16_t* __restrict__ A,
                                          const bf16_t* __restrict__ B,
                                          int r0, int c0,
                                          bf16_t* At, bf16_t* Bt,
                                          f32x4 (&acc)[WM][4]) {
  const int ASZ = WM * 1024;   // elems per A buffer
  const int BSZ = 4096;        // elems per B buffer
  const int tid = threadIdx.x, w = tid >> 6, l = tid & 63;
  const int lm = l & 15, q = l >> 4;
  const int wrow = w >> 1, wcol = w & 1;
  const int gg  = (l & 3) ^ ((l >> 3) & 3);
  const int rsw = (lm >> 1) & 3;
  const bf16_t* gA = A + (size_t)(r0 + w * (WM / 2) * 16 + (l >> 2)) * 1024 + gg * 8;
  const bf16_t* gB = B + (size_t)(c0 + w * 32 + (l >> 2)) * 1024 + gg * 8;
  bf16_t* lA = At + w * (WM / 2) * 512;
  bf16_t* lB = Bt + w * 1024;
  const bf16_t* fA = At + (wrow * WM * 16 + lm) * 32;
  const bf16_t* fB = Bt + (wcol * 64 + lm) * 32;
#pragma unroll
  for (int t2 = 0; t2 < WM / 2; ++t2) gl_lds16(gA + (size_t)t2 * 16384, lA + t2 * 512);
#pragma unroll
  for (int t2 = 0; t2 < 2; ++t2)      gl_lds16(gB + (size_t)t2 * 16384, lB + t2 * 512);
  __syncthreads();
  int p = 0;
  for (int k0 = 0; k0 < 1024; k0 += 32) {
    int pn = p ^ 1;
    if (k0 < 992) {
#pragma unroll
      for (int t2 = 0; t2 < WM / 2; ++t2)
        gl_lds16(gA + (size_t)t2 * 16384 + k0 + 32, lA + pn * ASZ + t2 * 512);
#pragma unroll
      for (int t2 = 0; t2 < 2; ++t2)
        gl_lds16(gB + (size_t)t2 * 16384 + k0 + 32, lB + pn * BSZ + t2 * 512);
    }
    bf16x8 af[WM], bfm[4];
#pragma unroll
    for (int it = 0; it < WM; ++it)
      af[it] = *(const bf16x8*)(fA + p * ASZ + it * 512 + ((q ^ rsw) << 3));
#pragma unroll
    for (int jt = 0; jt < 4; ++jt)
      bfm[jt] = *(const bf16x8*)(fB + p * BSZ + jt * 512 + ((q ^ rsw) << 3));
#pragma unroll
    for (int it = 0; it < WM; ++it)
#pragma unroll
      for (int jt = 0; jt < 4; ++jt)
        acc[it][jt] = mfma32(af[it], bfm[jt], acc[it][jt]);
    __syncthreads();
    p = pn;
  }
}

// ---------------- K1: q GEMM -> A_s = [(q+u)*SCALE | shift((q+v))*SCALE] ----------------
// 1D grid 256: c0-panel pinned per XCD (blk&7), r0 = blk>>3. x read through hb.
__global__ __launch_bounds__(256) void k1_q(const bf16_t* __restrict__ hb,
                                            const bf16_t* __restrict__ Wqb,
                                            const float* __restrict__ u,
                                            const float* __restrict__ v,
                                            bf16_t* __restrict__ As) {
  __shared__ union { struct { bf16_t At[4096]; bf16_t Bt[8192]; } m; float Tt[4][272]; } sm;
  int blk = blockIdx.x;
  int r0 = (blk >> 3) * 64, c0 = (blk & 7) * 128;
  int b = r0 >> 10;
  const bf16_t* Axv = hb + ((size_t)(b + 1) << 20);  // hb row (b+1)*1024 + r == x row r
  f32x4 acc[2][4] = {};
  gemm_core<2>(Axv, Wqb, r0, c0, sm.m.At, sm.m.Bt, acc);
  const int tid = threadIdx.x, w = tid >> 6, l = tid & 63;
  const int lm = l & 15, q = l >> 4;
  const int wrow = w >> 1, wcol = w & 1;
  float* Tw = sm.Tt[w];
  int h = (c0 + wcol * 64) >> 6;
#pragma unroll
  for (int it = 0; it < 2; ++it) {
#pragma unroll
    for (int jt = 0; jt < 4; ++jt) {
#pragma unroll
      for (int r = 0; r < 4; ++r) Tw[(q * 4 + r) * 17 + lm] = acc[it][jt][r];
      __builtin_amdgcn_wave_barrier();
      int row = r0 + wrow * 32 + it * 16 + lm;
      int ii = row & 1023;
      int cbase = c0 + wcol * 64 + jt * 16 + q * 4;
      int d0 = cbase & 63;
      f32x4 u4 = *(const f32x4*)(u + cbase);
      f32x4 v4 = *(const f32x4*)(v + cbase);
      f32x4 tv;
#pragma unroll
      for (int e = 0; e < 4; ++e) tv[e] = Tw[lm * 17 + q * 4 + e];
      bf16x4 oc, op;
#pragma unroll
      for (int e = 0; e < 4; ++e) {
        oc[e] = (bf16_t)((tv[e] + u4[e]) * SCALE_A);
        op[e] = (bf16_t)((tv[e] + v4[e]) * SCALE_A);
      }
      *(bf16x4*)(As + (((size_t)(b * 16 + h)) * CUR + ii) * 128 + d0) = oc;
      if (b == 0) {
        if (ii >= 1)
          *(bf16x4*)(As + (((size_t)h) * CUR + (ii - 1)) * 128 + 64 + d0) = op;
        if (ii == 1023) {
          bf16x4 z = {};
          *(bf16x4*)(As + (((size_t)h) * CUR + 1023) * 128 + 64 + d0) = z;
        }
      } else {
        *(bf16x4*)(As + (((size_t)(16 + h)) * CUR + ii) * 128 + 64 + d0) = op;
      }
      __builtin_amdgcn_wave_barrier();
    }
  }
}

// ---------------- K2: kv GEMM -> k (transposed epilogue) + vvT ----------------
// 1D grid 512: c0-panel pinned per XCD.
__global__ __launch_bounds__(256) void k2_kv(const bf16_t* __restrict__ hb,
                                             const bf16_t* __restrict__ Wkvb,
                                             bf16_t* __restrict__ Bs,
                                             bf16_t* __restrict__ vvT) {
  __shared__ union { struct { bf16_t At[8192]; bf16_t Bt[8192]; } m; float Tt[4][272]; } sm;
  int blk = blockIdx.x;
  int xcd = blk & 7, t = blk >> 3;
  int r0 = (t & 31) * 128;
  int c0 = (xcd * 2 + (t >> 5)) * 128;
  f32x4 acc[4][4] = {};
  gemm_core<4>(hb, Wkvb, r0, c0, sm.m.At, sm.m.Bt, acc);
  const int tid = threadIdx.x, w = tid >> 6, l = tid & 63;
  const int lm = l & 15, q = l >> 4;
  const int wrow = w >> 1, wcol = w & 1;
  int b = r0 >> 11;
  if (c0 < 1024) {
    // k half: transpose each 16x16 so stores are bf16x4 along d
    float* Tw = sm.Tt[w];
    int h = (c0 + wcol * 64) >> 6;
#pragma unroll
    for (int it = 0; it < 4; ++it) {
#pragma unroll
      for (int jt = 0; jt < 4; ++jt) {
#pragma unroll
        for (int r = 0; r < 4; ++r) Tw[(q * 4 + r) * 17 + lm] = acc[it][jt][r];
        __builtin_amdgcn_wave_barrier();
        int j = (r0 + wrow * 64 + it * 16 + lm) & 2047;
        int d0 = jt * 16 + q * 4;
        bf16x4 o;
#pragma unroll
        for (int e = 0; e < 4; ++e) o[e] = (bf16_t)Tw[lm * 17 + q * 4 + e];
        *(bf16x4*)(Bs + (((size_t)(b * 16 + h)) * TT + j) * 128 + d0) = o;
        __builtin_amdgcn_wave_barrier();
      }
    }
  } else {
#pragma unroll
    for (int it = 0; it < 4; ++it) {
#pragma unroll
      for (int jt = 0; jt < 4; ++jt) {
        int c2 = c0 + wcol * 64 + jt * 16 + lm - 1024;
        int h = c2 >> 6, d = c2 & 63;
        int j = (r0 + wrow * 64 + it * 16 + q * 4) & 2047;
        bf16x4 o;
#pragma unroll
        for (int r = 0; r < 4; ++r) o[r] = (bf16_t)acc[it][jt][r];
        *(bf16x4*)(vvT + (((size_t)(b * 16 + h)) * 64 + d) * TT + j) = o;
      }
    }
  }
}

// ---------------- K3: column stats over i -> LL[bh][j] = M + log2(L) ----------------
// 1D grid 512, XCD-grouped by bh. dbuf As staging, swizzled LDS.
__global__ __launch_bounds__(256) void k3_stats(const bf16_t* __restrict__ As,
                                                const bf16_t* __restrict__ Bs,
                                                float* __restrict__ LL) {
  __shared__ bf16_t At[2 * 8192];
  const int tid = threadIdx.x, w = tid >> 6, l = tid & 63;
  const int lm = l & 15, q = l >> 4;
  const int gg  = (l & 3) ^ ((l >> 3) & 3);
  const int rsw = (lm >> 1) & 3;
  int blk = blockIdx.x;
  int xcd = blk & 7, t = blk >> 3;
  int jblk = t & 15, bh = xcd * 4 + (t >> 4);
  int j0 = jblk * 128;
  const bf16_t* bsrow = Bs + ((size_t)bh * TT + j0 + w * 32 + lm) * 128 + q * 8;
  bf16x8 bfr[2][4];
#pragma unroll
  for (int js = 0; js < 2; ++js)
#pragma unroll
    for (int kt = 0; kt < 4; ++kt)
      bfr[js][kt] = *(const bf16x8*)(bsrow + js * 2048 + kt * 32);
  const bf16_t* abase = As + (size_t)bh * CUR * 128 + (size_t)(l >> 2) * 128 + w * 32 + gg * 8;
  bf16_t* lA = At + w * 2048;
  const bf16_t* fA = At + lm * 32;
  float m0 = -3.0e38f, l0 = 0.f, m1 = -3.0e38f, l1 = 0.f;
#pragma unroll
  for (int t2 = 0; t2 < 4; ++t2)
    gl_lds16(abase + (size_t)t2 * 16 * 128, lA + t2 * 512);
  __syncthreads();
  int p = 0;
  for (int ib = 0; ib < 16; ++ib) {
    int pn = p ^ 1;
    if (ib < 15) {
#pragma unroll
      for (int t2 = 0; t2 < 4; ++t2)
        gl_lds16(abase + (size_t)((ib + 1) * 64 + t2 * 16) * 128, lA + pn * 8192 + t2 * 512);
    }
#pragma unroll
    for (int isub = 0; isub < 4; ++isub) {
      bf16x8 af[4];
#pragma unroll
      for (int kt = 0; kt < 4; ++kt)
        af[kt] = *(const bf16x8*)(fA + p * 8192 + kt * 2048 + isub * 512 + ((q ^ rsw) << 3));
      f32x4 s0 = {}, s1 = {};
#pragma unroll
      for (int kt = 0; kt < 4; ++kt) {
        s0 = mfma32(af[kt], bfr[0][kt], s0);
        s1 = mfma32(af[kt], bfr[1][kt], s1);
      }
      float tm = fmaxf(fmaxf(s0[0], s0[1]), fmaxf(s0[2], s0[3]));
      float nm = fmaxf(m0, tm);
      l0 = l0 * exp2fast(m0 - nm) + exp2fast(s0[0] - nm) + exp2fast(s0[1] - nm) +
           exp2fast(s0[2] - nm) + exp2fast(s0[3] - nm);
      m0 = nm;
      tm = fmaxf(fmaxf(s1[0], s1[1]), fmaxf(s1[2], s1[3]));
      nm = fmaxf(m1, tm);
      l1 = l1 * exp2fast(m1 - nm) + exp2fast(s1[0] - nm) + exp2fast(s1[1] - nm) +
           exp2fast(s1[2] - nm) + exp2fast(s1[3] - nm);
      m1 = nm;
    }
    __syncthreads();
    p = pn;
  }
#pragma unroll
  for (int off = 16; off <= 32; off <<= 1) {
    float m2 = __shfl_xor(m0, off, 64), l2 = __shfl_xor(l0, off, 64);
    float nm = fmaxf(m0, m2);
    l0 = l0 * exp2fast(m0 - nm) + l2 * exp2fast(m2 - nm);
    m0 = nm;
    m2 = __shfl_xor(m1, off, 64); l2 = __shfl_xor(l1, off, 64);
    nm = fmaxf(m1, m2);
    l1 = l1 * exp2fast(m1 - nm) + l2 * exp2fast(m2 - nm);
    m1 = nm;
  }
  if (l < 16) {
    LL[(size_t)bh * TT + j0 + w * 32 + l]      = m0 + log2fast(l0);
    LL[(size_t)bh * TT + j0 + w * 32 + 16 + l] = m1 + log2fast(l1);
  }
}

// ---------------- K4: partial[i,d] = sum_{j in chunk} exp2(s - LL[j]) * vT[d,j] ----------------
// 1D grid 512 = 8 xcd x 8 pl x 8 iblk; pair = xcd*8+pl -> (bh, jch). dbuf, swizzled.
__global__ __launch_bounds__(256) void k4_attnv(const bf16_t* __restrict__ As,
                                                const bf16_t* __restrict__ Bs,
                                                const bf16_t* __restrict__ vvT,
                                                const float* __restrict__ LL,
                                                float* __restrict__ Pp) {
  __shared__ union {
    struct { bf16_t Bt[2 * 8192]; bf16_t Vt[2 * 4096]; } m;
    float Tt[4][1088];
  } sm;
  int blk = blockIdx.x;
  int xcd = blk & 7, tb = blk >> 3;
  int iblk = tb & 7, pl = tb >> 3;
  int bh = xcd * 4 + (pl >> 1), jch = pl & 1;
  int b = bh >> 4, h = bh & 15;
  int i0 = iblk * 128;
  int jbase = jch * 1024;
  const int tid = threadIdx.x, w = tid >> 6, l = tid & 63;
  const int lm = l & 15, q = l >> 4;
  const int gg  = (l & 3) ^ ((l >> 3) & 3);
  const int rsw = (lm >> 1) & 3;
  // register i-frags (B-operand of score MFMA)
  const bf16_t* ar = As + (size_t)bh * CUR * 128 + (size_t)(i0 + w * 32 + lm) * 128 + q * 8;
  bf16x8 bi[2][4];
#pragma unroll
  for (int is = 0; is < 2; ++is)
#pragma unroll
    for (int kt = 0; kt < 4; ++kt)
      bi[is][kt] = *(const bf16x8*)(ar + is * 2048 + kt * 32);
  const bf16_t* bbase = Bs + ((size_t)bh * TT + jbase) * 128 + (size_t)(l >> 2) * 128 + w * 32 + gg * 8;
  int inst0 = w * 2, inst1 = w * 2 + 1;
  const bf16_t* vsrc0 = vvT + ((size_t)bh * 64 + (inst0 & 3) * 16 + (l >> 2)) * TT + jbase +
                        (inst0 >> 2) * 32 + gg * 8;
  const bf16_t* vsrc1 = vvT + ((size_t)bh * 64 + (inst1 & 3) * 16 + (l >> 2)) * TT + jbase +
                        (inst1 >> 2) * 32 + gg * 8;
  bf16_t* vdst0 = sm.m.Vt + (inst0 >> 2) * 2048 + (inst0 & 3) * 512;
  bf16_t* vdst1 = sm.m.Vt + (inst1 >> 2) * 2048 + (inst1 & 3) * 512;
  bf16_t* lB = sm.m.Bt + w * 2048;
  const float* llb = LL + (size_t)bh * TT + jbase;
  f32x4 acc0[4] = {}, acc1[4] = {};
  // prologue: stage jb=0 into buf 0
#pragma unroll
  for (int t2 = 0; t2 < 4; ++t2)
    gl_lds16(bbase + (size_t)t2 * 16 * 128, lB + t2 * 512);
  gl_lds16(vsrc0, vdst0);
  gl_lds16(vsrc1, vdst1);
  __syncthreads();
  int p = 0;
  for (int jb = 0; jb < 16; ++jb) {
    int pn = p ^ 1;
    if (jb < 15) {
      const bf16_t* bs2 = bbase + (size_t)(jb + 1) * 64 * 128;
#pragma unroll
      for (int t2 = 0; t2 < 4; ++t2)
        gl_lds16(bs2 + (size_t)t2 * 16 * 128, lB + pn * 8192 + t2 * 512);
      gl_lds16(vsrc0 + (jb + 1) * 64, vdst0 + pn * 4096);
      gl_lds16(vsrc1 + (jb + 1) * 64, vdst1 + pn * 4096);
    }
    const bf16_t* fB = sm.m.Bt + p * 8192 + lm * 32;
    const bf16_t* vf = sm.m.Vt + p * 4096 + lm * 32;
#pragma unroll
    for (int js = 0; js < 4; ++js) {
      bf16x8 af[4];
#pragma unroll
      for (int kt = 0; kt < 4; ++kt)
        af[kt] = *(const bf16x8*)(fB + kt * 2048 + js * 512 + ((q ^ rsw) << 3));
      f32x4 s0 = {}, s1 = {};
#pragma unroll
      for (int kt = 0; kt < 4; ++kt) {
        s0 = mfma32(af[kt], bi[0][kt], s0);
        s1 = mfma32(af[kt], bi[1][kt], s1);
      }
      f32x4 ll = *(const f32x4*)(llb + jb * 64 + js * 16 + q * 4);
      bf16x4 p0, p1;
#pragma unroll
      for (int e = 0; e < 4; ++e) {
        p0[e] = (bf16_t)exp2fast(s0[e] - ll[e]);
        p1[e] = (bf16_t)exp2fast(s1[e] - ll[e]);
      }
      int vg = ((js & 1) << 1) | (q >> 1);
      const bf16_t* vfa = vf + (js >> 1) * 2048 + ((vg ^ rsw) << 3) + ((q & 1) << 2);
#pragma unroll
      for (int dt = 0; dt < 4; ++dt) {
        bf16x4 a2 = *(const bf16x4*)(vfa + dt * 512);
        acc0[dt] = mfma16(a2, p0, acc0[dt]);
        acc1[dt] = mfma16(a2, p1, acc1[dt]);
      }
    }
    __syncthreads();
    p = pn;
  }
  // epilogue: transpose wT[64 d][16 i] per i-tile, store fp32 partial rows
  float* Tw = sm.Tt[w];
  float* pout = Pp + ((size_t)jch << 21);
  int ir = l >> 2, dc = (l & 3) * 16;
#pragma unroll
  for (int is = 0; is < 2; ++is) {
#pragma unroll
    for (int dt = 0; dt < 4; ++dt) {
      f32x4 a = is ? acc1[dt] : acc0[dt];
#pragma unroll
      for (int r = 0; r < 4; ++r) Tw[(dt * 16 + q * 4 + r) * 17 + lm] = a[r];
    }
    __builtin_amdgcn_wave_barrier();
    int i = i0 + w * 32 + is * 16 + ir;
    float* orow = pout + ((size_t)(b * CUR + i)) * DM + h * 64 + dc;
#pragma unroll
    for (int e4 = 0; e4 < 4; ++e4) {
      f32x4 o;
#pragma unroll
      for (int e = 0; e < 4; ++e) o[e] = Tw[(dc + e4 * 4 + e) * 17 + ir];
      *(f32x4*)(orow + e4 * 4) = o;
    }
    __builtin_amdgcn_wave_barrier();
  }
}

// ---------------- K4r: wbuf = bf16(P0 + P1) ----------------
__global__ __launch_bounds__(256) void k4_reduce(const float* __restrict__ P,
                                                 bf16_t* __restrict__ wbuf) {
  int t = blockIdx.x * 256 + threadIdx.x;
  f32x4 a = *(const f32x4*)(P + (size_t)t * 4);
  f32x4 c = *(const f32x4*)(P + (1u << 21) + (size_t)t * 4);
  bf16x4 o;
#pragma unroll
  for (int e = 0; e < 4; ++e) o[e] = (bf16_t)(a[e] + c[e]);
  *(bf16x4*)(wbuf + (size_t)t * 4) = o;
}

// ---------------- K5: y = x + w @ Wfc^T + bfc (transposed epilogue) ----------------
__global__ __launch_bounds__(256) void k5_fc(const bf16_t* __restrict__ wb,
                                             const bf16_t* __restrict__ Wfcb,
                                             const float* __restrict__ x,
                                             const float* __restrict__ bfc,
                                             float* __restrict__ y) {
  __shared__ union { struct { bf16_t At[4096]; bf16_t Bt[8192]; } m; float Tt[4][272]; } sm;
  int blk = blockIdx.x;
  int r0 = (blk >> 3) * 64, c0 = (blk & 7) * 128;
  f32x4 acc[2][4] = {};
  gemm_core<2>(wb, Wfcb, r0, c0, sm.m.At, sm.m.Bt, acc);
  const int tid = threadIdx.x, w = tid >> 6, l = tid & 63;
  const int lm = l & 15, q = l >> 4;
  const int wrow = w >> 1, wcol = w & 1;
  float* Tw = sm.Tt[w];
#pragma unroll
  for (int it = 0; it < 2; ++it) {
#pragma unroll
    for (int jt = 0; jt < 4; ++jt) {
#pragma unroll
      for (int r = 0; r < 4; ++r) Tw[(q * 4 + r) * 17 + lm] = acc[it][jt][r];
      __builtin_amdgcn_wave_barrier();
      int row = r0 + wrow * 32 + it * 16 + lm;
      int cb = c0 + wcol * 64 + jt * 16 + q * 4;
      f32x4 xb4 = *(const f32x4*)(x + (size_t)row * DM + cb);
      f32x4 bf4 = *(const f32x4*)(bfc + cb);
      f32x4 o;
#pragma unroll
      for (int e = 0; e < 4; ++e) o[e] = Tw[lm * 17 + q * 4 + e] + xb4[e] + bf4[e];
      *(f32x4*)(y + (size_t)row * DM + cb) = o;
      __builtin_amdgcn_wave_barrier();
    }
  }
}

// ---------------- K6: LayerNorm ----------------
__global__ __launch_bounds__(256) void k6_ln(const float* __restrict__ y,
                                             const float* __restrict__ gamma,
                                             const float* __restrict__ beta,
                                             float* __restrict__ out) {
  int row = blockIdx.x, t = threadIdx.x;
  const float* yr = y + (size_t)row * DM;
  f32x4 v = *(const f32x4*)(yr + t * 4);
  float s = v[0] + v[1] + v[2] + v[3];
  float ss = v[0] * v[0] + v[1] * v[1] + v[2] * v[2] + v[3] * v[3];
#pragma unroll
  for (int off = 1; off < 64; off <<= 1) {
    s += __shfl_xor(s, off, 64);
    ss += __shfl_xor(ss, off, 64);
  }
  __shared__ float ps[4], pss[4];
  int wv = t >> 6, ln = t & 63;
  if (ln == 0) { ps[wv] = s; pss[wv] = ss; }
  __syncthreads();
  s = ps[0] + ps[1] + ps[2] + ps[3];
  ss = pss[0] + pss[1] + pss[2] + pss[3];
  float mu = s * (1.0f / DM);
  float var = ss * (1.0f / DM) - mu * mu;
  float rstd = rsqrtf(var + 1e-5f);
  f32x4 g = *(const f32x4*)(gamma + t * 4);
  f32x4 bb = *(const f32x4*)(beta + t * 4);
  f32x4 o;
#pragma unroll
  for (int e = 0; e < 4; ++e) o[e] = (v[e] - mu) * rstd * g[e] + bb[e];
  *(f32x4*)(out + (size_t)row * DM + t * 4) = o;
}

// ---------------- launch ----------------
extern "C" void kernel_launch(void* const* d_in, const int* in_sizes, int n_in,
                              void* d_out, int out_size, void* d_ws, size_t ws_size,
                              hipStream_t stream) {
  const float* x    = (const float*)d_in[0];
  const float* pos  = (const float*)d_in[1];
  const float* u    = (const float*)d_in[2];
  const float* v    = (const float*)d_in[3];
  const float* mem  = (const float*)d_in[5];
  const float* Wq   = (const float*)d_in[6];
  const float* Wkv  = (const float*)d_in[7];
  const float* Wfc  = (const float*)d_in[8];
  const float* bfc  = (const float*)d_in[9];
  const float* gam  = (const float*)d_in[10];
  const float* bet  = (const float*)d_in[11];
  float* out = (float*)d_out;

  char* ws = (char*)d_ws;
  const size_t MB = 1ull << 20;
  bf16_t* hb   = (bf16_t*)(ws);              // 8 MB  [b][t][c]
  bf16_t* wqb  = (bf16_t*)(ws + 8 * MB);     // 2 MB
  bf16_t* wkvb = (bf16_t*)(ws + 10 * MB);    // 4 MB
  bf16_t* wfcb = (bf16_t*)(ws + 14 * MB);    // 2 MB
  bf16_t* As   = (bf16_t*)(ws + 16 * MB);    // 8 MB  [bh][i][128]
  bf16_t* Bs   = (bf16_t*)(ws + 24 * MB);    // 16 MB [bh][j][128]
  bf16_t* vvT  = (bf16_t*)(ws + 40 * MB);    // 8 MB  [bh][d][2048]
  float*  LL   = (float*) (ws + 48 * MB);    // 256 KB
  bf16_t* wbuf = (bf16_t*)(ws + 49 * MB);    // 4 MB
  float*  y    = (float*) (ws + 53 * MB);    // 8 MB
  float*  Pp   = (float*) (ws + 61 * MB);    // 16 MB (2 x 8 MB partials)

  wconv_kernel<<<4096, 256, 0, stream>>>(Wq, Wkv, Wfc, wqb, wkvb, wfcb);
  conv_h_kernel<<<4096, 256, 0, stream>>>(mem, x, hb);
  pe_fill_kernel<<<4096, 256, 0, stream>>>(pos, Bs);

  k1_q<<<256, 256, 0, stream>>>(hb, wqb, u, v, As);
  k2_kv<<<512, 256, 0, stream>>>(hb, wkvb, Bs, vvT);

  k3_stats<<<512, 256, 0, stream>>>(As, Bs, LL);
  k4_attnv<<<512, 256, 0, stream>>>(As, Bs, vvT, LL, Pp);
  k4_reduce<<<2048, 256, 0, stream>>>(Pp, wbuf);

  k5_fc<<<256, 256, 0, stream>>>(wbuf, wfcb, x, bfc, y);
  k6_ln<<<2048, 256, 0, stream>>>(y, gam, bet, out);
}

// Round 5
// 246.618 us; speedup vs baseline: 2.8256x; 1.0179x over previous
//
#include <hip/hip_runtime.h>

#define DM   1024
#define CUR  1024
#define TT   2048

typedef float  f32x4  __attribute__((ext_vector_type(4)));
typedef __bf16 bf16_t;
typedef __bf16 bf16x8 __attribute__((ext_vector_type(8)));
typedef __bf16 bf16x4 __attribute__((ext_vector_type(4)));
typedef short  s16x4  __attribute__((ext_vector_type(4)));

#define SCALE_A 0.18033688f   // 0.125 * log2(e): scores live in log2 domain

static __device__ __forceinline__ float exp2fast(float x) { return __builtin_amdgcn_exp2f(x); }
static __device__ __forceinline__ float log2fast(float x) { return __builtin_amdgcn_logf(x); }

static __device__ __forceinline__ f32x4 mfma32(bf16x8 a, bf16x8 b, f32x4 c) {
  return __builtin_amdgcn_mfma_f32_16x16x32_bf16(a, b, c, 0, 0, 0);
}
static __device__ __forceinline__ f32x4 mfma16(bf16x4 a, bf16x4 b, f32x4 c) {
  return __builtin_amdgcn_mfma_f32_16x16x16bf16_1k(
      __builtin_bit_cast(s16x4, a), __builtin_bit_cast(s16x4, b), c, 0, 0, 0);
}
static __device__ __forceinline__ void gl_lds16(const bf16_t* g, bf16_t* l) {
  __builtin_amdgcn_global_load_lds(
      (const __attribute__((address_space(1))) void*)g,
      (__attribute__((address_space(3))) void*)l, 16, 0, 0);
}

// ---------------- fused prep: weight cvt + h concat cvt + pe fill ----------------
__global__ __launch_bounds__(256) void prep_kernel(const float* __restrict__ Wq,
                                                   const float* __restrict__ Wkv,
                                                   const float* __restrict__ Wfc,
                                                   const float* __restrict__ mem,
                                                   const float* __restrict__ x,
                                                   const float* __restrict__ pos,
                                                   bf16_t* __restrict__ wqb,
                                                   bf16_t* __restrict__ wkvb,
                                                   bf16_t* __restrict__ wfcb,
                                                   bf16_t* __restrict__ hb,
                                                   bf16_t* __restrict__ Bs) {
  int t = blockIdx.x * 256 + threadIdx.x;   // [0, 3M)
  if (t < (1 << 20)) {
    const float* src; bf16_t* dst; int off;
    if (t < 262144)      { src = Wq;  dst = wqb;  off = t; }
    else if (t < 786432) { src = Wkv; dst = wkvb; off = t - 262144; }
    else                 { src = Wfc; dst = wfcb; off = t - 786432; }
    f32x4 v = *(const f32x4*)(src + (size_t)off * 4);
    bf16x4 o;
    o[0] = (bf16_t)v[0]; o[1] = (bf16_t)v[1]; o[2] = (bf16_t)v[2]; o[3] = (bf16_t)v[3];
    *(bf16x4*)(dst + (size_t)off * 4) = o;
  } else if (t < (2 << 20)) {
    int th = t - (1 << 20);
    int idx = th << 2;
    int b   = idx >> 21;
    int rem = idx & ((1 << 21) - 1);
    int tt  = rem >> 10;
    int c   = rem & 1023;
    const float* s = (tt < 1024)
        ? (mem + ((size_t)b * 1024 + tt) * DM + c)
        : (x   + ((size_t)b * 1024 + (tt - 1024)) * DM + c);
    f32x4 v = *(const f32x4*)s;
    bf16x4 o;
    o[0] = (bf16_t)v[0]; o[1] = (bf16_t)v[1]; o[2] = (bf16_t)v[2]; o[3] = (bf16_t)v[3];
    *(bf16x4*)(hb + idx) = o;
  } else {
    int tp = t - (2 << 20);
    int d4 = (tp & 15) << 2;
    int j  = (tp >> 4) & 2047;
    int bh = tp >> 15;
    int h  = bh & 15;
    f32x4 v = *(const f32x4*)(pos + (size_t)j * DM + h * 64 + d4);
    bf16x4 o;
    o[0] = (bf16_t)v[0]; o[1] = (bf16_t)v[1]; o[2] = (bf16_t)v[2]; o[3] = (bf16_t)v[3];
    *(bf16x4*)(Bs + ((size_t)bh * TT + j) * 128 + 64 + d4) = o;
  }
}

// ---------------- LDS-staged GEMM core, double-buffered, XOR-swizzled ----------------
template<int WM>
__device__ __forceinline__ void gemm_core(const bf16_t* __restrict__ A,
                                          const bf16_t* __restrict__ B,
                                          int r0, int c0,
                                          bf16_t* At, bf16_t* Bt,
                                          f32x4 (&acc)[WM][4]) {
  const int ASZ = WM * 1024;
  const int BSZ = 4096;
  const int tid = threadIdx.x, w = tid >> 6, l = tid & 63;
  const int lm = l & 15, q = l >> 4;
  const int wrow = w >> 1, wcol = w & 1;
  const int gg  = (l & 3) ^ ((l >> 3) & 3);
  const int rsw = (lm >> 1) & 3;
  const bf16_t* gA = A + (size_t)(r0 + w * (WM / 2) * 16 + (l >> 2)) * 1024 + gg * 8;
  const bf16_t* gB = B + (size_t)(c0 + w * 32 + (l >> 2)) * 1024 + gg * 8;
  bf16_t* lA = At + w * (WM / 2) * 512;
  bf16_t* lB = Bt + w * 1024;
  const bf16_t* fA = At + (wrow * WM * 16 + lm) * 32;
  const bf16_t* fB = Bt + (wcol * 64 + lm) * 32;
#pragma unroll
  for (int t2 = 0; t2 < WM / 2; ++t2) gl_lds16(gA + (size_t)t2 * 16384, lA + t2 * 512);
#pragma unroll
  for (int t2 = 0; t2 < 2; ++t2)      gl_lds16(gB + (size_t)t2 * 16384, lB + t2 * 512);
  __syncthreads();
  int p = 0;
  for (int k0 = 0; k0 < 1024; k0 += 32) {
    int pn = p ^ 1;
    if (k0 < 992) {
#pragma unroll
      for (int t2 = 0; t2 < WM / 2; ++t2)
        gl_lds16(gA + (size_t)t2 * 16384 + k0 + 32, lA + pn * ASZ + t2 * 512);
#pragma unroll
      for (int t2 = 0; t2 < 2; ++t2)
        gl_lds16(gB + (size_t)t2 * 16384 + k0 + 32, lB + pn * BSZ + t2 * 512);
    }
    bf16x8 af[WM], bfm[4];
#pragma unroll
    for (int it = 0; it < WM; ++it)
      af[it] = *(const bf16x8*)(fA + p * ASZ + it * 512 + ((q ^ rsw) << 3));
#pragma unroll
    for (int jt = 0; jt < 4; ++jt)
      bfm[jt] = *(const bf16x8*)(fB + p * BSZ + jt * 512 + ((q ^ rsw) << 3));
#pragma unroll
    for (int it = 0; it < WM; ++it)
#pragma unroll
      for (int jt = 0; jt < 4; ++jt)
        acc[it][jt] = mfma32(af[it], bfm[jt], acc[it][jt]);
    __syncthreads();
    p = pn;
  }
}

// ---------------- K1: q GEMM -> A_s = [(q+u)*SCALE | shift((q+v))*SCALE] ----------------
__global__ __launch_bounds__(256) void k1_q(const bf16_t* __restrict__ hb,
                                            const bf16_t* __restrict__ Wqb,
                                            const float* __restrict__ u,
                                            const float* __restrict__ v,
                                            bf16_t* __restrict__ As) {
  __shared__ union { struct { bf16_t At[4096]; bf16_t Bt[8192]; } m; float Tt[4][272]; } sm;
  int blk = blockIdx.x;
  int r0 = (blk >> 3) * 64, c0 = (blk & 7) * 128;
  int b = r0 >> 10;
  const bf16_t* Axv = hb + ((size_t)(b + 1) << 20);
  f32x4 acc[2][4] = {};
  gemm_core<2>(Axv, Wqb, r0, c0, sm.m.At, sm.m.Bt, acc);
  const int tid = threadIdx.x, w = tid >> 6, l = tid & 63;
  const int lm = l & 15, q = l >> 4;
  const int wrow = w >> 1, wcol = w & 1;
  float* Tw = sm.Tt[w];
  int h = (c0 + wcol * 64) >> 6;
#pragma unroll
  for (int it = 0; it < 2; ++it) {
#pragma unroll
    for (int jt = 0; jt < 4; ++jt) {
#pragma unroll
      for (int r = 0; r < 4; ++r) Tw[(q * 4 + r) * 17 + lm] = acc[it][jt][r];
      __builtin_amdgcn_wave_barrier();
      int row = r0 + wrow * 32 + it * 16 + lm;
      int ii = row & 1023;
      int cbase = c0 + wcol * 64 + jt * 16 + q * 4;
      int d0 = cbase & 63;
      f32x4 u4 = *(const f32x4*)(u + cbase);
      f32x4 v4 = *(const f32x4*)(v + cbase);
      f32x4 tv;
#pragma unroll
      for (int e = 0; e < 4; ++e) tv[e] = Tw[lm * 17 + q * 4 + e];
      bf16x4 oc, op;
#pragma unroll
      for (int e = 0; e < 4; ++e) {
        oc[e] = (bf16_t)((tv[e] + u4[e]) * SCALE_A);
        op[e] = (bf16_t)((tv[e] + v4[e]) * SCALE_A);
      }
      *(bf16x4*)(As + (((size_t)(b * 16 + h)) * CUR + ii) * 128 + d0) = oc;
      if (b == 0) {
        if (ii >= 1)
          *(bf16x4*)(As + (((size_t)h) * CUR + (ii - 1)) * 128 + 64 + d0) = op;
        if (ii == 1023) {
          bf16x4 z = {};
          *(bf16x4*)(As + (((size_t)h) * CUR + 1023) * 128 + 64 + d0) = z;
        }
      } else {
        *(bf16x4*)(As + (((size_t)(16 + h)) * CUR + ii) * 128 + 64 + d0) = op;
      }
      __builtin_amdgcn_wave_barrier();
    }
  }
}

// ---------------- K2: kv GEMM -> k (transposed epilogue) + vvT ----------------
__global__ __launch_bounds__(256) void k2_kv(const bf16_t* __restrict__ hb,
                                             const bf16_t* __restrict__ Wkvb,
                                             bf16_t* __restrict__ Bs,
                                             bf16_t* __restrict__ vvT) {
  __shared__ union { struct { bf16_t At[8192]; bf16_t Bt[8192]; } m; float Tt[4][272]; } sm;
  int blk = blockIdx.x;
  int xcd = blk & 7, t = blk >> 3;
  int r0 = (t & 31) * 128;
  int c0 = (xcd * 2 + (t >> 5)) * 128;
  f32x4 acc[4][4] = {};
  gemm_core<4>(hb, Wkvb, r0, c0, sm.m.At, sm.m.Bt, acc);
  const int tid = threadIdx.x, w = tid >> 6, l = tid & 63;
  const int lm = l & 15, q = l >> 4;
  const int wrow = w >> 1, wcol = w & 1;
  int b = r0 >> 11;
  if (c0 < 1024) {
    float* Tw = sm.Tt[w];
    int h = (c0 + wcol * 64) >> 6;
#pragma unroll
    for (int it = 0; it < 4; ++it) {
#pragma unroll
      for (int jt = 0; jt < 4; ++jt) {
#pragma unroll
        for (int r = 0; r < 4; ++r) Tw[(q * 4 + r) * 17 + lm] = acc[it][jt][r];
        __builtin_amdgcn_wave_barrier();
        int j = (r0 + wrow * 64 + it * 16 + lm) & 2047;
        int d0 = jt * 16 + q * 4;
        bf16x4 o;
#pragma unroll
        for (int e = 0; e < 4; ++e) o[e] = (bf16_t)Tw[lm * 17 + q * 4 + e];
        *(bf16x4*)(Bs + (((size_t)(b * 16 + h)) * TT + j) * 128 + d0) = o;
        __builtin_amdgcn_wave_barrier();
      }
    }
  } else {
#pragma unroll
    for (int it = 0; it < 4; ++it) {
#pragma unroll
      for (int jt = 0; jt < 4; ++jt) {
        int c2 = c0 + wcol * 64 + jt * 16 + lm - 1024;
        int h = c2 >> 6, d = c2 & 63;
        int j = (r0 + wrow * 64 + it * 16 + q * 4) & 2047;
        bf16x4 o;
#pragma unroll
        for (int r = 0; r < 4; ++r) o[r] = (bf16_t)acc[it][jt][r];
        *(bf16x4*)(vvT + (((size_t)(b * 16 + h)) * 64 + d) * TT + j) = o;
      }
    }
  }
}

// ---------------- K3: partial col-sums over i-chunk: Lp[ich][bh][j] = sum exp2(s) ----------------
// grid 1024 = 8 xcd x (16 jblk x 2 ich x 4 bh'). Fixed-max (scores bounded, fp32 safe).
__global__ __launch_bounds__(256) void k3_stats(const bf16_t* __restrict__ As,
                                                const bf16_t* __restrict__ Bs,
                                                float* __restrict__ Lp) {
  __shared__ bf16_t At[2 * 8192];
  const int tid = threadIdx.x, w = tid >> 6, l = tid & 63;
  const int lm = l & 15, q = l >> 4;
  const int gg  = (l & 3) ^ ((l >> 3) & 3);
  const int rsw = (lm >> 1) & 3;
  int blk = blockIdx.x;
  int xcd = blk & 7, t = blk >> 3;
  int jblk = t & 15, ich = (t >> 4) & 1, bh = xcd * 4 + (t >> 5);
  int j0 = jblk * 128;
  const bf16_t* bsrow = Bs + ((size_t)bh * TT + j0 + w * 32 + lm) * 128 + q * 8;
  bf16x8 bfr[2][4];
#pragma unroll
  for (int js = 0; js < 2; ++js)
#pragma unroll
    for (int kt = 0; kt < 4; ++kt)
      bfr[js][kt] = *(const bf16x8*)(bsrow + js * 2048 + kt * 32);
  const bf16_t* abase = As + (size_t)bh * CUR * 128 +
                        (size_t)(ich * 512 + (l >> 2)) * 128 + w * 32 + gg * 8;
  bf16_t* lA = At + w * 2048;
  const bf16_t* fA = At + lm * 32;
  float l0 = 0.f, l1 = 0.f;
#pragma unroll
  for (int t2 = 0; t2 < 4; ++t2)
    gl_lds16(abase + (size_t)t2 * 16 * 128, lA + t2 * 512);
  __syncthreads();
  int p = 0;
  for (int ib = 0; ib < 8; ++ib) {
    int pn = p ^ 1;
    if (ib < 7) {
#pragma unroll
      for (int t2 = 0; t2 < 4; ++t2)
        gl_lds16(abase + (size_t)((ib + 1) * 64 + t2 * 16) * 128, lA + pn * 8192 + t2 * 512);
    }
#pragma unroll
    for (int isub = 0; isub < 4; ++isub) {
      bf16x8 af[4];
#pragma unroll
      for (int kt = 0; kt < 4; ++kt)
        af[kt] = *(const bf16x8*)(fA + p * 8192 + kt * 2048 + isub * 512 + ((q ^ rsw) << 3));
      f32x4 s0 = {}, s1 = {};
#pragma unroll
      for (int kt = 0; kt < 4; ++kt) {
        s0 = mfma32(af[kt], bfr[0][kt], s0);
        s1 = mfma32(af[kt], bfr[1][kt], s1);
      }
      l0 += exp2fast(s0[0]) + exp2fast(s0[1]) + exp2fast(s0[2]) + exp2fast(s0[3]);
      l1 += exp2fast(s1[0]) + exp2fast(s1[1]) + exp2fast(s1[2]) + exp2fast(s1[3]);
    }
    __syncthreads();
    p = pn;
  }
#pragma unroll
  for (int off = 16; off <= 32; off <<= 1) {
    l0 += __shfl_xor(l0, off, 64);
    l1 += __shfl_xor(l1, off, 64);
  }
  if (l < 16) {
    float* lp = Lp + (size_t)ich * 65536 + (size_t)bh * TT + j0 + w * 32;
    lp[l]      = l0;
    lp[16 + l] = l1;
  }
}

// ---------------- K3r: LL = log2(Lp0 + Lp1) ----------------
__global__ __launch_bounds__(256) void k3_comb(const float* __restrict__ Lp,
                                               float* __restrict__ LL) {
  int t = blockIdx.x * 256 + threadIdx.x;   // 16384 threads x 4
  f32x4 a = *(const f32x4*)(Lp + (size_t)t * 4);
  f32x4 b = *(const f32x4*)(Lp + 65536 + (size_t)t * 4);
  f32x4 o;
#pragma unroll
  for (int e = 0; e < 4; ++e) o[e] = log2fast(a[e] + b[e]);
  *(f32x4*)(LL + (size_t)t * 4) = o;
}

// ---------------- K4: partial[i,d] over j-chunk (4-way) ----------------
// grid 1024 = 8 xcd x (8 iblk x 16 pl); pl -> (bh', jch). dbuf, swizzled.
__global__ __launch_bounds__(256) void k4_attnv(const bf16_t* __restrict__ As,
                                                const bf16_t* __restrict__ Bs,
                                                const bf16_t* __restrict__ vvT,
                                                const float* __restrict__ LL,
                                                float* __restrict__ Pp) {
  __shared__ union {
    struct { bf16_t Bt[2 * 8192]; bf16_t Vt[2 * 4096]; } m;
    float Tt[4][1088];
  } sm;
  int blk = blockIdx.x;
  int xcd = blk & 7, tb = blk >> 3;
  int iblk = tb & 7, pl = tb >> 3;
  int bh = xcd * 4 + (pl >> 2), jch = pl & 3;
  int b = bh >> 4, h = bh & 15;
  int i0 = iblk * 128;
  int jbase = jch * 512;
  const int tid = threadIdx.x, w = tid >> 6, l = tid & 63;
  const int lm = l & 15, q = l >> 4;
  const int gg  = (l & 3) ^ ((l >> 3) & 3);
  const int rsw = (lm >> 1) & 3;
  const bf16_t* ar = As + (size_t)bh * CUR * 128 + (size_t)(i0 + w * 32 + lm) * 128 + q * 8;
  bf16x8 bi[2][4];
#pragma unroll
  for (int is = 0; is < 2; ++is)
#pragma unroll
    for (int kt = 0; kt < 4; ++kt)
      bi[is][kt] = *(const bf16x8*)(ar + is * 2048 + kt * 32);
  const bf16_t* bbase = Bs + ((size_t)bh * TT + jbase) * 128 + (size_t)(l >> 2) * 128 + w * 32 + gg * 8;
  int inst0 = w * 2, inst1 = w * 2 + 1;
  const bf16_t* vsrc0 = vvT + ((size_t)bh * 64 + (inst0 & 3) * 16 + (l >> 2)) * TT + jbase +
                        (inst0 >> 2) * 32 + gg * 8;
  const bf16_t* vsrc1 = vvT + ((size_t)bh * 64 + (inst1 & 3) * 16 + (l >> 2)) * TT + jbase +
                        (inst1 >> 2) * 32 + gg * 8;
  bf16_t* vdst0 = sm.m.Vt + (inst0 >> 2) * 2048 + (inst0 & 3) * 512;
  bf16_t* vdst1 = sm.m.Vt + (inst1 >> 2) * 2048 + (inst1 & 3) * 512;
  bf16_t* lB = sm.m.Bt + w * 2048;
  const float* llb = LL + (size_t)bh * TT + jbase;
  f32x4 acc0[4] = {}, acc1[4] = {};
#pragma unroll
  for (int t2 = 0; t2 < 4; ++t2)
    gl_lds16(bbase + (size_t)t2 * 16 * 128, lB + t2 * 512);
  gl_lds16(vsrc0, vdst0);
  gl_lds16(vsrc1, vdst1);
  __syncthreads();
  int p = 0;
  for (int jb = 0; jb < 8; ++jb) {
    int pn = p ^ 1;
    if (jb < 7) {
      const bf16_t* bs2 = bbase + (size_t)(jb + 1) * 64 * 128;
#pragma unroll
      for (int t2 = 0; t2 < 4; ++t2)
        gl_lds16(bs2 + (size_t)t2 * 16 * 128, lB + pn * 8192 + t2 * 512);
      gl_lds16(vsrc0 + (jb + 1) * 64, vdst0 + pn * 4096);
      gl_lds16(vsrc1 + (jb + 1) * 64, vdst1 + pn * 4096);
    }
    const bf16_t* fB = sm.m.Bt + p * 8192 + lm * 32;
    const bf16_t* vf = sm.m.Vt + p * 4096 + lm * 32;
#pragma unroll
    for (int js = 0; js < 4; ++js) {
      bf16x8 af[4];
#pragma unroll
      for (int kt = 0; kt < 4; ++kt)
        af[kt] = *(const bf16x8*)(fB + kt * 2048 + js * 512 + ((q ^ rsw) << 3));
      f32x4 s0 = {}, s1 = {};
#pragma unroll
      for (int kt = 0; kt < 4; ++kt) {
        s0 = mfma32(af[kt], bi[0][kt], s0);
        s1 = mfma32(af[kt], bi[1][kt], s1);
      }
      f32x4 ll = *(const f32x4*)(llb + jb * 64 + js * 16 + q * 4);
      bf16x4 p0, p1;
#pragma unroll
      for (int e = 0; e < 4; ++e) {
        p0[e] = (bf16_t)exp2fast(s0[e] - ll[e]);
        p1[e] = (bf16_t)exp2fast(s1[e] - ll[e]);
      }
      int vg = ((js & 1) << 1) | (q >> 1);
      const bf16_t* vfa = vf + (js >> 1) * 2048 + ((vg ^ rsw) << 3) + ((q & 1) << 2);
#pragma unroll
      for (int dt = 0; dt < 4; ++dt) {
        bf16x4 a2 = *(const bf16x4*)(vfa + dt * 512);
        acc0[dt] = mfma16(a2, p0, acc0[dt]);
        acc1[dt] = mfma16(a2, p1, acc1[dt]);
      }
    }
    __syncthreads();
    p = pn;
  }
  float* Tw = sm.Tt[w];
  float* pout = Pp + ((size_t)jch << 21);
  int ir = l >> 2, dc = (l & 3) * 16;
#pragma unroll
  for (int is = 0; is < 2; ++is) {
#pragma unroll
    for (int dt = 0; dt < 4; ++dt) {
      f32x4 a = is ? acc1[dt] : acc0[dt];
#pragma unroll
      for (int r = 0; r < 4; ++r) Tw[(dt * 16 + q * 4 + r) * 17 + lm] = a[r];
    }
    __builtin_amdgcn_wave_barrier();
    int i = i0 + w * 32 + is * 16 + ir;
    float* orow = pout + ((size_t)(b * CUR + i)) * DM + h * 64 + dc;
#pragma unroll
    for (int e4 = 0; e4 < 4; ++e4) {
      f32x4 o;
#pragma unroll
      for (int e = 0; e < 4; ++e) o[e] = Tw[(dc + e4 * 4 + e) * 17 + ir];
      *(f32x4*)(orow + e4 * 4) = o;
    }
    __builtin_amdgcn_wave_barrier();
  }
}

// ---------------- K4r: wbuf = bf16(P0+P1+P2+P3) ----------------
__global__ __launch_bounds__(256) void k4_reduce(const float* __restrict__ P,
                                                 bf16_t* __restrict__ wbuf) {
  int t = blockIdx.x * 256 + threadIdx.x;
  f32x4 a = *(const f32x4*)(P + (size_t)t * 4);
  f32x4 b = *(const f32x4*)(P + (1u << 21) + (size_t)t * 4);
  f32x4 c = *(const f32x4*)(P + (2u << 21) + (size_t)t * 4);
  f32x4 d = *(const f32x4*)(P + (3u << 21) + (size_t)t * 4);
  bf16x4 o;
#pragma unroll
  for (int e = 0; e < 4; ++e) o[e] = (bf16_t)((a[e] + b[e]) + (c[e] + d[e]));
  *(bf16x4*)(wbuf + (size_t)t * 4) = o;
}

// ---------------- K5: y = x + w @ Wfc^T + bfc (transposed epilogue) ----------------
__global__ __launch_bounds__(256) void k5_fc(const bf16_t* __restrict__ wb,
                                             const bf16_t* __restrict__ Wfcb,
                                             const float* __restrict__ x,
                                             const float* __restrict__ bfc,
                                             float* __restrict__ y) {
  __shared__ union { struct { bf16_t At[4096]; bf16_t Bt[8192]; } m; float Tt[4][272]; } sm;
  int blk = blockIdx.x;
  int r0 = (blk >> 3) * 64, c0 = (blk & 7) * 128;
  f32x4 acc[2][4] = {};
  gemm_core<2>(wb, Wfcb, r0, c0, sm.m.At, sm.m.Bt, acc);
  const int tid = threadIdx.x, w = tid >> 6, l = tid & 63;
  const int lm = l & 15, q = l >> 4;
  const int wrow = w >> 1, wcol = w & 1;
  float* Tw = sm.Tt[w];
#pragma unroll
  for (int it = 0; it < 2; ++it) {
#pragma unroll
    for (int jt = 0; jt < 4; ++jt) {
#pragma unroll
      for (int r = 0; r < 4; ++r) Tw[(q * 4 + r) * 17 + lm] = acc[it][jt][r];
      __builtin_amdgcn_wave_barrier();
      int row = r0 + wrow * 32 + it * 16 + lm;
      int cb = c0 + wcol * 64 + jt * 16 + q * 4;
      f32x4 xb4 = *(const f32x4*)(x + (size_t)row * DM + cb);
      f32x4 bf4 = *(const f32x4*)(bfc + cb);
      f32x4 o;
#pragma unroll
      for (int e = 0; e < 4; ++e) o[e] = Tw[lm * 17 + q * 4 + e] + xb4[e] + bf4[e];
      *(f32x4*)(y + (size_t)row * DM + cb) = o;
      __builtin_amdgcn_wave_barrier();
    }
  }
}

// ---------------- K6: LayerNorm ----------------
__global__ __launch_bounds__(256) void k6_ln(const float* __restrict__ y,
                                             const float* __restrict__ gamma,
                                             const float* __restrict__ beta,
                                             float* __restrict__ out) {
  int row = blockIdx.x, t = threadIdx.x;
  const float* yr = y + (size_t)row * DM;
  f32x4 v = *(const f32x4*)(yr + t * 4);
  float s = v[0] + v[1] + v[2] + v[3];
  float ss = v[0] * v[0] + v[1] * v[1] + v[2] * v[2] + v[3] * v[3];
#pragma unroll
  for (int off = 1; off < 64; off <<= 1) {
    s += __shfl_xor(s, off, 64);
    ss += __shfl_xor(ss, off, 64);
  }
  __shared__ float ps[4], pss[4];
  int wv = t >> 6, ln = t & 63;
  if (ln == 0) { ps[wv] = s; pss[wv] = ss; }
  __syncthreads();
  s = ps[0] + ps[1] + ps[2] + ps[3];
  ss = pss[0] + pss[1] + pss[2] + pss[3];
  float mu = s * (1.0f / DM);
  float var = ss * (1.0f / DM) - mu * mu;
  float rstd = rsqrtf(var + 1e-5f);
  f32x4 g = *(const f32x4*)(gamma + t * 4);
  f32x4 bb = *(const f32x4*)(beta + t * 4);
  f32x4 o;
#pragma unroll
  for (int e = 0; e < 4; ++e) o[e] = (v[e] - mu) * rstd * g[e] + bb[e];
  *(f32x4*)(out + (size_t)row * DM + t * 4) = o;
}

// ---------------- launch ----------------
extern "C" void kernel_launch(void* const* d_in, const int* in_sizes, int n_in,
                              void* d_out, int out_size, void* d_ws, size_t ws_size,
                              hipStream_t stream) {
  const float* x    = (const float*)d_in[0];
  const float* pos  = (const float*)d_in[1];
  const float* u    = (const float*)d_in[2];
  const float* v    = (const float*)d_in[3];
  const float* mem  = (const float*)d_in[5];
  const float* Wq   = (const float*)d_in[6];
  const float* Wkv  = (const float*)d_in[7];
  const float* Wfc  = (const float*)d_in[8];
  const float* bfc  = (const float*)d_in[9];
  const float* gam  = (const float*)d_in[10];
  const float* bet  = (const float*)d_in[11];
  float* out = (float*)d_out;

  char* ws = (char*)d_ws;
  const size_t MB = 1ull << 20;
  // Lifetime-overlapped layout (max 81 MB):
  bf16_t* hb   = (bf16_t*)(ws);              // 0-8    (prep -> k2)
  bf16_t* wqb  = (bf16_t*)(ws + 8 * MB);     // 8-10   (prep -> k1)
  bf16_t* wkvb = (bf16_t*)(ws + 10 * MB);    // 10-14  (prep -> k2)
  bf16_t* As   = (bf16_t*)(ws + 14 * MB);    // 14-22  (k1 -> k4)
  bf16_t* Bs   = (bf16_t*)(ws + 22 * MB);    // 22-38  (prep/k2 -> k4)
  bf16_t* vvT  = (bf16_t*)(ws + 38 * MB);    // 38-46  (k2 -> k4)
  bf16_t* wfcb = (bf16_t*)(ws + 46 * MB);    // 46-48  (prep -> k5)
  float*  LL   = (float*) (ws + 48 * MB);    // 256 KB (k3r -> k4)
  float*  Lp   = (float*) (ws + 48 * MB + 262144); // 512 KB (k3 -> k3r)
  float*  Pp   = (float*) (ws + 49 * MB);    // 49-81  (k4 -> k4r), 4 x 8 MB
  bf16_t* wbuf = (bf16_t*)(ws);              // 0-4    (k4r -> k5, hb dead)
  float*  y    = (float*) (ws + 4 * MB);     // 4-12   (k5 -> k6, hb/wqb dead)

  prep_kernel<<<12288, 256, 0, stream>>>(Wq, Wkv, Wfc, mem, x, pos,
                                         wqb, wkvb, wfcb, hb, Bs);
  k1_q<<<256, 256, 0, stream>>>(hb, wqb, u, v, As);
  k2_kv<<<512, 256, 0, stream>>>(hb, wkvb, Bs, vvT);

  k3_stats<<<1024, 256, 0, stream>>>(As, Bs, Lp);
  k3_comb<<<64, 256, 0, stream>>>(Lp, LL);
  k4_attnv<<<1024, 256, 0, stream>>>(As, Bs, vvT, LL, Pp);
  k4_reduce<<<2048, 256, 0, stream>>>(Pp, wbuf);

  k5_fc<<<256, 256, 0, stream>>>(wbuf, wfcb, x, bfc, y);
  k6_ln<<<2048, 256, 0, stream>>>(y, gam, bet, out);
}

// Round 6
// 244.054 us; speedup vs baseline: 2.8552x; 1.0105x over previous
//
#include <hip/hip_runtime.h>

#define DM   1024
#define CUR  1024
#define TT   2048

typedef float  f32x4  __attribute__((ext_vector_type(4)));
typedef __bf16 bf16_t;
typedef __bf16 bf16x8 __attribute__((ext_vector_type(8)));
typedef __bf16 bf16x4 __attribute__((ext_vector_type(4)));
typedef short  s16x4  __attribute__((ext_vector_type(4)));

#define SCALE_A 0.18033688f   // 0.125 * log2(e): scores live in log2 domain

static __device__ __forceinline__ float exp2fast(float x) { return __builtin_amdgcn_exp2f(x); }

static __device__ __forceinline__ f32x4 mfma32(bf16x8 a, bf16x8 b, f32x4 c) {
  return __builtin_amdgcn_mfma_f32_16x16x32_bf16(a, b, c, 0, 0, 0);
}
static __device__ __forceinline__ f32x4 mfma16(bf16x4 a, bf16x4 b, f32x4 c) {
  return __builtin_amdgcn_mfma_f32_16x16x16bf16_1k(
      __builtin_bit_cast(s16x4, a), __builtin_bit_cast(s16x4, b), c, 0, 0, 0);
}
static __device__ __forceinline__ void gl_lds16(const bf16_t* g, bf16_t* l) {
  __builtin_amdgcn_global_load_lds(
      (const __attribute__((address_space(1))) void*)g,
      (__attribute__((address_space(3))) void*)l, 16, 0, 0);
}

// ---------------- fused prep: weight cvt + h concat cvt + pe fill ----------------
__global__ __launch_bounds__(256) void prep_kernel(const float* __restrict__ Wq,
                                                   const float* __restrict__ Wkv,
                                                   const float* __restrict__ Wfc,
                                                   const float* __restrict__ mem,
                                                   const float* __restrict__ x,
                                                   const float* __restrict__ pos,
                                                   bf16_t* __restrict__ wqb,
                                                   bf16_t* __restrict__ wkvb,
                                                   bf16_t* __restrict__ wfcb,
                                                   bf16_t* __restrict__ hb,
                                                   bf16_t* __restrict__ Bs) {
  int t = blockIdx.x * 256 + threadIdx.x;   // [0, 3M)
  if (t < (1 << 20)) {
    const float* src; bf16_t* dst; int off;
    if (t < 262144)      { src = Wq;  dst = wqb;  off = t; }
    else if (t < 786432) { src = Wkv; dst = wkvb; off = t - 262144; }
    else                 { src = Wfc; dst = wfcb; off = t - 786432; }
    f32x4 v = *(const f32x4*)(src + (size_t)off * 4);
    bf16x4 o;
    o[0] = (bf16_t)v[0]; o[1] = (bf16_t)v[1]; o[2] = (bf16_t)v[2]; o[3] = (bf16_t)v[3];
    *(bf16x4*)(dst + (size_t)off * 4) = o;
  } else if (t < (2 << 20)) {
    int th = t - (1 << 20);
    int idx = th << 2;
    int b   = idx >> 21;
    int rem = idx & ((1 << 21) - 1);
    int tt  = rem >> 10;
    int c   = rem & 1023;
    const float* s = (tt < 1024)
        ? (mem + ((size_t)b * 1024 + tt) * DM + c)
        : (x   + ((size_t)b * 1024 + (tt - 1024)) * DM + c);
    f32x4 v = *(const f32x4*)s;
    bf16x4 o;
    o[0] = (bf16_t)v[0]; o[1] = (bf16_t)v[1]; o[2] = (bf16_t)v[2]; o[3] = (bf16_t)v[3];
    *(bf16x4*)(hb + idx) = o;
  } else {
    int tp = t - (2 << 20);
    int d4 = (tp & 15) << 2;
    int j  = (tp >> 4) & 2047;
    int bh = tp >> 15;
    int h  = bh & 15;
    f32x4 v = *(const f32x4*)(pos + (size_t)j * DM + h * 64 + d4);
    bf16x4 o;
    o[0] = (bf16_t)v[0]; o[1] = (bf16_t)v[1]; o[2] = (bf16_t)v[2]; o[3] = (bf16_t)v[3];
    *(bf16x4*)(Bs + ((size_t)bh * TT + j) * 128 + 64 + d4) = o;
  }
}

// ---------------- LDS-staged GEMM core, double-buffered, XOR-swizzled ----------------
template<int WM>
__device__ __forceinline__ void gemm_core(const bf16_t* __restrict__ A,
                                          const bf16_t* __restrict__ B,
                                          int r0, int c0,
                                          bf16_t* At, bf16_t* Bt,
                                          f32x4 (&acc)[WM][4]) {
  const int ASZ = WM * 1024;
  const int BSZ = 4096;
  const int tid = threadIdx.x, w = tid >> 6, l = tid & 63;
  const int lm = l & 15, q = l >> 4;
  const int wrow = w >> 1, wcol = w & 1;
  const int gg  = (l & 3) ^ ((l >> 3) & 3);
  const int rsw = (lm >> 1) & 3;
  const bf16_t* gA = A + (size_t)(r0 + w * (WM / 2) * 16 + (l >> 2)) * 1024 + gg * 8;
  const bf16_t* gB = B + (size_t)(c0 + w * 32 + (l >> 2)) * 1024 + gg * 8;
  bf16_t* lA = At + w * (WM / 2) * 512;
  bf16_t* lB = Bt + w * 1024;
  const bf16_t* fA = At + (wrow * WM * 16 + lm) * 32;
  const bf16_t* fB = Bt + (wcol * 64 + lm) * 32;
#pragma unroll
  for (int t2 = 0; t2 < WM / 2; ++t2) gl_lds16(gA + (size_t)t2 * 16384, lA + t2 * 512);
#pragma unroll
  for (int t2 = 0; t2 < 2; ++t2)      gl_lds16(gB + (size_t)t2 * 16384, lB + t2 * 512);
  __syncthreads();
  int p = 0;
  for (int k0 = 0; k0 < 1024; k0 += 32) {
    int pn = p ^ 1;
    if (k0 < 992) {
#pragma unroll
      for (int t2 = 0; t2 < WM / 2; ++t2)
        gl_lds16(gA + (size_t)t2 * 16384 + k0 + 32, lA + pn * ASZ + t2 * 512);
#pragma unroll
      for (int t2 = 0; t2 < 2; ++t2)
        gl_lds16(gB + (size_t)t2 * 16384 + k0 + 32, lB + pn * BSZ + t2 * 512);
    }
    bf16x8 af[WM], bfm[4];
#pragma unroll
    for (int it = 0; it < WM; ++it)
      af[it] = *(const bf16x8*)(fA + p * ASZ + it * 512 + ((q ^ rsw) << 3));
#pragma unroll
    for (int jt = 0; jt < 4; ++jt)
      bfm[jt] = *(const bf16x8*)(fB + p * BSZ + jt * 512 + ((q ^ rsw) << 3));
#pragma unroll
    for (int it = 0; it < WM; ++it)
#pragma unroll
      for (int jt = 0; jt < 4; ++jt)
        acc[it][jt] = mfma32(af[it], bfm[jt], acc[it][jt]);
    __syncthreads();
    p = pn;
  }
}

// ---------------- K1: q GEMM -> A_s = [(q+u)*SCALE | shift((q+v))*SCALE] ----------------
__global__ __launch_bounds__(256) void k1_q(const bf16_t* __restrict__ hb,
                                            const bf16_t* __restrict__ Wqb,
                                            const float* __restrict__ u,
                                            const float* __restrict__ v,
                                            bf16_t* __restrict__ As) {
  __shared__ union { struct { bf16_t At[4096]; bf16_t Bt[8192]; } m; float Tt[4][272]; } sm;
  int blk = blockIdx.x;
  int r0 = (blk >> 3) * 64, c0 = (blk & 7) * 128;
  int b = r0 >> 10;
  const bf16_t* Axv = hb + ((size_t)(b + 1) << 20);
  f32x4 acc[2][4] = {};
  gemm_core<2>(Axv, Wqb, r0, c0, sm.m.At, sm.m.Bt, acc);
  const int tid = threadIdx.x, w = tid >> 6, l = tid & 63;
  const int lm = l & 15, q = l >> 4;
  const int wrow = w >> 1, wcol = w & 1;
  float* Tw = sm.Tt[w];
  int h = (c0 + wcol * 64) >> 6;
#pragma unroll
  for (int it = 0; it < 2; ++it) {
#pragma unroll
    for (int jt = 0; jt < 4; ++jt) {
#pragma unroll
      for (int r = 0; r < 4; ++r) Tw[(q * 4 + r) * 17 + lm] = acc[it][jt][r];
      __builtin_amdgcn_wave_barrier();
      int row = r0 + wrow * 32 + it * 16 + lm;
      int ii = row & 1023;
      int cbase = c0 + wcol * 64 + jt * 16 + q * 4;
      int d0 = cbase & 63;
      f32x4 u4 = *(const f32x4*)(u + cbase);
      f32x4 v4 = *(const f32x4*)(v + cbase);
      f32x4 tv;
#pragma unroll
      for (int e = 0; e < 4; ++e) tv[e] = Tw[lm * 17 + q * 4 + e];
      bf16x4 oc, op;
#pragma unroll
      for (int e = 0; e < 4; ++e) {
        oc[e] = (bf16_t)((tv[e] + u4[e]) * SCALE_A);
        op[e] = (bf16_t)((tv[e] + v4[e]) * SCALE_A);
      }
      *(bf16x4*)(As + (((size_t)(b * 16 + h)) * CUR + ii) * 128 + d0) = oc;
      if (b == 0) {
        if (ii >= 1)
          *(bf16x4*)(As + (((size_t)h) * CUR + (ii - 1)) * 128 + 64 + d0) = op;
        if (ii == 1023) {
          bf16x4 z = {};
          *(bf16x4*)(As + (((size_t)h) * CUR + 1023) * 128 + 64 + d0) = z;
        }
      } else {
        *(bf16x4*)(As + (((size_t)(16 + h)) * CUR + ii) * 128 + 64 + d0) = op;
      }
      __builtin_amdgcn_wave_barrier();
    }
  }
}

// ---------------- K2: kv GEMM -> k (transposed epilogue) + vvT ----------------
__global__ __launch_bounds__(256) void k2_kv(const bf16_t* __restrict__ hb,
                                             const bf16_t* __restrict__ Wkvb,
                                             bf16_t* __restrict__ Bs,
                                             bf16_t* __restrict__ vvT) {
  __shared__ union { struct { bf16_t At[8192]; bf16_t Bt[8192]; } m; float Tt[4][272]; } sm;
  int blk = blockIdx.x;
  int xcd = blk & 7, t = blk >> 3;
  int r0 = (t & 31) * 128;
  int c0 = (xcd * 2 + (t >> 5)) * 128;
  f32x4 acc[4][4] = {};
  gemm_core<4>(hb, Wkvb, r0, c0, sm.m.At, sm.m.Bt, acc);
  const int tid = threadIdx.x, w = tid >> 6, l = tid & 63;
  const int lm = l & 15, q = l >> 4;
  const int wrow = w >> 1, wcol = w & 1;
  int b = r0 >> 11;
  if (c0 < 1024) {
    float* Tw = sm.Tt[w];
    int h = (c0 + wcol * 64) >> 6;
#pragma unroll
    for (int it = 0; it < 4; ++it) {
#pragma unroll
      for (int jt = 0; jt < 4; ++jt) {
#pragma unroll
        for (int r = 0; r < 4; ++r) Tw[(q * 4 + r) * 17 + lm] = acc[it][jt][r];
        __builtin_amdgcn_wave_barrier();
        int j = (r0 + wrow * 64 + it * 16 + lm) & 2047;
        int d0 = jt * 16 + q * 4;
        bf16x4 o;
#pragma unroll
        for (int e = 0; e < 4; ++e) o[e] = (bf16_t)Tw[lm * 17 + q * 4 + e];
        *(bf16x4*)(Bs + (((size_t)(b * 16 + h)) * TT + j) * 128 + d0) = o;
        __builtin_amdgcn_wave_barrier();
      }
    }
  } else {
#pragma unroll
    for (int it = 0; it < 4; ++it) {
#pragma unroll
      for (int jt = 0; jt < 4; ++jt) {
        int c2 = c0 + wcol * 64 + jt * 16 + lm - 1024;
        int h = c2 >> 6, d = c2 & 63;
        int j = (r0 + wrow * 64 + it * 16 + q * 4) & 2047;
        bf16x4 o;
#pragma unroll
        for (int r = 0; r < 4; ++r) o[r] = (bf16_t)acc[it][jt][r];
        *(bf16x4*)(vvT + (((size_t)(b * 16 + h)) * 64 + d) * TT + j) = o;
      }
    }
  }
}

// ---------------- K3: partial col-sums over i-chunk: Lp[ich][bh][j] = sum exp2(s) ----------------
// grid 512 = 8 xcd x (8 jblk x 2 ich x 4 bh'). j-width 64/wave (bfr[4][4]).
__global__ __launch_bounds__(256) void k3_stats(const bf16_t* __restrict__ As,
                                                const bf16_t* __restrict__ Bs,
                                                float* __restrict__ Lp) {
  __shared__ bf16_t At[2 * 8192];
  const int tid = threadIdx.x, w = tid >> 6, l = tid & 63;
  const int lm = l & 15, q = l >> 4;
  const int gg  = (l & 3) ^ ((l >> 3) & 3);
  const int rsw = (lm >> 1) & 3;
  int blk = blockIdx.x;
  int xcd = blk & 7, t = blk >> 3;
  int jblk = t & 7, ich = (t >> 3) & 1, bh = xcd * 4 + (t >> 4);
  int j0 = jblk * 256 + w * 64;
  const bf16_t* bsrow = Bs + ((size_t)bh * TT + j0 + lm) * 128 + q * 8;
  bf16x8 bfr[4][4];
#pragma unroll
  for (int js = 0; js < 4; ++js)
#pragma unroll
    for (int kt = 0; kt < 4; ++kt)
      bfr[js][kt] = *(const bf16x8*)(bsrow + js * 2048 + kt * 32);
  const bf16_t* abase = As + (size_t)bh * CUR * 128 +
                        (size_t)(ich * 512 + (l >> 2)) * 128 + w * 32 + gg * 8;
  bf16_t* lA = At + w * 2048;
  const bf16_t* fA = At + lm * 32;
  float lacc[4] = {0.f, 0.f, 0.f, 0.f};
#pragma unroll
  for (int t2 = 0; t2 < 4; ++t2)
    gl_lds16(abase + (size_t)t2 * 16 * 128, lA + t2 * 512);
  __syncthreads();
  int p = 0;
  for (int ib = 0; ib < 8; ++ib) {
    int pn = p ^ 1;
    if (ib < 7) {
#pragma unroll
      for (int t2 = 0; t2 < 4; ++t2)
        gl_lds16(abase + (size_t)((ib + 1) * 64 + t2 * 16) * 128, lA + pn * 8192 + t2 * 512);
    }
#pragma unroll
    for (int isub = 0; isub < 4; ++isub) {
      bf16x8 af[4];
#pragma unroll
      for (int kt = 0; kt < 4; ++kt)
        af[kt] = *(const bf16x8*)(fA + p * 8192 + kt * 2048 + isub * 512 + ((q ^ rsw) << 3));
      f32x4 s[4] = {};
#pragma unroll
      for (int js = 0; js < 4; ++js)
#pragma unroll
        for (int kt = 0; kt < 4; ++kt)
          s[js] = mfma32(af[kt], bfr[js][kt], s[js]);
#pragma unroll
      for (int js = 0; js < 4; ++js)
        lacc[js] += (exp2fast(s[js][0]) + exp2fast(s[js][1])) +
                    (exp2fast(s[js][2]) + exp2fast(s[js][3]));
    }
    __syncthreads();
    p = pn;
  }
#pragma unroll
  for (int js = 0; js < 4; ++js) {
#pragma unroll
    for (int off = 16; off <= 32; off <<= 1)
      lacc[js] += __shfl_xor(lacc[js], off, 64);
  }
  if (l < 16) {
    float* lp = Lp + (size_t)ich * 65536 + (size_t)bh * TT + j0;
#pragma unroll
    for (int js = 0; js < 4; ++js) lp[js * 16 + l] = lacc[js];
  }
}

// ---------------- vscale: vvT[bh][d][j] *= rcp(Lp0[j]+Lp1[j]) (in place) ----------------
__global__ __launch_bounds__(256) void vscale(const float* __restrict__ Lp,
                                              bf16_t* __restrict__ vvT) {
  int bh = blockIdx.x >> 3, jc = blockIdx.x & 7;
  int tid = threadIdx.x;
  int jj = jc * 256 + (tid & 63) * 4;
  int dg = tid >> 6;
  const float* lp = Lp + (size_t)bh * TT + jj;
  f32x4 a = *(const f32x4*)lp;
  f32x4 b = *(const f32x4*)(lp + 65536);
  f32x4 rl;
#pragma unroll
  for (int e = 0; e < 4; ++e) rl[e] = __builtin_amdgcn_rcpf(a[e] + b[e]);
  bf16_t* vb = vvT + ((size_t)bh * 64 + dg * 16) * TT + jj;
#pragma unroll
  for (int dd = 0; dd < 16; ++dd) {
    bf16x4 vv = *(const bf16x4*)(vb + (size_t)dd * TT);
    bf16x4 o;
#pragma unroll
    for (int e = 0; e < 4; ++e) o[e] = (bf16_t)((float)vv[e] * rl[e]);
    *(bf16x4*)(vb + (size_t)dd * TT) = o;
  }
}

// ---------------- K4: partial[i,d] over j-chunk; i-width 64/wave ----------------
// grid 512 = 8 xcd x (4 iblk x 4 bh' x 4 jch). dbuf, swizzled. V pre-normalized.
__global__ __launch_bounds__(256, 2) void k4_attnv(const bf16_t* __restrict__ As,
                                                   const bf16_t* __restrict__ Bs,
                                                   const bf16_t* __restrict__ vvT,
                                                   float* __restrict__ Pp) {
  __shared__ union {
    struct { bf16_t Bt[2 * 8192]; bf16_t Vt[2 * 4096]; } m;
    float Tt[4][1088];
  } sm;
  int blk = blockIdx.x;
  int xcd = blk & 7, tb = blk >> 3;
  int iblk = tb & 3, pl = tb >> 2;       // pl: bh'(4) x jch(4)
  int bh = xcd * 4 + (pl >> 2), jch = pl & 3;
  int b = bh >> 4, h = bh & 15;
  int i0 = iblk * 256;
  int jbase = jch * 512;
  const int tid = threadIdx.x, w = tid >> 6, l = tid & 63;
  const int lm = l & 15, q = l >> 4;
  const int gg  = (l & 3) ^ ((l >> 3) & 3);
  const int rsw = (lm >> 1) & 3;
  // register i-frags: 4 i-subtiles of 16 (wave covers 64 i)
  const bf16_t* ar = As + (size_t)bh * CUR * 128 + (size_t)(i0 + w * 64 + lm) * 128 + q * 8;
  bf16x8 bi[4][4];
#pragma unroll
  for (int is = 0; is < 4; ++is)
#pragma unroll
    for (int kt = 0; kt < 4; ++kt)
      bi[is][kt] = *(const bf16x8*)(ar + is * 2048 + kt * 32);
  const bf16_t* bbase = Bs + ((size_t)bh * TT + jbase) * 128 + (size_t)(l >> 2) * 128 + w * 32 + gg * 8;
  int inst0 = w * 2, inst1 = w * 2 + 1;
  const bf16_t* vsrc0 = vvT + ((size_t)bh * 64 + (inst0 & 3) * 16 + (l >> 2)) * TT + jbase +
                        (inst0 >> 2) * 32 + gg * 8;
  const bf16_t* vsrc1 = vvT + ((size_t)bh * 64 + (inst1 & 3) * 16 + (l >> 2)) * TT + jbase +
                        (inst1 >> 2) * 32 + gg * 8;
  bf16_t* vdst0 = sm.m.Vt + (inst0 >> 2) * 2048 + (inst0 & 3) * 512;
  bf16_t* vdst1 = sm.m.Vt + (inst1 >> 2) * 2048 + (inst1 & 3) * 512;
  bf16_t* lB = sm.m.Bt + w * 2048;
  f32x4 acc[4][4] = {};
#pragma unroll
  for (int t2 = 0; t2 < 4; ++t2)
    gl_lds16(bbase + (size_t)t2 * 16 * 128, lB + t2 * 512);
  gl_lds16(vsrc0, vdst0);
  gl_lds16(vsrc1, vdst1);
  __syncthreads();
  int p = 0;
  for (int jb = 0; jb < 8; ++jb) {
    int pn = p ^ 1;
    if (jb < 7) {
      const bf16_t* bs2 = bbase + (size_t)(jb + 1) * 64 * 128;
#pragma unroll
      for (int t2 = 0; t2 < 4; ++t2)
        gl_lds16(bs2 + (size_t)t2 * 16 * 128, lB + pn * 8192 + t2 * 512);
      gl_lds16(vsrc0 + (jb + 1) * 64, vdst0 + pn * 4096);
      gl_lds16(vsrc1 + (jb + 1) * 64, vdst1 + pn * 4096);
    }
    const bf16_t* fB = sm.m.Bt + p * 8192 + lm * 32;
    const bf16_t* vf = sm.m.Vt + p * 4096 + lm * 32;
#pragma unroll
    for (int js = 0; js < 4; ++js) {
      bf16x8 af[4];
#pragma unroll
      for (int kt = 0; kt < 4; ++kt)
        af[kt] = *(const bf16x8*)(fB + kt * 2048 + js * 512 + ((q ^ rsw) << 3));
      f32x4 s[4] = {};
#pragma unroll
      for (int is = 0; is < 4; ++is)
#pragma unroll
        for (int kt = 0; kt < 4; ++kt)
          s[is] = mfma32(af[kt], bi[is][kt], s[is]);
      bf16x4 pp[4];
#pragma unroll
      for (int is = 0; is < 4; ++is)
#pragma unroll
        for (int e = 0; e < 4; ++e)
          pp[is][e] = (bf16_t)exp2fast(s[is][e]);
      int vg = ((js & 1) << 1) | (q >> 1);
      const bf16_t* vfa = vf + (js >> 1) * 2048 + ((vg ^ rsw) << 3) + ((q & 1) << 2);
#pragma unroll
      for (int dt = 0; dt < 4; ++dt) {
        bf16x4 a2 = *(const bf16x4*)(vfa + dt * 512);
#pragma unroll
        for (int is = 0; is < 4; ++is)
          acc[is][dt] = mfma16(a2, pp[is], acc[is][dt]);
      }
    }
    __syncthreads();
    p = pn;
  }
  // epilogue: per i-subtile transpose wT[64 d][16 i] -> rows, store fp32 partials
  float* Tw = sm.Tt[w];
  float* pout = Pp + ((size_t)jch << 21);
  int ir = l >> 2, dc = (l & 3) * 16;
#pragma unroll
  for (int is = 0; is < 4; ++is) {
#pragma unroll
    for (int dt = 0; dt < 4; ++dt) {
      f32x4 a = acc[is][dt];
#pragma unroll
      for (int r = 0; r < 4; ++r) Tw[(dt * 16 + q * 4 + r) * 17 + lm] = a[r];
    }
    __builtin_amdgcn_wave_barrier();
    int i = i0 + w * 64 + is * 16 + ir;
    float* orow = pout + ((size_t)(b * CUR + i)) * DM + h * 64 + dc;
#pragma unroll
    for (int e4 = 0; e4 < 4; ++e4) {
      f32x4 o;
#pragma unroll
      for (int e = 0; e < 4; ++e) o[e] = Tw[(dc + e4 * 4 + e) * 17 + ir];
      *(f32x4*)(orow + e4 * 4) = o;
    }
    __builtin_amdgcn_wave_barrier();
  }
}

// ---------------- K4r: wbuf = bf16(P0+P1+P2+P3) ----------------
__global__ __launch_bounds__(256) void k4_reduce(const float* __restrict__ P,
                                                 bf16_t* __restrict__ wbuf) {
  int t = blockIdx.x * 256 + threadIdx.x;
  f32x4 a = *(const f32x4*)(P + (size_t)t * 4);
  f32x4 b = *(const f32x4*)(P + (1u << 21) + (size_t)t * 4);
  f32x4 c = *(const f32x4*)(P + (2u << 21) + (size_t)t * 4);
  f32x4 d = *(const f32x4*)(P + (3u << 21) + (size_t)t * 4);
  bf16x4 o;
#pragma unroll
  for (int e = 0; e < 4; ++e) o[e] = (bf16_t)((a[e] + b[e]) + (c[e] + d[e]));
  *(bf16x4*)(wbuf + (size_t)t * 4) = o;
}

// ---------------- K5: y = x + w @ Wfc^T + bfc (transposed epilogue) ----------------
__global__ __launch_bounds__(256) void k5_fc(const bf16_t* __restrict__ wb,
                                             const bf16_t* __restrict__ Wfcb,
                                             const float* __restrict__ x,
                                             const float* __restrict__ bfc,
                                             float* __restrict__ y) {
  __shared__ union { struct { bf16_t At[4096]; bf16_t Bt[8192]; } m; float Tt[4][272]; } sm;
  int blk = blockIdx.x;
  int r0 = (blk >> 3) * 64, c0 = (blk & 7) * 128;
  f32x4 acc[2][4] = {};
  gemm_core<2>(wb, Wfcb, r0, c0, sm.m.At, sm.m.Bt, acc);
  const int tid = threadIdx.x, w = tid >> 6, l = tid & 63;
  const int lm = l & 15, q = l >> 4;
  const int wrow = w >> 1, wcol = w & 1;
  float* Tw = sm.Tt[w];
#pragma unroll
  for (int it = 0; it < 2; ++it) {
#pragma unroll
    for (int jt = 0; jt < 4; ++jt) {
#pragma unroll
      for (int r = 0; r < 4; ++r) Tw[(q * 4 + r) * 17 + lm] = acc[it][jt][r];
      __builtin_amdgcn_wave_barrier();
      int row = r0 + wrow * 32 + it * 16 + lm;
      int cb = c0 + wcol * 64 + jt * 16 + q * 4;
      f32x4 xb4 = *(const f32x4*)(x + (size_t)row * DM + cb);
      f32x4 bf4 = *(const f32x4*)(bfc + cb);
      f32x4 o;
#pragma unroll
      for (int e = 0; e < 4; ++e) o[e] = Tw[lm * 17 + q * 4 + e] + xb4[e] + bf4[e];
      *(f32x4*)(y + (size_t)row * DM + cb) = o;
      __builtin_amdgcn_wave_barrier();
    }
  }
}

// ---------------- K6: LayerNorm ----------------
__global__ __launch_bounds__(256) void k6_ln(const float* __restrict__ y,
                                             const float* __restrict__ gamma,
                                             const float* __restrict__ beta,
                                             float* __restrict__ out) {
  int row = blockIdx.x, t = threadIdx.x;
  const float* yr = y + (size_t)row * DM;
  f32x4 v = *(const f32x4*)(yr + t * 4);
  float s = v[0] + v[1] + v[2] + v[3];
  float ss = v[0] * v[0] + v[1] * v[1] + v[2] * v[2] + v[3] * v[3];
#pragma unroll
  for (int off = 1; off < 64; off <<= 1) {
    s += __shfl_xor(s, off, 64);
    ss += __shfl_xor(ss, off, 64);
  }
  __shared__ float ps[4], pss[4];
  int wv = t >> 6, ln = t & 63;
  if (ln == 0) { ps[wv] = s; pss[wv] = ss; }
  __syncthreads();
  s = ps[0] + ps[1] + ps[2] + ps[3];
  ss = pss[0] + pss[1] + pss[2] + pss[3];
  float mu = s * (1.0f / DM);
  float var = ss * (1.0f / DM) - mu * mu;
  float rstd = rsqrtf(var + 1e-5f);
  f32x4 g = *(const f32x4*)(gamma + t * 4);
  f32x4 bb = *(const f32x4*)(beta + t * 4);
  f32x4 o;
#pragma unroll
  for (int e = 0; e < 4; ++e) o[e] = (v[e] - mu) * rstd * g[e] + bb[e];
  *(f32x4*)(out + (size_t)row * DM + t * 4) = o;
}

// ---------------- launch ----------------
extern "C" void kernel_launch(void* const* d_in, const int* in_sizes, int n_in,
                              void* d_out, int out_size, void* d_ws, size_t ws_size,
                              hipStream_t stream) {
  const float* x    = (const float*)d_in[0];
  const float* pos  = (const float*)d_in[1];
  const float* u    = (const float*)d_in[2];
  const float* v    = (const float*)d_in[3];
  const float* mem  = (const float*)d_in[5];
  const float* Wq   = (const float*)d_in[6];
  const float* Wkv  = (const float*)d_in[7];
  const float* Wfc  = (const float*)d_in[8];
  const float* bfc  = (const float*)d_in[9];
  const float* gam  = (const float*)d_in[10];
  const float* bet  = (const float*)d_in[11];
  float* out = (float*)d_out;

  char* ws = (char*)d_ws;
  const size_t MB = 1ull << 20;
  bf16_t* hb   = (bf16_t*)(ws);              // 0-8    (prep -> k2)
  bf16_t* wqb  = (bf16_t*)(ws + 8 * MB);     // 8-10   (prep -> k1)
  bf16_t* wkvb = (bf16_t*)(ws + 10 * MB);    // 10-14  (prep -> k2)
  bf16_t* As   = (bf16_t*)(ws + 14 * MB);    // 14-22  (k1 -> k4)
  bf16_t* Bs   = (bf16_t*)(ws + 22 * MB);    // 22-38  (prep/k2 -> k4)
  bf16_t* vvT  = (bf16_t*)(ws + 38 * MB);    // 38-46  (k2 -> vscale -> k4)
  bf16_t* wfcb = (bf16_t*)(ws + 46 * MB);    // 46-48  (prep -> k5)
  float*  Lp   = (float*) (ws + 48 * MB);    // 512 KB (k3 -> vscale)
  float*  Pp   = (float*) (ws + 49 * MB);    // 49-81  (k4 -> k4r), 4 x 8 MB
  bf16_t* wbuf = (bf16_t*)(ws);              // 0-4    (k4r -> k5, hb dead)
  float*  y    = (float*) (ws + 4 * MB);     // 4-12   (k5 -> k6)

  prep_kernel<<<12288, 256, 0, stream>>>(Wq, Wkv, Wfc, mem, x, pos,
                                         wqb, wkvb, wfcb, hb, Bs);
  k1_q<<<256, 256, 0, stream>>>(hb, wqb, u, v, As);
  k2_kv<<<512, 256, 0, stream>>>(hb, wkvb, Bs, vvT);

  k3_stats<<<512, 256, 0, stream>>>(As, Bs, Lp);
  vscale<<<256, 256, 0, stream>>>(Lp, vvT);
  k4_attnv<<<512, 256, 0, stream>>>(As, Bs, vvT, Pp);
  k4_reduce<<<2048, 256, 0, stream>>>(Pp, wbuf);

  k5_fc<<<256, 256, 0, stream>>>(wbuf, wfcb, x, bfc, y);
  k6_ln<<<2048, 256, 0, stream>>>(y, gam, bet, out);
}

// Round 7
// 240.109 us; speedup vs baseline: 2.9022x; 1.0164x over previous
//
#include <hip/hip_runtime.h>

#define DM   1024
#define CUR  1024
#define TT   2048

typedef float  f32x4  __attribute__((ext_vector_type(4)));
typedef __bf16 bf16_t;
typedef __bf16 bf16x8 __attribute__((ext_vector_type(8)));
typedef __bf16 bf16x4 __attribute__((ext_vector_type(4)));
typedef short  s16x4  __attribute__((ext_vector_type(4)));

#define SCALE_A 0.18033688f   // 0.125 * log2(e): scores live in log2 domain

static __device__ __forceinline__ float exp2fast(float x) { return __builtin_amdgcn_exp2f(x); }

static __device__ __forceinline__ f32x4 mfma32(bf16x8 a, bf16x8 b, f32x4 c) {
  return __builtin_amdgcn_mfma_f32_16x16x32_bf16(a, b, c, 0, 0, 0);
}
static __device__ __forceinline__ f32x4 mfma16(bf16x4 a, bf16x4 b, f32x4 c) {
  return __builtin_amdgcn_mfma_f32_16x16x16bf16_1k(
      __builtin_bit_cast(s16x4, a), __builtin_bit_cast(s16x4, b), c, 0, 0, 0);
}
static __device__ __forceinline__ void gl_lds16(const bf16_t* g, bf16_t* l) {
  __builtin_amdgcn_global_load_lds(
      (const __attribute__((address_space(1))) void*)g,
      (__attribute__((address_space(3))) void*)l, 16, 0, 0);
}

// ---------------- fused prep: weight cvt + h concat cvt + pe fill ----------------
__global__ __launch_bounds__(256) void prep_kernel(const float* __restrict__ Wq,
                                                   const float* __restrict__ Wkv,
                                                   const float* __restrict__ Wfc,
                                                   const float* __restrict__ mem,
                                                   const float* __restrict__ x,
                                                   const float* __restrict__ pos,
                                                   bf16_t* __restrict__ wqb,
                                                   bf16_t* __restrict__ wkvb,
                                                   bf16_t* __restrict__ wfcb,
                                                   bf16_t* __restrict__ hb,
                                                   bf16_t* __restrict__ Bs) {
  int t = blockIdx.x * 256 + threadIdx.x;   // [0, 3M)
  if (t < (1 << 20)) {
    const float* src; bf16_t* dst; int off;
    if (t < 262144)      { src = Wq;  dst = wqb;  off = t; }
    else if (t < 786432) { src = Wkv; dst = wkvb; off = t - 262144; }
    else                 { src = Wfc; dst = wfcb; off = t - 786432; }
    f32x4 v = *(const f32x4*)(src + (size_t)off * 4);
    bf16x4 o;
    o[0] = (bf16_t)v[0]; o[1] = (bf16_t)v[1]; o[2] = (bf16_t)v[2]; o[3] = (bf16_t)v[3];
    *(bf16x4*)(dst + (size_t)off * 4) = o;
  } else if (t < (2 << 20)) {
    int th = t - (1 << 20);
    int idx = th << 2;
    int b   = idx >> 21;
    int rem = idx & ((1 << 21) - 1);
    int tt  = rem >> 10;
    int c   = rem & 1023;
    const float* s = (tt < 1024)
        ? (mem + ((size_t)b * 1024 + tt) * DM + c)
        : (x   + ((size_t)b * 1024 + (tt - 1024)) * DM + c);
    f32x4 v = *(const f32x4*)s;
    bf16x4 o;
    o[0] = (bf16_t)v[0]; o[1] = (bf16_t)v[1]; o[2] = (bf16_t)v[2]; o[3] = (bf16_t)v[3];
    *(bf16x4*)(hb + idx) = o;
  } else {
    int tp = t - (2 << 20);
    int d4 = (tp & 15) << 2;
    int j  = (tp >> 4) & 2047;
    int bh = tp >> 15;
    int h  = bh & 15;
    f32x4 v = *(const f32x4*)(pos + (size_t)j * DM + h * 64 + d4);
    bf16x4 o;
    o[0] = (bf16_t)v[0]; o[1] = (bf16_t)v[1]; o[2] = (bf16_t)v[2]; o[3] = (bf16_t)v[3];
    *(bf16x4*)(Bs + ((size_t)bh * TT + j) * 128 + 64 + d4) = o;
  }
}

// ---------------- LDS-staged GEMM core, double-buffered, XOR-swizzled ----------------
template<int WM>
__device__ __forceinline__ void gemm_core(const bf16_t* __restrict__ A,
                                          const bf16_t* __restrict__ B,
                                          int r0, int c0,
                                          bf16_t* At, bf16_t* Bt,
                                          f32x4 (&acc)[WM][4]) {
  const int ASZ = WM * 1024;
  const int BSZ = 4096;
  const int tid = threadIdx.x, w = tid >> 6, l = tid & 63;
  const int lm = l & 15, q = l >> 4;
  const int wrow = w >> 1, wcol = w & 1;
  const int gg  = (l & 3) ^ ((l >> 3) & 3);
  const int rsw = (lm >> 1) & 3;
  const bf16_t* gA = A + (size_t)(r0 + w * (WM / 2) * 16 + (l >> 2)) * 1024 + gg * 8;
  const bf16_t* gB = B + (size_t)(c0 + w * 32 + (l >> 2)) * 1024 + gg * 8;
  bf16_t* lA = At + w * (WM / 2) * 512;
  bf16_t* lB = Bt + w * 1024;
  const bf16_t* fA = At + (wrow * WM * 16 + lm) * 32;
  const bf16_t* fB = Bt + (wcol * 64 + lm) * 32;
#pragma unroll
  for (int t2 = 0; t2 < WM / 2; ++t2) gl_lds16(gA + (size_t)t2 * 16384, lA + t2 * 512);
#pragma unroll
  for (int t2 = 0; t2 < 2; ++t2)      gl_lds16(gB + (size_t)t2 * 16384, lB + t2 * 512);
  __syncthreads();
  int p = 0;
  for (int k0 = 0; k0 < 1024; k0 += 32) {
    int pn = p ^ 1;
    if (k0 < 992) {
#pragma unroll
      for (int t2 = 0; t2 < WM / 2; ++t2)
        gl_lds16(gA + (size_t)t2 * 16384 + k0 + 32, lA + pn * ASZ + t2 * 512);
#pragma unroll
      for (int t2 = 0; t2 < 2; ++t2)
        gl_lds16(gB + (size_t)t2 * 16384 + k0 + 32, lB + pn * BSZ + t2 * 512);
    }
    bf16x8 af[WM], bfm[4];
#pragma unroll
    for (int it = 0; it < WM; ++it)
      af[it] = *(const bf16x8*)(fA + p * ASZ + it * 512 + ((q ^ rsw) << 3));
#pragma unroll
    for (int jt = 0; jt < 4; ++jt)
      bfm[jt] = *(const bf16x8*)(fB + p * BSZ + jt * 512 + ((q ^ rsw) << 3));
#pragma unroll
    for (int it = 0; it < WM; ++it)
#pragma unroll
      for (int jt = 0; jt < 4; ++jt)
        acc[it][jt] = mfma32(af[it], bfm[jt], acc[it][jt]);
    __syncthreads();
    p = pn;
  }
}

// ---------------- K1: q GEMM -> A_s = [(q+u)*SCALE | shift((q+v))*SCALE] ----------------
__global__ __launch_bounds__(256) void k1_q(const bf16_t* __restrict__ hb,
                                            const bf16_t* __restrict__ Wqb,
                                            const float* __restrict__ u,
                                            const float* __restrict__ v,
                                            bf16_t* __restrict__ As) {
  __shared__ union { struct { bf16_t At[4096]; bf16_t Bt[8192]; } m; float Tt[4][272]; } sm;
  int blk = blockIdx.x;
  int r0 = (blk >> 3) * 64, c0 = (blk & 7) * 128;
  int b = r0 >> 10;
  const bf16_t* Axv = hb + ((size_t)(b + 1) << 20);
  f32x4 acc[2][4] = {};
  gemm_core<2>(Axv, Wqb, r0, c0, sm.m.At, sm.m.Bt, acc);
  const int tid = threadIdx.x, w = tid >> 6, l = tid & 63;
  const int lm = l & 15, q = l >> 4;
  const int wrow = w >> 1, wcol = w & 1;
  float* Tw = sm.Tt[w];
  int h = (c0 + wcol * 64) >> 6;
#pragma unroll
  for (int it = 0; it < 2; ++it) {
#pragma unroll
    for (int jt = 0; jt < 4; ++jt) {
#pragma unroll
      for (int r = 0; r < 4; ++r) Tw[(q * 4 + r) * 17 + lm] = acc[it][jt][r];
      __builtin_amdgcn_wave_barrier();
      int row = r0 + wrow * 32 + it * 16 + lm;
      int ii = row & 1023;
      int cbase = c0 + wcol * 64 + jt * 16 + q * 4;
      int d0 = cbase & 63;
      f32x4 u4 = *(const f32x4*)(u + cbase);
      f32x4 v4 = *(const f32x4*)(v + cbase);
      f32x4 tv;
#pragma unroll
      for (int e = 0; e < 4; ++e) tv[e] = Tw[lm * 17 + q * 4 + e];
      bf16x4 oc, op;
#pragma unroll
      for (int e = 0; e < 4; ++e) {
        oc[e] = (bf16_t)((tv[e] + u4[e]) * SCALE_A);
        op[e] = (bf16_t)((tv[e] + v4[e]) * SCALE_A);
      }
      *(bf16x4*)(As + (((size_t)(b * 16 + h)) * CUR + ii) * 128 + d0) = oc;
      if (b == 0) {
        if (ii >= 1)
          *(bf16x4*)(As + (((size_t)h) * CUR + (ii - 1)) * 128 + 64 + d0) = op;
        if (ii == 1023) {
          bf16x4 z = {};
          *(bf16x4*)(As + (((size_t)h) * CUR + 1023) * 128 + 64 + d0) = z;
        }
      } else {
        *(bf16x4*)(As + (((size_t)(16 + h)) * CUR + ii) * 128 + 64 + d0) = op;
      }
      __builtin_amdgcn_wave_barrier();
    }
  }
}

// ---------------- K2: kv GEMM -> k (transposed epilogue) + vvT ----------------
__global__ __launch_bounds__(256) void k2_kv(const bf16_t* __restrict__ hb,
                                             const bf16_t* __restrict__ Wkvb,
                                             bf16_t* __restrict__ Bs,
                                             bf16_t* __restrict__ vvT) {
  __shared__ union { struct { bf16_t At[8192]; bf16_t Bt[8192]; } m; float Tt[4][272]; } sm;
  int blk = blockIdx.x;
  int xcd = blk & 7, t = blk >> 3;
  int r0 = (t & 31) * 128;
  int c0 = (xcd * 2 + (t >> 5)) * 128;
  f32x4 acc[4][4] = {};
  gemm_core<4>(hb, Wkvb, r0, c0, sm.m.At, sm.m.Bt, acc);
  const int tid = threadIdx.x, w = tid >> 6, l = tid & 63;
  const int lm = l & 15, q = l >> 4;
  const int wrow = w >> 1, wcol = w & 1;
  int b = r0 >> 11;
  if (c0 < 1024) {
    float* Tw = sm.Tt[w];
    int h = (c0 + wcol * 64) >> 6;
#pragma unroll
    for (int it = 0; it < 4; ++it) {
#pragma unroll
      for (int jt = 0; jt < 4; ++jt) {
#pragma unroll
        for (int r = 0; r < 4; ++r) Tw[(q * 4 + r) * 17 + lm] = acc[it][jt][r];
        __builtin_amdgcn_wave_barrier();
        int j = (r0 + wrow * 64 + it * 16 + lm) & 2047;
        int d0 = jt * 16 + q * 4;
        bf16x4 o;
#pragma unroll
        for (int e = 0; e < 4; ++e) o[e] = (bf16_t)Tw[lm * 17 + q * 4 + e];
        *(bf16x4*)(Bs + (((size_t)(b * 16 + h)) * TT + j) * 128 + d0) = o;
        __builtin_amdgcn_wave_barrier();
      }
    }
  } else {
#pragma unroll
    for (int it = 0; it < 4; ++it) {
#pragma unroll
      for (int jt = 0; jt < 4; ++jt) {
        int c2 = c0 + wcol * 64 + jt * 16 + lm - 1024;
        int h = c2 >> 6, d = c2 & 63;
        int j = (r0 + wrow * 64 + it * 16 + q * 4) & 2047;
        bf16x4 o;
#pragma unroll
        for (int r = 0; r < 4; ++r) o[r] = (bf16_t)acc[it][jt][r];
        *(bf16x4*)(vvT + (((size_t)(b * 16 + h)) * 64 + d) * TT + j) = o;
      }
    }
  }
}

// ---------------- K3: partial col-sums over i-chunk: Lp[ich][bh][j] = sum exp2(s) ----------------
// grid 1024 = 8 xcd x (8 jblk x 4 ich x 4 bh'). j-width 64/wave, i-chunk 256.
__global__ __launch_bounds__(256) void k3_stats(const bf16_t* __restrict__ As,
                                                const bf16_t* __restrict__ Bs,
                                                float* __restrict__ Lp) {
  __shared__ bf16_t At[2 * 8192];
  const int tid = threadIdx.x, w = tid >> 6, l = tid & 63;
  const int lm = l & 15, q = l >> 4;
  const int gg  = (l & 3) ^ ((l >> 3) & 3);
  const int rsw = (lm >> 1) & 3;
  int blk = blockIdx.x;
  int xcd = blk & 7, t = blk >> 3;
  int jblk = t & 7, ich = (t >> 3) & 3, bh = xcd * 4 + (t >> 5);
  int j0 = jblk * 256 + w * 64;
  const bf16_t* bsrow = Bs + ((size_t)bh * TT + j0 + lm) * 128 + q * 8;
  bf16x8 bfr[4][4];
#pragma unroll
  for (int js = 0; js < 4; ++js)
#pragma unroll
    for (int kt = 0; kt < 4; ++kt)
      bfr[js][kt] = *(const bf16x8*)(bsrow + js * 2048 + kt * 32);
  const bf16_t* abase = As + (size_t)bh * CUR * 128 +
                        (size_t)(ich * 256 + (l >> 2)) * 128 + w * 32 + gg * 8;
  bf16_t* lA = At + w * 2048;
  const bf16_t* fA = At + lm * 32;
  float lacc[4] = {0.f, 0.f, 0.f, 0.f};
#pragma unroll
  for (int t2 = 0; t2 < 4; ++t2)
    gl_lds16(abase + (size_t)t2 * 16 * 128, lA + t2 * 512);
  __syncthreads();
  int p = 0;
  for (int ib = 0; ib < 4; ++ib) {
    int pn = p ^ 1;
    if (ib < 3) {
#pragma unroll
      for (int t2 = 0; t2 < 4; ++t2)
        gl_lds16(abase + (size_t)((ib + 1) * 64 + t2 * 16) * 128, lA + pn * 8192 + t2 * 512);
    }
#pragma unroll
    for (int isub = 0; isub < 4; ++isub) {
      bf16x8 af[4];
#pragma unroll
      for (int kt = 0; kt < 4; ++kt)
        af[kt] = *(const bf16x8*)(fA + p * 8192 + kt * 2048 + isub * 512 + ((q ^ rsw) << 3));
      f32x4 s[4] = {};
#pragma unroll
      for (int js = 0; js < 4; ++js)
#pragma unroll
        for (int kt = 0; kt < 4; ++kt)
          s[js] = mfma32(af[kt], bfr[js][kt], s[js]);
#pragma unroll
      for (int js = 0; js < 4; ++js)
        lacc[js] += (exp2fast(s[js][0]) + exp2fast(s[js][1])) +
                    (exp2fast(s[js][2]) + exp2fast(s[js][3]));
    }
    __syncthreads();
    p = pn;
  }
#pragma unroll
  for (int js = 0; js < 4; ++js) {
#pragma unroll
    for (int off = 16; off <= 32; off <<= 1)
      lacc[js] += __shfl_xor(lacc[js], off, 64);
  }
  if (l < 16) {
    float* lp = Lp + (size_t)ich * 65536 + (size_t)bh * TT + j0;
#pragma unroll
    for (int js = 0; js < 4; ++js) lp[js * 16 + l] = lacc[js];
  }
}

// ---------------- vscale: vvT[bh][d][j] *= rcp(sum_ich Lp[ich][j]) (in place) ----------------
__global__ __launch_bounds__(256) void vscale(const float* __restrict__ Lp,
                                              bf16_t* __restrict__ vvT) {
  int bh = blockIdx.x >> 3, jc = blockIdx.x & 7;
  int tid = threadIdx.x;
  int jj = jc * 256 + (tid & 63) * 4;
  int dg = tid >> 6;
  const float* lp = Lp + (size_t)bh * TT + jj;
  f32x4 a0 = *(const f32x4*)lp;
  f32x4 a1 = *(const f32x4*)(lp + 65536);
  f32x4 a2 = *(const f32x4*)(lp + 131072);
  f32x4 a3 = *(const f32x4*)(lp + 196608);
  f32x4 rl;
#pragma unroll
  for (int e = 0; e < 4; ++e)
    rl[e] = __builtin_amdgcn_rcpf((a0[e] + a1[e]) + (a2[e] + a3[e]));
  bf16_t* vb = vvT + ((size_t)bh * 64 + dg * 16) * TT + jj;
#pragma unroll
  for (int dd = 0; dd < 16; ++dd) {
    bf16x4 vv = *(const bf16x4*)(vb + (size_t)dd * TT);
    bf16x4 o;
#pragma unroll
    for (int e = 0; e < 4; ++e) o[e] = (bf16_t)((float)vv[e] * rl[e]);
    *(bf16x4*)(vb + (size_t)dd * TT) = o;
  }
}

// ---------------- K4: partial[i,d] over 256-j chunk; i-width 64/wave; bf16 partials ----------------
// grid 1024 = 8 xcd x (4 iblk x 4 bh' x 8 jch). dbuf, swizzled. V pre-normalized.
__global__ __launch_bounds__(256, 2) void k4_attnv(const bf16_t* __restrict__ As,
                                                   const bf16_t* __restrict__ Bs,
                                                   const bf16_t* __restrict__ vvT,
                                                   bf16_t* __restrict__ Pp) {
  __shared__ union {
    struct { bf16_t Bt[2 * 8192]; bf16_t Vt[2 * 4096]; } m;
    float Tt[4][1088];
  } sm;
  int blk = blockIdx.x;
  int xcd = blk & 7, tb = blk >> 3;
  int iblk = tb & 3, pl = tb >> 2;       // pl: bh'(4) x jch(8)
  int bh = xcd * 4 + (pl >> 3), jch = pl & 7;
  int b = bh >> 4, h = bh & 15;
  int i0 = iblk * 256;
  int jbase = jch * 256;
  const int tid = threadIdx.x, w = tid >> 6, l = tid & 63;
  const int lm = l & 15, q = l >> 4;
  const int gg  = (l & 3) ^ ((l >> 3) & 3);
  const int rsw = (lm >> 1) & 3;
  // register i-frags: 4 i-subtiles of 16 (wave covers 64 i)
  const bf16_t* ar = As + (size_t)bh * CUR * 128 + (size_t)(i0 + w * 64 + lm) * 128 + q * 8;
  bf16x8 bi[4][4];
#pragma unroll
  for (int is = 0; is < 4; ++is)
#pragma unroll
    for (int kt = 0; kt < 4; ++kt)
      bi[is][kt] = *(const bf16x8*)(ar + is * 2048 + kt * 32);
  const bf16_t* bbase = Bs + ((size_t)bh * TT + jbase) * 128 + (size_t)(l >> 2) * 128 + w * 32 + gg * 8;
  int inst0 = w * 2, inst1 = w * 2 + 1;
  const bf16_t* vsrc0 = vvT + ((size_t)bh * 64 + (inst0 & 3) * 16 + (l >> 2)) * TT + jbase +
                        (inst0 >> 2) * 32 + gg * 8;
  const bf16_t* vsrc1 = vvT + ((size_t)bh * 64 + (inst1 & 3) * 16 + (l >> 2)) * TT + jbase +
                        (inst1 >> 2) * 32 + gg * 8;
  bf16_t* vdst0 = sm.m.Vt + (inst0 >> 2) * 2048 + (inst0 & 3) * 512;
  bf16_t* vdst1 = sm.m.Vt + (inst1 >> 2) * 2048 + (inst1 & 3) * 512;
  bf16_t* lB = sm.m.Bt + w * 2048;
  f32x4 acc[4][4] = {};
#pragma unroll
  for (int t2 = 0; t2 < 4; ++t2)
    gl_lds16(bbase + (size_t)t2 * 16 * 128, lB + t2 * 512);
  gl_lds16(vsrc0, vdst0);
  gl_lds16(vsrc1, vdst1);
  __syncthreads();
  int p = 0;
  for (int jb = 0; jb < 4; ++jb) {
    int pn = p ^ 1;
    if (jb < 3) {
      const bf16_t* bs2 = bbase + (size_t)(jb + 1) * 64 * 128;
#pragma unroll
      for (int t2 = 0; t2 < 4; ++t2)
        gl_lds16(bs2 + (size_t)t2 * 16 * 128, lB + pn * 8192 + t2 * 512);
      gl_lds16(vsrc0 + (jb + 1) * 64, vdst0 + pn * 4096);
      gl_lds16(vsrc1 + (jb + 1) * 64, vdst1 + pn * 4096);
    }
    const bf16_t* fB = sm.m.Bt + p * 8192 + lm * 32;
    const bf16_t* vf = sm.m.Vt + p * 4096 + lm * 32;
#pragma unroll
    for (int js = 0; js < 4; ++js) {
      bf16x8 af[4];
#pragma unroll
      for (int kt = 0; kt < 4; ++kt)
        af[kt] = *(const bf16x8*)(fB + kt * 2048 + js * 512 + ((q ^ rsw) << 3));
      f32x4 s[4] = {};
#pragma unroll
      for (int is = 0; is < 4; ++is)
#pragma unroll
        for (int kt = 0; kt < 4; ++kt)
          s[is] = mfma32(af[kt], bi[is][kt], s[is]);
      bf16x4 pp[4];
#pragma unroll
      for (int is = 0; is < 4; ++is)
#pragma unroll
        for (int e = 0; e < 4; ++e)
          pp[is][e] = (bf16_t)exp2fast(s[is][e]);
      int vg = ((js & 1) << 1) | (q >> 1);
      const bf16_t* vfa = vf + (js >> 1) * 2048 + ((vg ^ rsw) << 3) + ((q & 1) << 2);
#pragma unroll
      for (int dt = 0; dt < 4; ++dt) {
        bf16x4 a2 = *(const bf16x4*)(vfa + dt * 512);
#pragma unroll
        for (int is = 0; is < 4; ++is)
          acc[is][dt] = mfma16(a2, pp[is], acc[is][dt]);
      }
    }
    __syncthreads();
    p = pn;
  }
  // epilogue: per i-subtile transpose wT[64 d][16 i] -> rows, store bf16 partials
  float* Tw = sm.Tt[w];
  bf16_t* pout = Pp + ((size_t)jch << 21);
  int ir = l >> 2, dc = (l & 3) * 16;
#pragma unroll
  for (int is = 0; is < 4; ++is) {
#pragma unroll
    for (int dt = 0; dt < 4; ++dt) {
      f32x4 a = acc[is][dt];
#pragma unroll
      for (int r = 0; r < 4; ++r) Tw[(dt * 16 + q * 4 + r) * 17 + lm] = a[r];
    }
    __builtin_amdgcn_wave_barrier();
    int i = i0 + w * 64 + is * 16 + ir;
    bf16_t* orow = pout + ((size_t)(b * CUR + i)) * DM + h * 64 + dc;
#pragma unroll
    for (int e4 = 0; e4 < 4; ++e4) {
      bf16x4 o;
#pragma unroll
      for (int e = 0; e < 4; ++e) o[e] = (bf16_t)Tw[(dc + e4 * 4 + e) * 17 + ir];
      *(bf16x4*)(orow + e4 * 4) = o;
    }
    __builtin_amdgcn_wave_barrier();
  }
}

// ---------------- K4r: wbuf = bf16(sum of 8 bf16 partial chunks) ----------------
__global__ __launch_bounds__(256) void k4_reduce(const bf16_t* __restrict__ P,
                                                 bf16_t* __restrict__ wbuf) {
  int t = blockIdx.x * 256 + threadIdx.x;
  float s[4] = {0.f, 0.f, 0.f, 0.f};
#pragma unroll
  for (int c = 0; c < 8; ++c) {
    bf16x4 v = *(const bf16x4*)(P + ((size_t)c << 21) + (size_t)t * 4);
#pragma unroll
    for (int e = 0; e < 4; ++e) s[e] += (float)v[e];
  }
  bf16x4 o;
#pragma unroll
  for (int e = 0; e < 4; ++e) o[e] = (bf16_t)s[e];
  *(bf16x4*)(wbuf + (size_t)t * 4) = o;
}

// ---------------- K5: y = x + w @ Wfc^T + bfc (transposed epilogue) ----------------
__global__ __launch_bounds__(256) void k5_fc(const bf16_t* __restrict__ wb,
                                             const bf16_t* __restrict__ Wfcb,
                                             const float* __restrict__ x,
                                             const float* __restrict__ bfc,
                                             float* __restrict__ y) {
  __shared__ union { struct { bf16_t At[4096]; bf16_t Bt[8192]; } m; float Tt[4][272]; } sm;
  int blk = blockIdx.x;
  int r0 = (blk >> 3) * 64, c0 = (blk & 7) * 128;
  f32x4 acc[2][4] = {};
  gemm_core<2>(wb, Wfcb, r0, c0, sm.m.At, sm.m.Bt, acc);
  const int tid = threadIdx.x, w = tid >> 6, l = tid & 63;
  const int lm = l & 15, q = l >> 4;
  const int wrow = w >> 1, wcol = w & 1;
  float* Tw = sm.Tt[w];
#pragma unroll
  for (int it = 0; it < 2; ++it) {
#pragma unroll
    for (int jt = 0; jt < 4; ++jt) {
#pragma unroll
      for (int r = 0; r < 4; ++r) Tw[(q * 4 + r) * 17 + lm] = acc[it][jt][r];
      __builtin_amdgcn_wave_barrier();
      int row = r0 + wrow * 32 + it * 16 + lm;
      int cb = c0 + wcol * 64 + jt * 16 + q * 4;
      f32x4 xb4 = *(const f32x4*)(x + (size_t)row * DM + cb);
      f32x4 bf4 = *(const f32x4*)(bfc + cb);
      f32x4 o;
#pragma unroll
      for (int e = 0; e < 4; ++e) o[e] = Tw[lm * 17 + q * 4 + e] + xb4[e] + bf4[e];
      *(f32x4*)(y + (size_t)row * DM + cb) = o;
      __builtin_amdgcn_wave_barrier();
    }
  }
}

// ---------------- K6: LayerNorm ----------------
__global__ __launch_bounds__(256) void k6_ln(const float* __restrict__ y,
                                             const float* __restrict__ gamma,
                                             const float* __restrict__ beta,
                                             float* __restrict__ out) {
  int row = blockIdx.x, t = threadIdx.x;
  const float* yr = y + (size_t)row * DM;
  f32x4 v = *(const f32x4*)(yr + t * 4);
  float s = v[0] + v[1] + v[2] + v[3];
  float ss = v[0] * v[0] + v[1] * v[1] + v[2] * v[2] + v[3] * v[3];
#pragma unroll
  for (int off = 1; off < 64; off <<= 1) {
    s += __shfl_xor(s, off, 64);
    ss += __shfl_xor(ss, off, 64);
  }
  __shared__ float ps[4], pss[4];
  int wv = t >> 6, ln = t & 63;
  if (ln == 0) { ps[wv] = s; pss[wv] = ss; }
  __syncthreads();
  s = ps[0] + ps[1] + ps[2] + ps[3];
  ss = pss[0] + pss[1] + pss[2] + pss[3];
  float mu = s * (1.0f / DM);
  float var = ss * (1.0f / DM) - mu * mu;
  float rstd = rsqrtf(var + 1e-5f);
  f32x4 g = *(const f32x4*)(gamma + t * 4);
  f32x4 bb = *(const f32x4*)(beta + t * 4);
  f32x4 o;
#pragma unroll
  for (int e = 0; e < 4; ++e) o[e] = (v[e] - mu) * rstd * g[e] + bb[e];
  *(f32x4*)(out + (size_t)row * DM + t * 4) = o;
}

// ---------------- launch ----------------
extern "C" void kernel_launch(void* const* d_in, const int* in_sizes, int n_in,
                              void* d_out, int out_size, void* d_ws, size_t ws_size,
                              hipStream_t stream) {
  const float* x    = (const float*)d_in[0];
  const float* pos  = (const float*)d_in[1];
  const float* u    = (const float*)d_in[2];
  const float* v    = (const float*)d_in[3];
  const float* mem  = (const float*)d_in[5];
  const float* Wq   = (const float*)d_in[6];
  const float* Wkv  = (const float*)d_in[7];
  const float* Wfc  = (const float*)d_in[8];
  const float* bfc  = (const float*)d_in[9];
  const float* gam  = (const float*)d_in[10];
  const float* bet  = (const float*)d_in[11];
  float* out = (float*)d_out;

  char* ws = (char*)d_ws;
  const size_t MB = 1ull << 20;
  bf16_t* hb   = (bf16_t*)(ws);              // 0-8    (prep -> k2)
  bf16_t* wqb  = (bf16_t*)(ws + 8 * MB);     // 8-10   (prep -> k1)
  bf16_t* wkvb = (bf16_t*)(ws + 10 * MB);    // 10-14  (prep -> k2)
  bf16_t* As   = (bf16_t*)(ws + 14 * MB);    // 14-22  (k1 -> k4)
  bf16_t* Bs   = (bf16_t*)(ws + 22 * MB);    // 22-38  (prep/k2 -> k4)
  bf16_t* vvT  = (bf16_t*)(ws + 38 * MB);    // 38-46  (k2 -> vscale -> k4)
  bf16_t* wfcb = (bf16_t*)(ws + 46 * MB);    // 46-48  (prep -> k5)
  float*  Lp   = (float*) (ws + 48 * MB);    // 1 MB   (k3 -> vscale), 4 slices
  bf16_t* Pp   = (bf16_t*)(ws + 49 * MB);    // 49-81  (k4 -> k4r), 8 x 4 MB
  bf16_t* wbuf = (bf16_t*)(ws);              // 0-4    (k4r -> k5, hb dead)
  float*  y    = (float*) (ws + 4 * MB);     // 4-12   (k5 -> k6)

  prep_kernel<<<12288, 256, 0, stream>>>(Wq, Wkv, Wfc, mem, x, pos,
                                         wqb, wkvb, wfcb, hb, Bs);
  k1_q<<<256, 256, 0, stream>>>(hb, wqb, u, v, As);
  k2_kv<<<512, 256, 0, stream>>>(hb, wkvb, Bs, vvT);

  k3_stats<<<1024, 256, 0, stream>>>(As, Bs, Lp);
  vscale<<<256, 256, 0, stream>>>(Lp, vvT);
  k4_attnv<<<1024, 256, 0, stream>>>(As, Bs, vvT, Pp);
  k4_reduce<<<2048, 256, 0, stream>>>(Pp, wbuf);

  k5_fc<<<256, 256, 0, stream>>>(wbuf, wfcb, x, bfc, y);
  k6_ln<<<2048, 256, 0, stream>>>(y, gam, bet, out);
}

// Round 8
// 234.448 us; speedup vs baseline: 2.9722x; 1.0241x over previous
//
#include <hip/hip_runtime.h>

#define DM   1024
#define CUR  1024
#define TT   2048

typedef float  f32x4  __attribute__((ext_vector_type(4)));
typedef __bf16 bf16_t;
typedef __bf16 bf16x8 __attribute__((ext_vector_type(8)));
typedef __bf16 bf16x4 __attribute__((ext_vector_type(4)));
typedef short  s16x4  __attribute__((ext_vector_type(4)));

#define SCALE_A 0.18033688f   // 0.125 * log2(e): scores live in log2 domain

static __device__ __forceinline__ float exp2fast(float x) { return __builtin_amdgcn_exp2f(x); }

static __device__ __forceinline__ f32x4 mfma32(bf16x8 a, bf16x8 b, f32x4 c) {
  return __builtin_amdgcn_mfma_f32_16x16x32_bf16(a, b, c, 0, 0, 0);
}
static __device__ __forceinline__ f32x4 mfma16(bf16x4 a, bf16x4 b, f32x4 c) {
  return __builtin_amdgcn_mfma_f32_16x16x16bf16_1k(
      __builtin_bit_cast(s16x4, a), __builtin_bit_cast(s16x4, b), c, 0, 0, 0);
}
static __device__ __forceinline__ void gl_lds16(const bf16_t* g, bf16_t* l) {
  __builtin_amdgcn_global_load_lds(
      (const __attribute__((address_space(1))) void*)g,
      (__attribute__((address_space(3))) void*)l, 16, 0, 0);
}

// ---------------- fused prep: weight cvt + h concat cvt + pe fill ----------------
__global__ __launch_bounds__(256) void prep_kernel(const float* __restrict__ Wq,
                                                   const float* __restrict__ Wkv,
                                                   const float* __restrict__ Wfc,
                                                   const float* __restrict__ mem,
                                                   const float* __restrict__ x,
                                                   const float* __restrict__ pos,
                                                   bf16_t* __restrict__ wqb,
                                                   bf16_t* __restrict__ wkvb,
                                                   bf16_t* __restrict__ wfcb,
                                                   bf16_t* __restrict__ hb,
                                                   bf16_t* __restrict__ Bs) {
  int t = blockIdx.x * 256 + threadIdx.x;   // [0, 3M)
  if (t < (1 << 20)) {
    const float* src; bf16_t* dst; int off;
    if (t < 262144)      { src = Wq;  dst = wqb;  off = t; }
    else if (t < 786432) { src = Wkv; dst = wkvb; off = t - 262144; }
    else                 { src = Wfc; dst = wfcb; off = t - 786432; }
    f32x4 v = *(const f32x4*)(src + (size_t)off * 4);
    bf16x4 o;
    o[0] = (bf16_t)v[0]; o[1] = (bf16_t)v[1]; o[2] = (bf16_t)v[2]; o[3] = (bf16_t)v[3];
    *(bf16x4*)(dst + (size_t)off * 4) = o;
  } else if (t < (2 << 20)) {
    int th = t - (1 << 20);
    int idx = th << 2;
    int b   = idx >> 21;
    int rem = idx & ((1 << 21) - 1);
    int tt  = rem >> 10;
    int c   = rem & 1023;
    const float* s = (tt < 1024)
        ? (mem + ((size_t)b * 1024 + tt) * DM + c)
        : (x   + ((size_t)b * 1024 + (tt - 1024)) * DM + c);
    f32x4 v = *(const f32x4*)s;
    bf16x4 o;
    o[0] = (bf16_t)v[0]; o[1] = (bf16_t)v[1]; o[2] = (bf16_t)v[2]; o[3] = (bf16_t)v[3];
    *(bf16x4*)(hb + idx) = o;
  } else {
    int tp = t - (2 << 20);
    int d4 = (tp & 15) << 2;
    int j  = (tp >> 4) & 2047;
    int bh = tp >> 15;
    int h  = bh & 15;
    f32x4 v = *(const f32x4*)(pos + (size_t)j * DM + h * 64 + d4);
    bf16x4 o;
    o[0] = (bf16_t)v[0]; o[1] = (bf16_t)v[1]; o[2] = (bf16_t)v[2]; o[3] = (bf16_t)v[3];
    *(bf16x4*)(Bs + ((size_t)bh * TT + j) * 128 + 64 + d4) = o;
  }
}

// ---------------- LDS-staged GEMM core, double-buffered, XOR-swizzled ----------------
template<int WM>
__device__ __forceinline__ void gemm_core(const bf16_t* __restrict__ A,
                                          const bf16_t* __restrict__ B,
                                          int r0, int c0,
                                          bf16_t* At, bf16_t* Bt,
                                          f32x4 (&acc)[WM][4]) {
  const int ASZ = WM * 1024;
  const int BSZ = 4096;
  const int tid = threadIdx.x, w = tid >> 6, l = tid & 63;
  const int lm = l & 15, q = l >> 4;
  const int wrow = w >> 1, wcol = w & 1;
  const int gg  = (l & 3) ^ ((l >> 3) & 3);
  const int rsw = (lm >> 1) & 3;
  const bf16_t* gA = A + (size_t)(r0 + w * (WM / 2) * 16 + (l >> 2)) * 1024 + gg * 8;
  const bf16_t* gB = B + (size_t)(c0 + w * 32 + (l >> 2)) * 1024 + gg * 8;
  bf16_t* lA = At + w * (WM / 2) * 512;
  bf16_t* lB = Bt + w * 1024;
  const bf16_t* fA = At + (wrow * WM * 16 + lm) * 32;
  const bf16_t* fB = Bt + (wcol * 64 + lm) * 32;
#pragma unroll
  for (int t2 = 0; t2 < WM / 2; ++t2) gl_lds16(gA + (size_t)t2 * 16384, lA + t2 * 512);
#pragma unroll
  for (int t2 = 0; t2 < 2; ++t2)      gl_lds16(gB + (size_t)t2 * 16384, lB + t2 * 512);
  __syncthreads();
  int p = 0;
  for (int k0 = 0; k0 < 1024; k0 += 32) {
    int pn = p ^ 1;
    if (k0 < 992) {
#pragma unroll
      for (int t2 = 0; t2 < WM / 2; ++t2)
        gl_lds16(gA + (size_t)t2 * 16384 + k0 + 32, lA + pn * ASZ + t2 * 512);
#pragma unroll
      for (int t2 = 0; t2 < 2; ++t2)
        gl_lds16(gB + (size_t)t2 * 16384 + k0 + 32, lB + pn * BSZ + t2 * 512);
    }
    bf16x8 af[WM], bfm[4];
#pragma unroll
    for (int it = 0; it < WM; ++it)
      af[it] = *(const bf16x8*)(fA + p * ASZ + it * 512 + ((q ^ rsw) << 3));
#pragma unroll
    for (int jt = 0; jt < 4; ++jt)
      bfm[jt] = *(const bf16x8*)(fB + p * BSZ + jt * 512 + ((q ^ rsw) << 3));
#pragma unroll
    for (int it = 0; it < WM; ++it)
#pragma unroll
      for (int jt = 0; jt < 4; ++jt)
        acc[it][jt] = mfma32(af[it], bfm[jt], acc[it][jt]);
    __syncthreads();
    p = pn;
  }
}

// ---------------- K12: fused q-GEMM (k1) + kv-GEMM (k2) ----------------
// grid 768: blocks [0,512) do kv (BM=128), [512,768) do q (BM=64).
// Both depend only on prep; co-resident at 3 blocks/CU so k1's tail fills under k2.
__global__ __launch_bounds__(256) void k12_gemm(const bf16_t* __restrict__ hb,
                                                const bf16_t* __restrict__ Wqb,
                                                const bf16_t* __restrict__ Wkvb,
                                                const float* __restrict__ u,
                                                const float* __restrict__ v,
                                                bf16_t* __restrict__ As,
                                                bf16_t* __restrict__ Bs,
                                                bf16_t* __restrict__ vvT) {
  __shared__ union { struct { bf16_t At[8192]; bf16_t Bt[8192]; } m; float Tt[4][272]; } sm;
  const int tid = threadIdx.x, w = tid >> 6, l = tid & 63;
  const int lm = l & 15, q = l >> 4;
  const int wrow = w >> 1, wcol = w & 1;
  int blk = blockIdx.x;
  if (blk < 512) {
    // ---- kv GEMM ----
    int xcd = blk & 7, t = blk >> 3;
    int r0 = (t & 31) * 128;
    int c0 = (xcd * 2 + (t >> 5)) * 128;
    f32x4 acc[4][4] = {};
    gemm_core<4>(hb, Wkvb, r0, c0, sm.m.At, sm.m.Bt, acc);
    int b = r0 >> 11;
    if (c0 < 1024) {
      float* Tw = sm.Tt[w];
      int h = (c0 + wcol * 64) >> 6;
#pragma unroll
      for (int it = 0; it < 4; ++it) {
#pragma unroll
        for (int jt = 0; jt < 4; ++jt) {
#pragma unroll
          for (int r = 0; r < 4; ++r) Tw[(q * 4 + r) * 17 + lm] = acc[it][jt][r];
          __builtin_amdgcn_wave_barrier();
          int j = (r0 + wrow * 64 + it * 16 + lm) & 2047;
          int d0 = jt * 16 + q * 4;
          bf16x4 o;
#pragma unroll
          for (int e = 0; e < 4; ++e) o[e] = (bf16_t)Tw[lm * 17 + q * 4 + e];
          *(bf16x4*)(Bs + (((size_t)(b * 16 + h)) * TT + j) * 128 + d0) = o;
          __builtin_amdgcn_wave_barrier();
        }
      }
    } else {
#pragma unroll
      for (int it = 0; it < 4; ++it) {
#pragma unroll
        for (int jt = 0; jt < 4; ++jt) {
          int c2 = c0 + wcol * 64 + jt * 16 + lm - 1024;
          int h = c2 >> 6, d = c2 & 63;
          int j = (r0 + wrow * 64 + it * 16 + q * 4) & 2047;
          bf16x4 o;
#pragma unroll
          for (int r = 0; r < 4; ++r) o[r] = (bf16_t)acc[it][jt][r];
          *(bf16x4*)(vvT + (((size_t)(b * 16 + h)) * 64 + d) * TT + j) = o;
        }
      }
    }
  } else {
    // ---- q GEMM -> A_s = [(q+u)*SCALE | shift((q+v))*SCALE] ----
    int blk2 = blk - 512;
    int r0 = (blk2 >> 3) * 64, c0 = (blk2 & 7) * 128;
    int b = r0 >> 10;
    const bf16_t* Axv = hb + ((size_t)(b + 1) << 20);  // hb row (b+1)*1024 + r == x row r
    f32x4 acc[2][4] = {};
    gemm_core<2>(Axv, Wqb, r0, c0, sm.m.At, sm.m.Bt, acc);
    float* Tw = sm.Tt[w];
    int h = (c0 + wcol * 64) >> 6;
#pragma unroll
    for (int it = 0; it < 2; ++it) {
#pragma unroll
      for (int jt = 0; jt < 4; ++jt) {
#pragma unroll
        for (int r = 0; r < 4; ++r) Tw[(q * 4 + r) * 17 + lm] = acc[it][jt][r];
        __builtin_amdgcn_wave_barrier();
        int row = r0 + wrow * 32 + it * 16 + lm;
        int ii = row & 1023;
        int cbase = c0 + wcol * 64 + jt * 16 + q * 4;
        int d0 = cbase & 63;
        f32x4 u4 = *(const f32x4*)(u + cbase);
        f32x4 v4 = *(const f32x4*)(v + cbase);
        f32x4 tv;
#pragma unroll
        for (int e = 0; e < 4; ++e) tv[e] = Tw[lm * 17 + q * 4 + e];
        bf16x4 oc, op;
#pragma unroll
        for (int e = 0; e < 4; ++e) {
          oc[e] = (bf16_t)((tv[e] + u4[e]) * SCALE_A);
          op[e] = (bf16_t)((tv[e] + v4[e]) * SCALE_A);
        }
        *(bf16x4*)(As + (((size_t)(b * 16 + h)) * CUR + ii) * 128 + d0) = oc;
        if (b == 0) {
          if (ii >= 1)
            *(bf16x4*)(As + (((size_t)h) * CUR + (ii - 1)) * 128 + 64 + d0) = op;
          if (ii == 1023) {
            bf16x4 z = {};
            *(bf16x4*)(As + (((size_t)h) * CUR + 1023) * 128 + 64 + d0) = z;
          }
        } else {
          *(bf16x4*)(As + (((size_t)(16 + h)) * CUR + ii) * 128 + 64 + d0) = op;
        }
        __builtin_amdgcn_wave_barrier();
      }
    }
  }
}

// ---------------- K3: partial col-sums over i-chunk: Lp[ich][bh][j] = sum exp2(s) ----------------
// grid 512 = 8 xcd x (4 jblk x 4 ich x 4 bh'). j-width 128/wave (bfr[8][4]), i-chunk 256.
__global__ __launch_bounds__(256) void k3_stats(const bf16_t* __restrict__ As,
                                                const bf16_t* __restrict__ Bs,
                                                float* __restrict__ Lp) {
  __shared__ bf16_t At[2 * 8192];
  const int tid = threadIdx.x, w = tid >> 6, l = tid & 63;
  const int lm = l & 15, q = l >> 4;
  const int gg  = (l & 3) ^ ((l >> 3) & 3);
  const int rsw = (lm >> 1) & 3;
  int blk = blockIdx.x;
  int xcd = blk & 7, t = blk >> 3;
  int jblk = t & 3, ich = (t >> 2) & 3, bh = xcd * 4 + (t >> 4);
  int j0 = jblk * 512 + w * 128;
  const bf16_t* bsrow = Bs + ((size_t)bh * TT + j0 + lm) * 128 + q * 8;
  bf16x8 bfr[8][4];
#pragma unroll
  for (int js = 0; js < 8; ++js)
#pragma unroll
    for (int kt = 0; kt < 4; ++kt)
      bfr[js][kt] = *(const bf16x8*)(bsrow + js * 2048 + kt * 32);
  const bf16_t* abase = As + (size_t)bh * CUR * 128 +
                        (size_t)(ich * 256 + (l >> 2)) * 128 + w * 32 + gg * 8;
  bf16_t* lA = At + w * 2048;
  const bf16_t* fA = At + lm * 32;
  float lacc[8] = {};
#pragma unroll
  for (int t2 = 0; t2 < 4; ++t2)
    gl_lds16(abase + (size_t)t2 * 16 * 128, lA + t2 * 512);
  __syncthreads();
  int p = 0;
  for (int ib = 0; ib < 4; ++ib) {
    int pn = p ^ 1;
    if (ib < 3) {
#pragma unroll
      for (int t2 = 0; t2 < 4; ++t2)
        gl_lds16(abase + (size_t)((ib + 1) * 64 + t2 * 16) * 128, lA + pn * 8192 + t2 * 512);
    }
#pragma unroll
    for (int isub = 0; isub < 4; ++isub) {
      bf16x8 af[4];
#pragma unroll
      for (int kt = 0; kt < 4; ++kt)
        af[kt] = *(const bf16x8*)(fA + p * 8192 + kt * 2048 + isub * 512 + ((q ^ rsw) << 3));
#pragma unroll
      for (int js = 0; js < 8; ++js) {
        f32x4 s = {};
#pragma unroll
        for (int kt = 0; kt < 4; ++kt)
          s = mfma32(af[kt], bfr[js][kt], s);
        lacc[js] += (exp2fast(s[0]) + exp2fast(s[1])) + (exp2fast(s[2]) + exp2fast(s[3]));
      }
    }
    __syncthreads();
    p = pn;
  }
#pragma unroll
  for (int js = 0; js < 8; ++js) {
#pragma unroll
    for (int off = 16; off <= 32; off <<= 1)
      lacc[js] += __shfl_xor(lacc[js], off, 64);
  }
  if (l < 16) {
    float* lp = Lp + (size_t)ich * 65536 + (size_t)bh * TT + j0;
#pragma unroll
    for (int js = 0; js < 8; ++js) lp[js * 16 + l] = lacc[js];
  }
}

// ---------------- vscale: vvT[bh][d][j] *= rcp(sum_ich Lp[ich][j]) (in place) ----------------
__global__ __launch_bounds__(256) void vscale(const float* __restrict__ Lp,
                                              bf16_t* __restrict__ vvT) {
  int bh = blockIdx.x >> 3, jc = blockIdx.x & 7;
  int tid = threadIdx.x;
  int jj = jc * 256 + (tid & 63) * 4;
  int dg = tid >> 6;
  const float* lp = Lp + (size_t)bh * TT + jj;
  f32x4 a0 = *(const f32x4*)lp;
  f32x4 a1 = *(const f32x4*)(lp + 65536);
  f32x4 a2 = *(const f32x4*)(lp + 131072);
  f32x4 a3 = *(const f32x4*)(lp + 196608);
  f32x4 rl;
#pragma unroll
  for (int e = 0; e < 4; ++e)
    rl[e] = __builtin_amdgcn_rcpf((a0[e] + a1[e]) + (a2[e] + a3[e]));
  bf16_t* vb = vvT + ((size_t)bh * 64 + dg * 16) * TT + jj;
#pragma unroll
  for (int dd = 0; dd < 16; ++dd) {
    bf16x4 vv = *(const bf16x4*)(vb + (size_t)dd * TT);
    bf16x4 o;
#pragma unroll
    for (int e = 0; e < 4; ++e) o[e] = (bf16_t)((float)vv[e] * rl[e]);
    *(bf16x4*)(vb + (size_t)dd * TT) = o;
  }
}

// ---------------- K4: partial[i,d] over 256-j chunk; i-width 64/wave; bf16 partials ----------------
// grid 1024 = 8 xcd x (4 iblk x 4 bh' x 8 jch). dbuf, swizzled. V pre-normalized.
__global__ __launch_bounds__(256, 2) void k4_attnv(const bf16_t* __restrict__ As,
                                                   const bf16_t* __restrict__ Bs,
                                                   const bf16_t* __restrict__ vvT,
                                                   bf16_t* __restrict__ Pp) {
  __shared__ union {
    struct { bf16_t Bt[2 * 8192]; bf16_t Vt[2 * 4096]; } m;
    float Tt[4][1088];
  } sm;
  int blk = blockIdx.x;
  int xcd = blk & 7, tb = blk >> 3;
  int iblk = tb & 3, pl = tb >> 2;       // pl: bh'(4) x jch(8)
  int bh = xcd * 4 + (pl >> 3), jch = pl & 7;
  int b = bh >> 4, h = bh & 15;
  int i0 = iblk * 256;
  int jbase = jch * 256;
  const int tid = threadIdx.x, w = tid >> 6, l = tid & 63;
  const int lm = l & 15, q = l >> 4;
  const int gg  = (l & 3) ^ ((l >> 3) & 3);
  const int rsw = (lm >> 1) & 3;
  const bf16_t* ar = As + (size_t)bh * CUR * 128 + (size_t)(i0 + w * 64 + lm) * 128 + q * 8;
  bf16x8 bi[4][4];
#pragma unroll
  for (int is = 0; is < 4; ++is)
#pragma unroll
    for (int kt = 0; kt < 4; ++kt)
      bi[is][kt] = *(const bf16x8*)(ar + is * 2048 + kt * 32);
  const bf16_t* bbase = Bs + ((size_t)bh * TT + jbase) * 128 + (size_t)(l >> 2) * 128 + w * 32 + gg * 8;
  int inst0 = w * 2, inst1 = w * 2 + 1;
  const bf16_t* vsrc0 = vvT + ((size_t)bh * 64 + (inst0 & 3) * 16 + (l >> 2)) * TT + jbase +
                        (inst0 >> 2) * 32 + gg * 8;
  const bf16_t* vsrc1 = vvT + ((size_t)bh * 64 + (inst1 & 3) * 16 + (l >> 2)) * TT + jbase +
                        (inst1 >> 2) * 32 + gg * 8;
  bf16_t* vdst0 = sm.m.Vt + (inst0 >> 2) * 2048 + (inst0 & 3) * 512;
  bf16_t* vdst1 = sm.m.Vt + (inst1 >> 2) * 2048 + (inst1 & 3) * 512;
  bf16_t* lB = sm.m.Bt + w * 2048;
  f32x4 acc[4][4] = {};
#pragma unroll
  for (int t2 = 0; t2 < 4; ++t2)
    gl_lds16(bbase + (size_t)t2 * 16 * 128, lB + t2 * 512);
  gl_lds16(vsrc0, vdst0);
  gl_lds16(vsrc1, vdst1);
  __syncthreads();
  int p = 0;
  for (int jb = 0; jb < 4; ++jb) {
    int pn = p ^ 1;
    if (jb < 3) {
      const bf16_t* bs2 = bbase + (size_t)(jb + 1) * 64 * 128;
#pragma unroll
      for (int t2 = 0; t2 < 4; ++t2)
        gl_lds16(bs2 + (size_t)t2 * 16 * 128, lB + pn * 8192 + t2 * 512);
      gl_lds16(vsrc0 + (jb + 1) * 64, vdst0 + pn * 4096);
      gl_lds16(vsrc1 + (jb + 1) * 64, vdst1 + pn * 4096);
    }
    const bf16_t* fB = sm.m.Bt + p * 8192 + lm * 32;
    const bf16_t* vf = sm.m.Vt + p * 4096 + lm * 32;
#pragma unroll
    for (int js = 0; js < 4; ++js) {
      bf16x8 af[4];
#pragma unroll
      for (int kt = 0; kt < 4; ++kt)
        af[kt] = *(const bf16x8*)(fB + kt * 2048 + js * 512 + ((q ^ rsw) << 3));
      f32x4 s[4] = {};
#pragma unroll
      for (int is = 0; is < 4; ++is)
#pragma unroll
        for (int kt = 0; kt < 4; ++kt)
          s[is] = mfma32(af[kt], bi[is][kt], s[is]);
      bf16x4 pp[4];
#pragma unroll
      for (int is = 0; is < 4; ++is)
#pragma unroll
        for (int e = 0; e < 4; ++e)
          pp[is][e] = (bf16_t)exp2fast(s[is][e]);
      int vg = ((js & 1) << 1) | (q >> 1);
      const bf16_t* vfa = vf + (js >> 1) * 2048 + ((vg ^ rsw) << 3) + ((q & 1) << 2);
#pragma unroll
      for (int dt = 0; dt < 4; ++dt) {
        bf16x4 a2 = *(const bf16x4*)(vfa + dt * 512);
#pragma unroll
        for (int is = 0; is < 4; ++is)
          acc[is][dt] = mfma16(a2, pp[is], acc[is][dt]);
      }
    }
    __syncthreads();
    p = pn;
  }
  // epilogue: per i-subtile transpose wT[64 d][16 i] -> rows, store bf16 partials
  float* Tw = sm.Tt[w];
  bf16_t* pout = Pp + ((size_t)jch << 21);
  int ir = l >> 2, dc = (l & 3) * 16;
#pragma unroll
  for (int is = 0; is < 4; ++is) {
#pragma unroll
    for (int dt = 0; dt < 4; ++dt) {
      f32x4 a = acc[is][dt];
#pragma unroll
      for (int r = 0; r < 4; ++r) Tw[(dt * 16 + q * 4 + r) * 17 + lm] = a[r];
    }
    __builtin_amdgcn_wave_barrier();
    int i = i0 + w * 64 + is * 16 + ir;
    bf16_t* orow = pout + ((size_t)(b * CUR + i)) * DM + h * 64 + dc;
#pragma unroll
    for (int e4 = 0; e4 < 4; ++e4) {
      bf16x4 o;
#pragma unroll
      for (int e = 0; e < 4; ++e) o[e] = (bf16_t)Tw[(dc + e4 * 4 + e) * 17 + ir];
      *(bf16x4*)(orow + e4 * 4) = o;
    }
    __builtin_amdgcn_wave_barrier();
  }
}

// ---------------- K4r: wbuf = bf16(sum of 8 bf16 partial chunks) ----------------
__global__ __launch_bounds__(256) void k4_reduce(const bf16_t* __restrict__ P,
                                                 bf16_t* __restrict__ wbuf) {
  int t = blockIdx.x * 256 + threadIdx.x;
  float s[4] = {0.f, 0.f, 0.f, 0.f};
#pragma unroll
  for (int c = 0; c < 8; ++c) {
    bf16x4 v = *(const bf16x4*)(P + ((size_t)c << 21) + (size_t)t * 4);
#pragma unroll
    for (int e = 0; e < 4; ++e) s[e] += (float)v[e];
  }
  bf16x4 o;
#pragma unroll
  for (int e = 0; e < 4; ++e) o[e] = (bf16_t)s[e];
  *(bf16x4*)(wbuf + (size_t)t * 4) = o;
}

// ---------------- K5: y = x + w @ Wfc^T + bfc (transposed epilogue) ----------------
__global__ __launch_bounds__(256) void k5_fc(const bf16_t* __restrict__ wb,
                                             const bf16_t* __restrict__ Wfcb,
                                             const float* __restrict__ x,
                                             const float* __restrict__ bfc,
                                             float* __restrict__ y) {
  __shared__ union { struct { bf16_t At[4096]; bf16_t Bt[8192]; } m; float Tt[4][272]; } sm;
  int blk = blockIdx.x;
  int r0 = (blk >> 3) * 64, c0 = (blk & 7) * 128;
  f32x4 acc[2][4] = {};
  gemm_core<2>(wb, Wfcb, r0, c0, sm.m.At, sm.m.Bt, acc);
  const int tid = threadIdx.x, w = tid >> 6, l = tid & 63;
  const int lm = l & 15, q = l >> 4;
  const int wrow = w >> 1, wcol = w & 1;
  float* Tw = sm.Tt[w];
#pragma unroll
  for (int it = 0; it < 2; ++it) {
#pragma unroll
    for (int jt = 0; jt < 4; ++jt) {
#pragma unroll
      for (int r = 0; r < 4; ++r) Tw[(q * 4 + r) * 17 + lm] = acc[it][jt][r];
      __builtin_amdgcn_wave_barrier();
      int row = r0 + wrow * 32 + it * 16 + lm;
      int cb = c0 + wcol * 64 + jt * 16 + q * 4;
      f32x4 xb4 = *(const f32x4*)(x + (size_t)row * DM + cb);
      f32x4 bf4 = *(const f32x4*)(bfc + cb);
      f32x4 o;
#pragma unroll
      for (int e = 0; e < 4; ++e) o[e] = Tw[lm * 17 + q * 4 + e] + xb4[e] + bf4[e];
      *(f32x4*)(y + (size_t)row * DM + cb) = o;
      __builtin_amdgcn_wave_barrier();
    }
  }
}

// ---------------- K6: LayerNorm ----------------
__global__ __launch_bounds__(256) void k6_ln(const float* __restrict__ y,
                                             const float* __restrict__ gamma,
                                             const float* __restrict__ beta,
                                             float* __restrict__ out) {
  int row = blockIdx.x, t = threadIdx.x;
  const float* yr = y + (size_t)row * DM;
  f32x4 v = *(const f32x4*)(yr + t * 4);
  float s = v[0] + v[1] + v[2] + v[3];
  float ss = v[0] * v[0] + v[1] * v[1] + v[2] * v[2] + v[3] * v[3];
#pragma unroll
  for (int off = 1; off < 64; off <<= 1) {
    s += __shfl_xor(s, off, 64);
    ss += __shfl_xor(ss, off, 64);
  }
  __shared__ float ps[4], pss[4];
  int wv = t >> 6, ln = t & 63;
  if (ln == 0) { ps[wv] = s; pss[wv] = ss; }
  __syncthreads();
  s = ps[0] + ps[1] + ps[2] + ps[3];
  ss = pss[0] + pss[1] + pss[2] + pss[3];
  float mu = s * (1.0f / DM);
  float var = ss * (1.0f / DM) - mu * mu;
  float rstd = rsqrtf(var + 1e-5f);
  f32x4 g = *(const f32x4*)(gamma + t * 4);
  f32x4 bb = *(const f32x4*)(beta + t * 4);
  f32x4 o;
#pragma unroll
  for (int e = 0; e < 4; ++e) o[e] = (v[e] - mu) * rstd * g[e] + bb[e];
  *(f32x4*)(out + (size_t)row * DM + t * 4) = o;
}

// ---------------- launch ----------------
extern "C" void kernel_launch(void* const* d_in, const int* in_sizes, int n_in,
                              void* d_out, int out_size, void* d_ws, size_t ws_size,
                              hipStream_t stream) {
  const float* x    = (const float*)d_in[0];
  const float* pos  = (const float*)d_in[1];
  const float* u    = (const float*)d_in[2];
  const float* v    = (const float*)d_in[3];
  const float* mem  = (const float*)d_in[5];
  const float* Wq   = (const float*)d_in[6];
  const float* Wkv  = (const float*)d_in[7];
  const float* Wfc  = (const float*)d_in[8];
  const float* bfc  = (const float*)d_in[9];
  const float* gam  = (const float*)d_in[10];
  const float* bet  = (const float*)d_in[11];
  float* out = (float*)d_out;

  char* ws = (char*)d_ws;
  const size_t MB = 1ull << 20;
  bf16_t* hb   = (bf16_t*)(ws);              // 0-8    (prep -> k12)
  bf16_t* wqb  = (bf16_t*)(ws + 8 * MB);     // 8-10   (prep -> k12)
  bf16_t* wkvb = (bf16_t*)(ws + 10 * MB);    // 10-14  (prep -> k12)
  bf16_t* As   = (bf16_t*)(ws + 14 * MB);    // 14-22  (k12 -> k4)
  bf16_t* Bs   = (bf16_t*)(ws + 22 * MB);    // 22-38  (prep/k12 -> k4)
  bf16_t* vvT  = (bf16_t*)(ws + 38 * MB);    // 38-46  (k12 -> vscale -> k4)
  bf16_t* wfcb = (bf16_t*)(ws + 46 * MB);    // 46-48  (prep -> k5)
  float*  Lp   = (float*) (ws + 48 * MB);    // 1 MB   (k3 -> vscale), 4 slices
  bf16_t* Pp   = (bf16_t*)(ws + 49 * MB);    // 49-81  (k4 -> k4r), 8 x 4 MB
  bf16_t* wbuf = (bf16_t*)(ws);              // 0-4    (k4r -> k5, hb dead)
  float*  y    = (float*) (ws + 4 * MB);     // 4-12   (k5 -> k6)

  prep_kernel<<<12288, 256, 0, stream>>>(Wq, Wkv, Wfc, mem, x, pos,
                                         wqb, wkvb, wfcb, hb, Bs);
  k12_gemm<<<768, 256, 0, stream>>>(hb, wqb, wkvb, u, v, As, Bs, vvT);

  k3_stats<<<512, 256, 0, stream>>>(As, Bs, Lp);
  vscale<<<256, 256, 0, stream>>>(Lp, vvT);
  k4_attnv<<<1024, 256, 0, stream>>>(As, Bs, vvT, Pp);
  k4_reduce<<<2048, 256, 0, stream>>>(Pp, wbuf);

  k5_fc<<<256, 256, 0, stream>>>(wbuf, wfcb, x, bfc, y);
  k6_ln<<<2048, 256, 0, stream>>>(y, gam, bet, out);
}